// Round 13
// baseline (301.462 us; speedup 1.0000x reference)
//
#include <hip/hip_runtime.h>
#include <math.h>

typedef _Float16 f16;
typedef _Float16 v8h __attribute__((ext_vector_type(8)));
typedef _Float16 v4h __attribute__((ext_vector_type(4)));
typedef float    v4f __attribute__((ext_vector_type(4)));

#define MFMA(a, b, c) __builtin_amdgcn_mfma_f32_16x16x32_f16((a), (b), (c), 0, 0, 0)

// ---------------- workspace layout (float offsets) ----------------
#define OFF_LN16    0u
#define OFF_LNLO    3145728u
#define OFF_FQ16    4194304u
#define OFF_FK16    5242880u
#define OFF_FVHT    6291456u
#define OFF_FVLT    7340032u
#define OFF_WINTH   8388608u
#define OFF_WINTL   8519680u
#define OFF_WOUTTH  8650752u
#define OFF_WOUTTL  8781824u
#define OFF_AVH     8912896u
#define OFF_AVL     9961472u
#define OFF_RQ1     11010048u
#define OFF_RQ2     11042816u
#define OFF_MUQ     11075584u
#define OFF_RK1     11108352u
#define OFF_RK2     11141120u
#define OFF_SK      11173888u
#define OFF_VC      11206656u   // 65536 (2 halves)
#define OFF_ROWCOS  11272192u   // 2 halves
#define OFF_ROWCOV  11337728u   // 2 halves
#define OFF_NUACC   11403264u   // 2048
#define OFF_PB      11405312u   // 1024*6
#define OFF_HS      11411456u   // 64
#define OFF_RP      11411520u   // 192
#define OFF_FEAT    11411712u   // 1024
#define OFF_WV      11412736u   // 24
#define OFF_SCAL    11412760u   // 8

__device__ __forceinline__ float clampf(float x, float lo, float hi) {
    return fminf(fmaxf(x, lo), hi);
}

__global__ void k_zero(float* feat, float* nuacck) {
    int i = blockIdx.x * 256 + threadIdx.x;
    if (i < 1024) feat[i] = 0.0f;
    if (i < 2048) nuacck[i] = 0.0f;
}

// transpose + hi/lo split of a 512x512 weight: W[k][c] -> WT{h,l}[c][k]
__global__ __launch_bounds__(256) void k_wprep(const float* __restrict__ Win,
        const float* __restrict__ Wout, f16* __restrict__ WinTh, f16* __restrict__ WinTl,
        f16* __restrict__ WoutTh, f16* __restrict__ WoutTl) {
    __shared__ float lds[64][68];
    const float* W = blockIdx.z ? Wout : Win;
    f16* Th = blockIdx.z ? WoutTh : WinTh;
    f16* Tl = blockIdx.z ? WoutTl : WinTl;
    int k0 = blockIdx.y * 64, c0 = blockIdx.x * 64;
    int t = threadIdx.x;
    #pragma unroll
    for (int p = 0; p < 4; ++p) {
        int flat = p * 1024 + t * 4;
        int r = flat >> 6, c = flat & 63;
        *(float4*)&lds[r][c] = *(const float4*)&W[(size_t)(k0 + r) * 512 + c0 + c];
    }
    __syncthreads();
    int c = t >> 2, kk = (t & 3) * 16;
    #pragma unroll
    for (int half = 0; half < 2; ++half) {
        v8h h8, l8;
        #pragma unroll
        for (int ii = 0; ii < 8; ++ii) {
            float v = lds[kk + half * 8 + ii][c];
            f16 h = (f16)v;
            h8[ii] = h;
            l8[ii] = (f16)(v - (float)h);
        }
        *(v8h*)&Th[(size_t)(c0 + c) * 512 + k0 + kk + half * 8] = h8;
        *(v8h*)&Tl[(size_t)(c0 + c) * 512 + k0 + kk + half * 8] = l8;
    }
}

// LayerNorm all 12288 tokens -> ln16 f16; v tokens also get lo residual
__global__ __launch_bounds__(256) void k_ln16(const float* __restrict__ q,
        const float* __restrict__ kk, const float* __restrict__ v,
        const float* __restrict__ lnw, const float* __restrict__ lnb,
        f16* __restrict__ ln16, f16* __restrict__ lnlo) {
    int t = threadIdx.x, wid = t >> 6, lane = t & 63;
    int token = blockIdx.x * 4 + wid;
    int inp = token >> 12, lt = token & 4095;
    const float* xp = (inp == 0) ? q : ((inp == 1) ? kk : v);
    const float4* xr = (const float4*)(xp + (size_t)lt * 512);
    float4 a = xr[lane], b = xr[lane + 64];
    float s = a.x + a.y + a.z + a.w + b.x + b.y + b.z + b.w;
    float s2 = a.x*a.x + a.y*a.y + a.z*a.z + a.w*a.w
             + b.x*b.x + b.y*b.y + b.z*b.z + b.w*b.w;
    for (int o = 32; o > 0; o >>= 1) { s += __shfl_down(s, o); s2 += __shfl_down(s2, o); }
    float m_ = __shfl(s, 0) * (1.0f / 512.0f);
    float var = __shfl(s2, 0) * (1.0f / 512.0f) - m_ * m_;
    var = fmaxf(var, 0.0f);
    float rs = rsqrtf(var + 1e-5f);
    const float4* w4 = (const float4*)lnw;
    const float4* b4 = (const float4*)lnb;
    float4 wa = w4[lane], wb = w4[lane + 64], ba = b4[lane], bb = b4[lane + 64];
    float ga[4] = { (a.x - m_) * rs * wa.x + ba.x, (a.y - m_) * rs * wa.y + ba.y,
                    (a.z - m_) * rs * wa.z + ba.z, (a.w - m_) * rs * wa.w + ba.w };
    float gb[4] = { (b.x - m_) * rs * wb.x + bb.x, (b.y - m_) * rs * wb.y + bb.y,
                    (b.z - m_) * rs * wb.z + bb.z, (b.w - m_) * rs * wb.w + bb.w };
    f16* orow = ln16 + (size_t)token * 512;
    v4h ha, hb;
    #pragma unroll
    for (int i = 0; i < 4; ++i) { ha[i] = (f16)ga[i]; hb[i] = (f16)gb[i]; }
    *(v4h*)&orow[lane * 4] = ha;
    *(v4h*)&orow[lane * 4 + 256] = hb;
    if (inp == 2) {
        f16* lrow = lnlo + (size_t)lt * 512;
        v4h la, lb;
        #pragma unroll
        for (int i = 0; i < 4; ++i) {
            la[i] = (f16)(ga[i] - (float)ha[i]);
            lb[i] = (f16)(gb[i] - (float)hb[i]);
        }
        *(v4h*)&lrow[lane * 4] = la;
        *(v4h*)&lrow[lane * 4 + 256] = lb;
    }
}

// LN16 @ Win (MFMA). MODE 0: q (fq16 + recip stats). MODE 1: k. MODE 2: v.
template<int MODE>
__device__ __forceinline__ void proj_body(const f16* __restrict__ A16,
        const f16* __restrict__ Alo,
        const f16* __restrict__ BTh, const f16* __restrict__ BTl,
        f16* __restrict__ fout16, f16* __restrict__ fhT, f16* __restrict__ flT,
        float* __restrict__ oA, float* __restrict__ oB, float* __restrict__ oC,
        float* __restrict__ feat, float* __restrict__ nuacck) {
    int t = threadIdx.x, l = t & 63, w = t >> 6;
    int wr = w >> 1, wc = w & 1;
    int col0 = blockIdx.x * 128 + wc * 64;
    int tok0 = blockIdx.y * 128 + wr * 64;
    int lr = l & 15, kg = (l >> 4) * 8;
    int rg4 = (l >> 4) * 4;
    v4f acc[4][4] = {};
    for (int ks = 0; ks < 512; ks += 32) {
        v8h a[4], b[4];
        #pragma unroll
        for (int i = 0; i < 4; ++i)
            a[i] = *(const v8h*)&A16[(size_t)(tok0 + i * 16 + lr) * 512 + ks + kg];
        #pragma unroll
        for (int j = 0; j < 4; ++j)
            b[j] = *(const v8h*)&BTh[(size_t)(col0 + j * 16 + lr) * 512 + ks + kg];
        if constexpr (MODE == 2) {
            v8h al[4], bl[4];
            #pragma unroll
            for (int i = 0; i < 4; ++i)
                al[i] = *(const v8h*)&Alo[(size_t)(tok0 + i * 16 + lr) * 512 + ks + kg];
            #pragma unroll
            for (int j = 0; j < 4; ++j)
                bl[j] = *(const v8h*)&BTl[(size_t)(col0 + j * 16 + lr) * 512 + ks + kg];
            #pragma unroll
            for (int i = 0; i < 4; ++i)
                #pragma unroll
                for (int j = 0; j < 4; ++j) {
                    acc[i][j] = MFMA(a[i], b[j], acc[i][j]);
                    acc[i][j] = MFMA(a[i], bl[j], acc[i][j]);
                    acc[i][j] = MFMA(al[i], b[j], acc[i][j]);
                }
        } else {
            #pragma unroll
            for (int i = 0; i < 4; ++i)
                #pragma unroll
                for (int j = 0; j < 4; ++j)
                    acc[i][j] = MFMA(a[i], b[j], acc[i][j]);
        }
    }
    int h = col0 >> 6;
    #pragma unroll
    for (int i = 0; i < 4; ++i)
        #pragma unroll
        for (int j = 0; j < 4; ++j)
            #pragma unroll
            for (int r = 0; r < 4; ++r) {
                int token = tok0 + i * 16 + rg4 + r;
                int d = j * 16 + lr;
                int qi = token >> 10, n = token & 1023;
                float val = acc[i][j][r];
                if constexpr (MODE != 2) {
                    fout16[((size_t)((h << 2) + qi) * 1024 + n) * 64 + d] = (f16)val;
                } else {
                    f16 hi = (f16)val;
                    fhT[((size_t)((h << 2) + qi) * 64 + d) * 1024 + n] = hi;
                    flT[((size_t)((h << 2) + qi) * 64 + d) * 1024 + n] = (f16)(val - (float)hi);
                }
            }
    if constexpr (MODE != 2) {
        #pragma unroll
        for (int i = 0; i < 4; ++i)
            #pragma unroll
            for (int r = 0; r < 4; ++r) {
                float s = 0.f, s2 = 0.f;
                #pragma unroll
                for (int j = 0; j < 4; ++j) { float v = acc[i][j][r]; s += v; s2 += v * v; }
                #pragma unroll
                for (int mk = 1; mk <= 8; mk <<= 1) {
                    s += __shfl_xor(s, mk); s2 += __shfl_xor(s2, mk);
                }
                if (lr == 0) {
                    int token = tok0 + i * 16 + rg4 + r;
                    int qi = token >> 10, n = token & 1023;
                    int row = ((h << 2) + qi) * 1024 + n;
                    float nv = sqrtf(s2);
                    oA[row] = 1.0f / (nv + 1e-6f);
                    oB[row] = 1.0f / fmaxf(nv, 1e-4f);
                    oC[row] = (MODE == 0) ? s * (1.0f / 64.0f) : s;
                }
            }
        float cs[4];
        #pragma unroll
        for (int j = 0; j < 4; ++j) {
            float c = 0.f;
            #pragma unroll
            for (int i = 0; i < 4; ++i)
                #pragma unroll
                for (int r = 0; r < 4; ++r) c += acc[i][j][r];
            c += __shfl_xor(c, 16); c += __shfl_xor(c, 32);
            cs[j] = c;
        }
        if (l < 16) {
            #pragma unroll
            for (int j = 0; j < 4; ++j)
                atomicAdd(&feat[h * 128 + (MODE == 1 ? 64 : 0) + j * 16 + l],
                          cs[j] * (1.0f / 4096.0f));
            if constexpr (MODE == 1) {
                int qi = tok0 >> 10;
                #pragma unroll
                for (int j = 0; j < 4; ++j)
                    atomicAdd(&nuacck[((h << 2) + qi) * 64 + j * 16 + l], cs[j]);
            }
        }
    }
}

__global__ __launch_bounds__(256) void k_proj_all(const f16* __restrict__ ln16,
        const f16* __restrict__ lnlo,
        const f16* __restrict__ BTh, const f16* __restrict__ BTl,
        f16* __restrict__ fq16, f16* __restrict__ fk16,
        f16* __restrict__ fvhT, f16* __restrict__ fvlT,
        float* __restrict__ rq1, float* __restrict__ rq2, float* __restrict__ muq,
        float* __restrict__ rk1, float* __restrict__ rk2, float* __restrict__ sk,
        float* __restrict__ feat, float* __restrict__ nuacck) {
    int mode = blockIdx.z;
    if (mode == 0)
        proj_body<0>(ln16, nullptr, BTh, BTl, fq16, nullptr, nullptr,
                     rq1, rq2, muq, feat, nullptr);
    else if (mode == 1)
        proj_body<1>(ln16 + 2097152u, nullptr, BTh, BTl, fk16, nullptr, nullptr,
                     rk1, rk2, sk, feat, nuacck);
    else
        proj_body<2>(ln16 + 4194304u, lnlo, BTh, BTl, nullptr, fvhT, fvlT,
                     nullptr, nullptr, nullptr, nullptr, nullptr);
}

// tiny MLP weight predictor, one block per head -> wv[h][3]
__global__ __launch_bounds__(256) void k_mlp(const float* __restrict__ feat,
        const float* __restrict__ W1, const float* __restrict__ b1,
        const float* __restrict__ lw, const float* __restrict__ lb,
        const float* __restrict__ W2, const float* __restrict__ b2,
        const float* __restrict__ W3, const float* __restrict__ b3,
        const float* __restrict__ W4, const float* __restrict__ b4,
        const float* __restrict__ wtemp, float* wv) {
    __shared__ float h1[256], h2[192], h3[64], red[8];
    int t = threadIdx.x;
    int h = blockIdx.x;
    float p = 0.0f;
    for (int i = 0; i < 128; ++i) p += feat[h * 128 + i] * W1[i * 256 + t];
    p += b1[t];
    float s = p, s2 = p * p;
    for (int o = 32; o > 0; o >>= 1) { s += __shfl_down(s, o); s2 += __shfl_down(s2, o); }
    if ((t & 63) == 0) { red[t >> 6] = s; red[4 + (t >> 6)] = s2; }
    __syncthreads();
    float S = red[0] + red[1] + red[2] + red[3];
    float S2 = red[4] + red[5] + red[6] + red[7];
    float mu = S / 256.0f;
    float var = S2 / 256.0f - mu * mu; if (var < 0.0f) var = 0.0f;
    float xh = (p - mu) * rsqrtf(var + 1e-5f) * lw[t] + lb[t];
    h1[t] = fmaxf(xh, 0.0f);
    __syncthreads();
    if (t < 192) {
        float a = 0.0f;
        for (int i = 0; i < 256; ++i) a += h1[i] * W2[i * 192 + t];
        h2[t] = fmaxf(a + b2[t], 0.0f);
    }
    __syncthreads();
    if (t < 64) {
        float a = 0.0f;
        for (int i = 0; i < 192; ++i) a += h2[i] * W3[i * 64 + t];
        h3[t] = fmaxf(a + b3[t], 0.0f);
    }
    __syncthreads();
    if (t == 0) {
        float lg[3];
        for (int j = 0; j < 3; ++j) {
            float a = 0.0f;
            for (int i = 0; i < 64; ++i) a += h3[i] * W4[i * 3 + j];
            lg[j] = a + b4[j];
        }
        float mx = fmaxf(lg[0], fmaxf(lg[1], lg[2]));
        float e0 = expf(lg[0] - mx), e1 = expf(lg[1] - mx), e2 = expf(lg[2] - mx);
        float se = e0 + e1 + e2;
        float pr0 = e0 / se, pr1 = e1 / se, pr2 = e2 / se;
        float wt = wtemp[0]; wt = fminf(fmaxf(wt, 0.01f), 1.0f);
        float q0 = pr0 / wt, q1 = pr1 / wt, q2 = pr2 / wt;
        float m2 = fmaxf(q0, fmaxf(q1, q2));
        float f0 = expf(q0 - m2), f1 = expf(q1 - m2), f2 = expf(q2 - m2);
        float sf = f0 + f1 + f2; f0 /= sf; f1 /= sf; f2 /= sf;
        f0 = fminf(fmaxf(f0, 0.01f), 0.95f);
        f1 = fminf(fmaxf(f1, 0.01f), 0.95f);
        f2 = fminf(fmaxf(f2, 0.01f), 0.95f);
        float sw = f0 + f1 + f2;
        wv[h * 3 + 0] = f0 / sw; wv[h * 3 + 1] = f1 / sw; wv[h * 3 + 2] = f2 / sw;
    }
}

// ---- shared per-pass preamble for passA: grid (16, 2, 32) ----
#define PASS_PREAMBLE_AB                                                       \
    int hq = blockIdx.z;                                                       \
    int half = blockIdx.y;                                                     \
    int m0base = half * 512;                                                   \
    int t = threadIdx.x, l = t & 63, w = t >> 6;                               \
    int lr = l & 15, kg = (l >> 4) * 8, rg4 = (l >> 4) * 4;                    \
    int nb = blockIdx.x * 64 + w * 16;                                         \
    const f16* Q = fq16 + (size_t)hq * 65536;                                  \
    const f16* K = fk16 + (size_t)hq * 65536;                                  \
    v8h aq0 = *(const v8h*)&Q[(size_t)(nb + lr) * 64 + kg];                    \
    v8h aq1 = *(const v8h*)&Q[(size_t)(nb + lr) * 64 + 32 + kg];               \
    const float inv1024 = 1.0f / 1024.0f;                                      \
    float uvp = nuacck[hq * 64 + l] * inv1024;                                 \
    _Pragma("unroll")                                                          \
    for (int o = 32; o > 0; o >>= 1) uvp += __shfl_xor(uvp, o);                \
    float uv = uvp;                                                            \
    float tp = 0.f;                                                            \
    _Pragma("unroll")                                                          \
    for (int e = 0; e < 8; ++e)                                                \
        tp += (float)aq0[e] * nuacck[hq * 64 + kg + e]                         \
            + (float)aq1[e] * nuacck[hq * 64 + 32 + kg + e];                   \
    tp *= inv1024;                                                             \
    tp += __shfl_xor(tp, 16);                                                  \
    tp += __shfl_xor(tp, 32);                                                  \
    float muv[4], tv[4];                                                       \
    _Pragma("unroll")                                                          \
    for (int r = 0; r < 4; ++r) {                                              \
        muv[r] = muq[hq * 1024 + nb + rg4 + r];                                \
        tv[r] = __shfl(tp, rg4 + r);                                           \
    }                                                                          \
    const float Acs = (0.001f / 1024.0f) / 8.0001f;                            \
    float Pr[4], Gr[4];                                                        \
    _Pragma("unroll")                                                          \
    for (int r = 0; r < 4; ++r) {                                              \
        Gr[r] = Acs * muv[r];                                                  \
        Pr[r] = Acs * fmaf(muv[r], uv, -tv[r]);                                \
    }

#define LOAD_KTILE(m0a)                                                        \
    v8h b0[4], b1[4];                                                          \
    _Pragma("unroll")                                                          \
    for (int j = 0; j < 4; ++j) {                                              \
        b0[j] = *(const v8h*)&K[(size_t)((m0a) + j * 16 + lr) * 64 + kg];      \
        b1[j] = *(const v8h*)&K[(size_t)((m0a) + j * 16 + lr) * 64 + 32 + kg]; \
    }

// pass A: cos/cov global+cross sums, per-row cos/cov sums, margin means
__global__ __launch_bounds__(256) void k_passA(const f16* __restrict__ fq16,
        const f16* __restrict__ fk16, const float* __restrict__ rq1,
        const float* __restrict__ rq2, const float* __restrict__ muq,
        const float* __restrict__ rk1, const float* __restrict__ rk2,
        const float* __restrict__ sk, const float* __restrict__ nuacck,
        float* __restrict__ vcrow, float* __restrict__ rowcos,
        float* __restrict__ rowcov, float* __restrict__ pb) {
    __shared__ float rk1s[512], rk2s[512], sks[512];
    PASS_PREAMBLE_AB
    {
        int i2 = t * 2;
        *(float2*)&rk1s[i2] = *(const float2*)&rk1[hq * 1024 + m0base + i2];
        *(float2*)&rk2s[i2] = *(const float2*)&rk2[hq * 1024 + m0base + i2];
        *(float2*)&sks[i2]  = *(const float2*)&sk[hq * 1024 + m0base + i2];
    }
    __syncthreads();
    float rq1v[4], rq2v[4];
    #pragma unroll
    for (int r = 0; r < 4; ++r) {
        rq1v[r] = rq1[hq * 1024 + nb + rg4 + r];
        rq2v[r] = rq2[hq * 1024 + nb + rg4 + r];
    }
    float scos = 0, s2cos = 0, scov = 0, s2cov = 0, sccov = 0;
    float mp[4] = {}, rcs[4] = {}, rcv[4] = {};
    #pragma unroll 2
    for (int m0 = 0; m0 < 512; m0 += 64) {
        LOAD_KTILE(m0base + m0)
        float rk1v[4], rk2v[4], skv[4];
        #pragma unroll
        for (int j = 0; j < 4; ++j) {
            int cg = m0 + j * 16 + lr;
            rk1v[j] = rk1s[cg]; rk2v[j] = rk2s[cg]; skv[j] = sks[cg];
        }
        v4f acc[4] = {};
        #pragma unroll
        for (int j = 0; j < 4; ++j) {
            acc[j] = MFMA(aq0, b0[j], acc[j]);
            acc[j] = MFMA(aq1, b1[j], acc[j]);
        }
        #pragma unroll
        for (int j = 0; j < 4; ++j)
            #pragma unroll
            for (int r = 0; r < 4; ++r) {
                float rv = acc[j][r];
                float cosv = clampf(rv * rq1v[r] * rk1v[j], -0.95f, 0.95f);
                float x2 = rv * rq2v[r] * rk2v[j];
                float marg = fmaxf(0.01f - fmaxf(x2, -0.95f), 0.0f);
                float cov = clampf(fmaf(-Gr[r], skv[j], fmaf(Acs, rv, Pr[r])),
                                   -50.0f, 50.0f);
                scos += cosv; s2cos = fmaf(cosv, cosv, s2cos);
                scov += cov;  s2cov = fmaf(cov, cov, s2cov);
                sccov = fmaf(cosv, cov, sccov);
                mp[r] += marg; rcs[r] += cosv; rcv[r] += cov;
            }
    }
    #pragma unroll
    for (int r = 0; r < 4; ++r) {
        float m_ = mp[r], c_ = rcs[r], v_ = rcv[r];
        #pragma unroll
        for (int mk = 1; mk <= 8; mk <<= 1) {
            m_ += __shfl_xor(m_, mk);
            c_ += __shfl_xor(c_, mk);
            v_ += __shfl_xor(v_, mk);
        }
        if (lr == 0) {
            int row = hq * 1024 + nb + rg4 + r;
            vcrow[half * 32768 + row] = m_ * inv1024;
            rowcos[half * 32768 + row] = c_;
            rowcov[half * 32768 + row] = v_;
        }
    }
    for (int o = 32; o > 0; o >>= 1) {
        scos += __shfl_down(scos, o); s2cos += __shfl_down(s2cos, o);
        scov += __shfl_down(scov, o); s2cov += __shfl_down(s2cov, o);
        sccov += __shfl_down(sccov, o);
    }
    __shared__ float bs[4][5];
    if (l == 0) { bs[w][0] = scos; bs[w][1] = s2cos; bs[w][2] = scov;
                  bs[w][3] = s2cov; bs[w][4] = sccov; }
    __syncthreads();
    if (t == 0) {
        int bid = (hq * 2 + half) * 16 + blockIdx.x;
        #pragma unroll
        for (int s = 0; s < 5; ++s)
            pb[bid * 6 + s] = bs[0][s] + bs[1][s] + bs[2][s] + bs[3][s];
    }
}

// fin1: per-head sums -> hs, global scal[0..2]
__global__ __launch_bounds__(256) void k_fin1(const float* __restrict__ pb,
        const float* __restrict__ vcrow, float* __restrict__ hs,
        float* __restrict__ scal) {
    __shared__ float hsl[40];
    int t = threadIdx.x;
    int hd = t >> 5, idx = t & 31;
    double a0 = 0, a1 = 0, a2 = 0, a3 = 0, a4 = 0;
    for (int i = idx; i < 128; i += 32) {
        const float* p = &pb[(hd * 128 + i) * 6];
        a0 += p[0]; a1 += p[1]; a2 += p[2]; a3 += p[3]; a4 += p[4];
    }
    for (int m = 1; m <= 16; m <<= 1) {
        a0 += __shfl_xor(a0, m); a1 += __shfl_xor(a1, m); a2 += __shfl_xor(a2, m);
        a3 += __shfl_xor(a3, m); a4 += __shfl_xor(a4, m);
    }
    if (idx == 0) {
        hsl[hd * 5 + 0] = (float)a0; hsl[hd * 5 + 1] = (float)a1;
        hsl[hd * 5 + 2] = (float)a2; hsl[hd * 5 + 3] = (float)a3;
        hsl[hd * 5 + 4] = (float)a4;
        hs[hd * 5 + 0] = (float)a0; hs[hd * 5 + 1] = (float)a1;
        hs[hd * 5 + 2] = (float)a2; hs[hd * 5 + 3] = (float)a3;
        hs[hd * 5 + 4] = (float)a4;
    }
    double s4 = 0, s5 = 0;
    for (int i = t; i < 32768; i += 256) {
        double rm = (double)(vcrow[i] + vcrow[32768 + i]);
        s4 += rm; s5 += rm * rm;
    }
    for (int o = 32; o > 0; o >>= 1) { s4 += __shfl_down(s4, o); s5 += __shfl_down(s5, o); }
    __shared__ double red[2][4];
    int wid = t >> 6, lane = t & 63;
    if (lane == 0) { red[0][wid] = s4; red[1][wid] = s5; }
    __syncthreads();
    if (t == 0) {
        double S4 = red[0][0] + red[0][1] + red[0][2] + red[0][3];
        double S5 = red[1][0] + red[1][1] + red[1][2] + red[1][3];
        double S0 = 0, S1 = 0, S2 = 0, S3 = 0;
        for (int h2 = 0; h2 < 8; ++h2) {
            S0 += hsl[h2 * 5 + 0]; S1 += hsl[h2 * 5 + 1];
            S2 += hsl[h2 * 5 + 2]; S3 += hsl[h2 * 5 + 3];
        }
        const double cnt = 33554432.0;
        scal[0] = (float)sqrt(fmax(0.0, (S1 - S0 * S0 / cnt) / (cnt - 1.0)));
        scal[1] = (float)sqrt(fmax(0.0, (S3 - S2 * S2 / cnt) / (cnt - 1.0)));
        double V4 = S4 * 1024.0, V5 = S5 * 1024.0;
        scal[2] = (float)sqrt(fmax(0.0, (V5 - V4 * V4 / cnt) / (cnt - 1.0)));
    }
}

// finrow: per-row addc cross terms -> rp[64][3]
__global__ __launch_bounds__(256) void k_finrow(const float* __restrict__ vcrow,
        const float* __restrict__ rowcos, const float* __restrict__ rowcov,
        const float* __restrict__ wv, const float* __restrict__ scal,
        float* __restrict__ rp) {
    int t = threadIdx.x;
    float s1 = scal[0] + 1e-4f, s2v = scal[1] + 1e-4f, s3 = scal[2] + 1e-4f;
    float p1 = 0, p2 = 0, p3 = 0;
    #pragma unroll
    for (int i = 0; i < 2; ++i) {
        int row = blockIdx.x * 512 + i * 256 + t;
        int h = row >> 12;
        float fc1 = wv[h * 3] / s1;
        float fc2 = wv[h * 3 + 1] * 0.3f / s2v;
        float c3 = wv[h * 3 + 2] * 0.3f / s3;
        float a = (vcrow[row] + vcrow[32768 + row]) * c3;
        float b = fc1 * (rowcos[row] + rowcos[32768 + row])
                + fc2 * (rowcov[row] + rowcov[32768 + row]);
        p1 += a; p2 = fmaf(a, a, p2); p3 = fmaf(a, b, p3);
    }
    for (int o = 32; o > 0; o >>= 1) {
        p1 += __shfl_down(p1, o); p2 += __shfl_down(p2, o); p3 += __shfl_down(p3, o);
    }
    __shared__ float red[3][4];
    int wid = t >> 6, lane = t & 63;
    if (lane == 0) { red[0][wid] = p1; red[1][wid] = p2; red[2][wid] = p3; }
    __syncthreads();
    if (t == 0) {
        rp[blockIdx.x * 3 + 0] = red[0][0] + red[0][1] + red[0][2] + red[0][3];
        rp[blockIdx.x * 3 + 1] = red[1][0] + red[1][1] + red[1][2] + red[1][3];
        rp[blockIdx.x * 3 + 2] = red[2][0] + red[2][1] + red[2][2] + red[2][3];
    }
}

// fin2: ds via decomposition -> temp
__global__ __launch_bounds__(64) void k_fin2(const float* __restrict__ rp,
        const float* __restrict__ hs, const float* __restrict__ wv,
        float* __restrict__ scal) {
    int t = threadIdx.x;
    double p1 = rp[t * 3 + 0], p2 = rp[t * 3 + 1], p3 = rp[t * 3 + 2];
    for (int o = 32; o > 0; o >>= 1) {
        p1 += __shfl_down(p1, o); p2 += __shfl_down(p2, o); p3 += __shfl_down(p3, o);
    }
    if (t == 0) {
        double s1 = (double)scal[0] + 1e-4, s2v = (double)scal[1] + 1e-4;
        double sdd = 1024.0 * p1;
        double sdd2 = 2.0 * p3 + 1024.0 * p2;
        for (int h = 0; h < 8; ++h) {
            double fc1 = (double)wv[h * 3] / s1;
            double fc2 = (double)wv[h * 3 + 1] * 0.3 / s2v;
            sdd += fc1 * hs[h * 5 + 0] + fc2 * hs[h * 5 + 2];
            sdd2 += fc1 * fc1 * hs[h * 5 + 1] + fc2 * fc2 * hs[h * 5 + 3]
                  + 2.0 * fc1 * fc2 * hs[h * 5 + 4];
        }
        const double cnt = 33554432.0;
        double ds = sqrt(fmax(0.0, (sdd2 - sdd * sdd / cnt) / (cnt - 1.0)));
        float temp = (ds < 1e-5) ? 0.01f : ((ds < 1e-3) ? 0.05f : (0.2f + (float)ds * 2.0f));
        temp = fminf(fmaxf(temp, 0.01f), 8.0f);
        scal[3] = temp;
    }
}

// ---- one 128-key double-tile flash step: sub-tile A -> Pa, B -> Pb,
// single merged max/rescale per 128 keys (halves the serial spine). ----
#define TILE2(MKA)                                                             \
    {                                                                          \
        int mkA = (MKA), mkB = (MKA) + 64;                                     \
        v8h ka0[4], ka1[4], kb0[4], kb1[4];                                    \
        _Pragma("unroll")                                                      \
        for (int j = 0; j < 4; ++j) {                                          \
            ka0[j] = *(const v8h*)&K[(size_t)(mkA + j * 16 + lr) * 64 + kg];   \
            ka1[j] = *(const v8h*)&K[(size_t)(mkA + j * 16 + lr) * 64 + 32 + kg];\
            kb0[j] = *(const v8h*)&K[(size_t)(mkB + j * 16 + lr) * 64 + kg];   \
            kb1[j] = *(const v8h*)&K[(size_t)(mkB + j * 16 + lr) * 64 + 32 + kg];\
        }                                                                      \
        float rk1A[4], skA[4], rk1B[4], skB[4];                                \
        _Pragma("unroll")                                                      \
        for (int j = 0; j < 4; ++j) {                                          \
            rk1A[j] = rk1s[mkA + j * 16 + lr]; skA[j] = sks[mkA + j * 16 + lr];\
            rk1B[j] = rk1s[mkB + j * 16 + lr]; skB[j] = sks[mkB + j * 16 + lr];\
        }                                                                      \
        v4f accA[4] = {}, accB[4] = {};                                        \
        _Pragma("unroll")                                                      \
        for (int j = 0; j < 4; ++j) {                                          \
            accA[j] = MFMA(aq0, ka0[j], accA[j]);                              \
            accA[j] = MFMA(aq1, ka1[j], accA[j]);                              \
            accB[j] = MFMA(aq0, kb0[j], accB[j]);                              \
            accB[j] = MFMA(aq1, kb1[j], accB[j]);                              \
        }                                                                      \
        float ddA[4][4], ddB[4][4];                                            \
        float tmax[4] = { -1e30f, -1e30f, -1e30f, -1e30f };                    \
        _Pragma("unroll")                                                      \
        for (int j = 0; j < 4; ++j)                                            \
            _Pragma("unroll")                                                  \
            for (int r = 0; r < 4; ++r) {                                      \
                float rvA = accA[j][r];                                        \
                float cosA = clampf(rvA * rq1v[r] * rk1A[j], -0.95f, 0.95f);   \
                float covA = clampf(fmaf(-Gcr[r], skA[j],                      \
                                         fmaf(Acs, rvA, Pcr[r])), -50.f, 50.f);\
                float dA = fmaf(fc2, covA, fmaf(fc1, cosA, addc[r]));          \
                ddA[j][r] = dA;                                                \
                float rvB = accB[j][r];                                        \
                float cosB = clampf(rvB * rq1v[r] * rk1B[j], -0.95f, 0.95f);   \
                float covB = clampf(fmaf(-Gcr[r], skB[j],                      \
                                         fmaf(Acs, rvB, Pcr[r])), -50.f, 50.f);\
                float dB = fmaf(fc2, covB, fmaf(fc1, cosB, addc[r]));          \
                ddB[j][r] = dB;                                                \
                tmax[r] = fmaxf(tmax[r], fmaxf(dA, dB));                       \
            }                                                                  \
        v4f fv;                                                                \
        _Pragma("unroll")                                                      \
        for (int r = 0; r < 4; ++r) {                                          \
            float tm = tmax[r];                                                \
            tm = fmaxf(tm, __shfl_xor(tm, 1));                                 \
            tm = fmaxf(tm, __shfl_xor(tm, 2));                                 \
            tm = fmaxf(tm, __shfl_xor(tm, 4));                                 \
            tm = fmaxf(tm, __shfl_xor(tm, 8));                                 \
            float mnew = fmaxf(mrun[r], tm);                                   \
            float fr_ = __expf((mrun[r] - mnew) * invt);                       \
            mrun[r] = mnew;                                                    \
            rsacc[r] *= fr_;                                                   \
            fv[r] = fr_;                                                       \
        }                                                                      \
        _Pragma("unroll")                                                      \
        for (int j = 0; j < 4; ++j) accpv[j] *= fv;                            \
        _Pragma("unroll")                                                      \
        for (int j = 0; j < 4; ++j)                                            \
            _Pragma("unroll")                                                  \
            for (int r = 0; r < 4; ++r) {                                      \
                float peA = __expf((ddA[j][r] - mrun[r]) * invt);              \
                f16 pA = (f16)peA;                                             \
                rsacc[r] += (float)pA;                                         \
                Pa[(w * 16 + rg4 + r) * 72 + j * 16 + lr] = pA;                \
                float peB = __expf((ddB[j][r] - mrun[r]) * invt);              \
                f16 pB = (f16)peB;                                             \
                rsacc[r] += (float)pB;                                         \
                Pb[(w * 16 + rg4 + r) * 72 + j * 16 + lr] = pB;                \
            }                                                                  \
        v8h paA0 = *(const v8h*)&Pa[(w * 16 + lr) * 72 + kg];                  \
        v8h paA1 = *(const v8h*)&Pa[(w * 16 + lr) * 72 + 32 + kg];             \
        v8h paB0 = *(const v8h*)&Pb[(w * 16 + lr) * 72 + kg];                  \
        v8h paB1 = *(const v8h*)&Pb[(w * 16 + lr) * 72 + 32 + kg];             \
        _Pragma("unroll")                                                      \
        for (int j = 0; j < 4; ++j) {                                          \
            size_t vbA = ((size_t)hq * 64 + j * 16 + lr) * 1024 + mkA;         \
            size_t vbB = vbA + 64;                                             \
            v8h vhA0 = *(const v8h*)&fvhT[vbA + kg];                           \
            v8h vhA1 = *(const v8h*)&fvhT[vbA + 32 + kg];                      \
            v8h vlA0 = *(const v8h*)&fvlT[vbA + kg];                           \
            v8h vlA1 = *(const v8h*)&fvlT[vbA + 32 + kg];                      \
            v8h vhB0 = *(const v8h*)&fvhT[vbB + kg];                           \
            v8h vhB1 = *(const v8h*)&fvhT[vbB + 32 + kg];                      \
            v8h vlB0 = *(const v8h*)&fvlT[vbB + kg];                           \
            v8h vlB1 = *(const v8h*)&fvlT[vbB + 32 + kg];                      \
            accpv[j] = MFMA(paA0, vhA0, accpv[j]);                             \
            accpv[j] = MFMA(paA1, vhA1, accpv[j]);                             \
            accpv[j] = MFMA(paA0, vlA0, accpv[j]);                             \
            accpv[j] = MFMA(paA1, vlA1, accpv[j]);                             \
            accpv[j] = MFMA(paB0, vhB0, accpv[j]);                             \
            accpv[j] = MFMA(paB1, vhB1, accpv[j]);                             \
            accpv[j] = MFMA(paB0, vlB0, accpv[j]);                             \
            accpv[j] = MFMA(paB1, vlB1, accpv[j]);                             \
        }                                                                      \
    }

// pass C: recompute QK^T -> dots -> ONLINE softmax (128-key steps) -> PV -> av.
// 512 threads = 4 row-groups x 2 K-halves; flash combine in overlaid LDS.
__global__ __launch_bounds__(512) void k_passC(const f16* __restrict__ fq16,
        const f16* __restrict__ fk16, const float* __restrict__ rq1,
        const float* __restrict__ muq, const float* __restrict__ rk1,
        const float* __restrict__ sk, const float* __restrict__ nuacck,
        const float* __restrict__ vcrow, const float* __restrict__ wv,
        const float* __restrict__ scal,
        const f16* __restrict__ fvhT, const f16* __restrict__ fvlT,
        f16* __restrict__ avh, f16* __restrict__ avl) {
    __shared__ __align__(16) char arena[36864];   // Pa(18432) + Pb(18432); combine overlays
    __shared__ float rk1s[1024], sks[1024];
    f16* Pa = (f16*)arena;
    f16* Pb = (f16*)(arena + 18432);
    int hq = blockIdx.y;
    int t = threadIdx.x, l = t & 63, w = t >> 6;
    int rg = w & 3, kh = w >> 2;
    int lr = l & 15, kg = (l >> 4) * 8, rg4 = (l >> 4) * 4;
    int nb = blockIdx.x * 64 + rg * 16;
    int m0base = kh * 512;
    const f16* Q = fq16 + (size_t)hq * 65536;
    const f16* K = fk16 + (size_t)hq * 65536;
    {
        int i2 = t * 2;
        *(float2*)&rk1s[i2] = *(const float2*)&rk1[hq * 1024 + i2];
        *(float2*)&sks[i2]  = *(const float2*)&sk[hq * 1024 + i2];
    }
    __syncthreads();
    v8h aq0 = *(const v8h*)&Q[(size_t)(nb + lr) * 64 + kg];
    v8h aq1 = *(const v8h*)&Q[(size_t)(nb + lr) * 64 + 32 + kg];
    const float inv1024 = 1.0f / 1024.0f;
    float uvp = nuacck[hq * 64 + l] * inv1024;
    #pragma unroll
    for (int o = 32; o > 0; o >>= 1) uvp += __shfl_xor(uvp, o);
    float uv = uvp;
    float tpv = 0.f;
    #pragma unroll
    for (int e = 0; e < 8; ++e)
        tpv += (float)aq0[e] * nuacck[hq * 64 + kg + e]
             + (float)aq1[e] * nuacck[hq * 64 + 32 + kg + e];
    tpv *= inv1024;
    tpv += __shfl_xor(tpv, 16);
    tpv += __shfl_xor(tpv, 32);
    float muv[4], tv[4];
    #pragma unroll
    for (int r = 0; r < 4; ++r) {
        muv[r] = muq[hq * 1024 + nb + rg4 + r];
        tv[r] = __shfl(tpv, rg4 + r);
    }
    const float Acs = (0.001f / 1024.0f) / 8.0001f;
    float Pcr[4], Gcr[4];
    #pragma unroll
    for (int r = 0; r < 4; ++r) {
        Gcr[r] = Acs * muv[r];
        Pcr[r] = Acs * fmaf(muv[r], uv, -tv[r]);
    }
    int h = hq >> 2;
    float s1 = scal[0] + 1e-4f, s2v = scal[1] + 1e-4f, s3 = scal[2] + 1e-4f;
    float fc1 = wv[h * 3] / s1;
    float fc2 = wv[h * 3 + 1] * 0.3f / s2v;
    float c3 = wv[h * 3 + 2] * 0.3f / s3;
    float invt = 1.0f / scal[3];
    float rq1v[4], addc[4];
    #pragma unroll
    for (int r = 0; r < 4; ++r) {
        int row = hq * 1024 + nb + rg4 + r;
        rq1v[r] = rq1[row];
        addc[r] = (vcrow[row] + vcrow[32768 + row]) * c3;
    }
    v4f accpv[4] = {};
    float rsacc[4] = {};
    float mrun[4] = { -1e30f, -1e30f, -1e30f, -1e30f };
    for (int it = 0; it < 4; ++it) {
        TILE2(m0base + it * 128)
    }
    __syncthreads();   // all Pa/Pb uses complete before combine overlay reuse
    #pragma unroll
    for (int r = 0; r < 4; ++r) {
        float s = rsacc[r];
        s += __shfl_xor(s, 1); s += __shfl_xor(s, 2);
        s += __shfl_xor(s, 4); s += __shfl_xor(s, 8);
        rsacc[r] = s;
    }
    float* cbacc = (float*)arena;            // [4][16][64] = 16384 B
    float* cbrs  = (float*)(arena + 16384);  // [4][4][64]  = 4096 B
    float* cbm   = (float*)(arena + 20480);  // [4][16]     = 256 B
    if (kh == 1) {
        #pragma unroll
        for (int j = 0; j < 4; ++j)
            #pragma unroll
            for (int r = 0; r < 4; ++r)
                cbacc[(rg * 16 + j * 4 + r) * 64 + l] = accpv[j][r];
        #pragma unroll
        for (int r = 0; r < 4; ++r) cbrs[(rg * 4 + r) * 64 + l] = rsacc[r];
        if (lr == 0) {
            #pragma unroll
            for (int r = 0; r < 4; ++r) cbm[rg * 16 + rg4 + r] = mrun[r];
        }
    }
    __syncthreads();
    if (kh == 0) {
        v4f f0v, f1v;
        float rinv[4];
        #pragma unroll
        for (int r = 0; r < 4; ++r) {
            float m1 = cbm[rg * 16 + rg4 + r];
            float mf = fmaxf(mrun[r], m1);
            float f0 = __expf((mrun[r] - mf) * invt);
            float f1 = __expf((m1 - mf) * invt);
            f0v[r] = f0; f1v[r] = f1;
            float rst = rsacc[r] * f0 + cbrs[(rg * 4 + r) * 64 + l] * f1;
            rinv[r] = 1.0f / rst;
        }
        #pragma unroll
        for (int j = 0; j < 4; ++j)
            #pragma unroll
            for (int r = 0; r < 4; ++r) {
                float val = (accpv[j][r] * f0v[r]
                           + cbacc[(rg * 16 + j * 4 + r) * 64 + l] * f1v[r]) * rinv[r];
                size_t idx = ((size_t)(hq * 1024 + nb + rg4 + r)) * 64 + j * 16 + lr;
                f16 hi = (f16)val;
                avh[idx] = hi;
                avl[idx] = (f16)(val - (float)hi);
            }
    }
}

// out = av @ Wout + bout (MFMA, 3-way split)
__global__ __launch_bounds__(256) void k_out_mfma(const f16* __restrict__ avh,
        const f16* __restrict__ avl,
        const f16* __restrict__ WoutTh, const f16* __restrict__ WoutTl,
        const float* __restrict__ bout, float* __restrict__ out) {
    __shared__ float red[2][4][4][4][64];
    int t = threadIdx.x, l = t & 63, w = t >> 6;
    int wc = w & 1, kh = w >> 1;
    int col0 = blockIdx.x * 128 + wc * 64;
    int tok0 = blockIdx.y * 64;
    int qi = tok0 >> 10, nb = tok0 & 1023;
    int lr = l & 15, kg = (l >> 4) * 8;
    v4f acc[4][4] = {};
    for (int ks8 = 0; ks8 < 8; ++ks8) {
        int ks = kh * 256 + ks8 * 32;
        int f = ks + kg;
        int h = f >> 6, d = f & 63;
        size_t hb = (size_t)((h << 2) + qi) * 1024;
        v8h ah[4], al4[4], bh[4], bl4[4];
        #pragma unroll
        for (int i = 0; i < 4; ++i) {
            int n = nb + i * 16 + lr;
            ah[i]  = *(const v8h*)&avh[(hb + n) * 64 + d];
            al4[i] = *(const v8h*)&avl[(hb + n) * 64 + d];
        }
        #pragma unroll
        for (int j = 0; j < 4; ++j) {
            bh[j]  = *(const v8h*)&WoutTh[(size_t)(col0 + j * 16 + lr) * 512 + ks + kg];
            bl4[j] = *(const v8h*)&WoutTl[(size_t)(col0 + j * 16 + lr) * 512 + ks + kg];
        }
        #pragma unroll
        for (int i = 0; i < 4; ++i)
            #pragma unroll
            for (int j = 0; j < 4; ++j) {
                acc[i][j] = MFMA(ah[i], bh[j], acc[i][j]);
                acc[i][j] = MFMA(ah[i], bl4[j], acc[i][j]);
                acc[i][j] = MFMA(al4[i], bh[j], acc[i][j]);
            }
    }
    if (kh == 0) {
        #pragma unroll
        for (int i = 0; i < 4; ++i)
            #pragma unroll
            for (int j = 0; j < 4; ++j)
                #pragma unroll
                for (int r = 0; r < 4; ++r)
                    red[wc][i][j][r][l] = acc[i][j][r];
    }
    __syncthreads();
    if (kh == 1) {
        #pragma unroll
        for (int i = 0; i < 4; ++i)
            #pragma unroll
            for (int j = 0; j < 4; ++j) {
                int col = col0 + j * 16 + lr;
                float bo = bout[col];
                #pragma unroll
                for (int r = 0; r < 4; ++r) {
                    float val = acc[i][j][r] + red[wc][i][j][r][l] + bo;
                    int token = tok0 + i * 16 + (l >> 4) * 4 + r;
                    out[(size_t)token * 512 + col] = val;
                }
            }
    }
}

extern "C" void kernel_launch(void* const* d_in, const int* in_sizes, int n_in,
                              void* d_out, int out_size, void* d_ws, size_t ws_size,
                              hipStream_t stream) {
    const float* q     = (const float*)d_in[0];
    const float* k     = (const float*)d_in[1];
    const float* v     = (const float*)d_in[2];
    const float* ln_w  = (const float*)d_in[3];
    const float* ln_b  = (const float*)d_in[4];
    const float* W_in  = (const float*)d_in[5];
    const float* W_out = (const float*)d_in[6];
    const float* b_out = (const float*)d_in[7];
    const float* wp_W1 = (const float*)d_in[8];
    const float* wp_b1 = (const float*)d_in[9];
    const float* wp_lw = (const float*)d_in[10];
    const float* wp_lb = (const float*)d_in[11];
    const float* wp_W2 = (const float*)d_in[12];
    const float* wp_b2 = (const float*)d_in[13];
    const float* wp_W3 = (const float*)d_in[14];
    const float* wp_b3 = (const float*)d_in[15];
    const float* wp_W4 = (const float*)d_in[16];
    const float* wp_b4 = (const float*)d_in[17];
    const float* wtemp = (const float*)d_in[18];

    float* ws = (float*)d_ws;
    f16* ln16     = (f16*)(ws + OFF_LN16);
    f16* lnlo     = (f16*)(ws + OFF_LNLO);
    f16* fq16     = (f16*)(ws + OFF_FQ16);
    f16* fk16     = (f16*)(ws + OFF_FK16);
    f16* fvhT     = (f16*)(ws + OFF_FVHT);
    f16* fvlT     = (f16*)(ws + OFF_FVLT);
    f16* WinTh    = (f16*)(ws + OFF_WINTH);
    f16* WinTl    = (f16*)(ws + OFF_WINTL);
    f16* WoutTh   = (f16*)(ws + OFF_WOUTTH);
    f16* WoutTl   = (f16*)(ws + OFF_WOUTTL);
    f16* avh      = (f16*)(ws + OFF_AVH);
    f16* avl      = (f16*)(ws + OFF_AVL);
    float* rq1    = ws + OFF_RQ1;
    float* rq2    = ws + OFF_RQ2;
    float* muq    = ws + OFF_MUQ;
    float* rk1    = ws + OFF_RK1;
    float* rk2    = ws + OFF_RK2;
    float* sk     = ws + OFF_SK;
    float* vcrow  = ws + OFF_VC;
    float* rowcos = ws + OFF_ROWCOS;
    float* rowcov = ws + OFF_ROWCOV;
    float* nuacck = ws + OFF_NUACC;
    float* pb     = ws + OFF_PB;
    float* hs     = ws + OFF_HS;
    float* rp     = ws + OFF_RP;
    float* feat   = ws + OFF_FEAT;
    float* wv     = ws + OFF_WV;
    float* scal   = ws + OFF_SCAL;

    k_zero<<<8, 256, 0, stream>>>(feat, nuacck);
    k_wprep<<<dim3(8, 8, 2), 256, 0, stream>>>(W_in, W_out, WinTh, WinTl, WoutTh, WoutTl);
    k_ln16<<<3072, 256, 0, stream>>>(q, k, v, ln_w, ln_b, ln16, lnlo);
    k_proj_all<<<dim3(4, 32, 3), 256, 0, stream>>>(ln16, lnlo, WinTh, WinTl,
            fq16, fk16, fvhT, fvlT, rq1, rq2, muq, rk1, rk2, sk, feat, nuacck);
    k_mlp<<<8, 256, 0, stream>>>(feat, wp_W1, wp_b1, wp_lw, wp_lb,
                                 wp_W2, wp_b2, wp_W3, wp_b3, wp_W4, wp_b4,
                                 wtemp, wv);
    k_passA<<<dim3(16, 2, 32), 256, 0, stream>>>(fq16, fk16, rq1, rq2, muq, rk1, rk2,
                                                 sk, nuacck, vcrow, rowcos, rowcov, pb);
    k_fin1<<<1, 256, 0, stream>>>(pb, vcrow, hs, scal);
    k_finrow<<<64, 256, 0, stream>>>(vcrow, rowcos, rowcov, wv, scal, rp);
    k_fin2<<<1, 64, 0, stream>>>(rp, hs, wv, scal);
    k_passC<<<dim3(16, 32), 512, 0, stream>>>(fq16, fk16, rq1, muq, rk1, sk, nuacck,
                                              vcrow, wv, scal, fvhT, fvlT, avh, avl);
    k_out_mfma<<<dim3(4, 64), 256, 0, stream>>>(avh, avl, WoutTh, WoutTl, b_out,
                                                (float*)d_out);
}

// Round 14
// 279.781 us; speedup vs baseline: 1.0775x; 1.0775x over previous
//
#include <hip/hip_runtime.h>
#include <math.h>

typedef _Float16 f16;
typedef _Float16 v8h __attribute__((ext_vector_type(8)));
typedef _Float16 v4h __attribute__((ext_vector_type(4)));
typedef float    v4f __attribute__((ext_vector_type(4)));

#define MFMA(a, b, c) __builtin_amdgcn_mfma_f32_16x16x32_f16((a), (b), (c), 0, 0, 0)

// ---------------- workspace layout (float offsets) ----------------
#define OFF_LN16    0u
#define OFF_LNLO    3145728u
#define OFF_FQ16    4194304u
#define OFF_FK16    5242880u
#define OFF_FVHT    6291456u
#define OFF_FVLT    7340032u
#define OFF_WINTH   8388608u
#define OFF_WINTL   8519680u
#define OFF_WOUTTH  8650752u
#define OFF_WOUTTL  8781824u
#define OFF_AVH     8912896u
#define OFF_AVL     9961472u
#define OFF_RQ1     11010048u
#define OFF_RQ2     11042816u
#define OFF_MUQ     11075584u
#define OFF_RK1     11108352u
#define OFF_RK2     11141120u
#define OFF_SK      11173888u
#define OFF_VC      11206656u   // 65536 (2 halves)
#define OFF_ROWCOS  11272192u   // 2 halves
#define OFF_ROWCOV  11337728u   // 2 halves
#define OFF_NUACC   11403264u   // 2048
#define OFF_PB      11405312u   // 1024*6
#define OFF_HS      11411456u   // 64
#define OFF_RP      11411520u   // 192
#define OFF_FEAT    11411712u   // 1024
#define OFF_WV      11412736u   // 24
#define OFF_SCAL    11412760u   // 8

__device__ __forceinline__ float clampf(float x, float lo, float hi) {
    return fminf(fmaxf(x, lo), hi);
}

__global__ void k_zero(float* feat, float* nuacck) {
    int i = blockIdx.x * 256 + threadIdx.x;
    if (i < 1024) feat[i] = 0.0f;
    if (i < 2048) nuacck[i] = 0.0f;
}

// transpose + hi/lo split of a 512x512 weight: W[k][c] -> WT{h,l}[c][k]
__global__ __launch_bounds__(256) void k_wprep(const float* __restrict__ Win,
        const float* __restrict__ Wout, f16* __restrict__ WinTh, f16* __restrict__ WinTl,
        f16* __restrict__ WoutTh, f16* __restrict__ WoutTl) {
    __shared__ float lds[64][68];
    const float* W = blockIdx.z ? Wout : Win;
    f16* Th = blockIdx.z ? WoutTh : WinTh;
    f16* Tl = blockIdx.z ? WoutTl : WinTl;
    int k0 = blockIdx.y * 64, c0 = blockIdx.x * 64;
    int t = threadIdx.x;
    #pragma unroll
    for (int p = 0; p < 4; ++p) {
        int flat = p * 1024 + t * 4;
        int r = flat >> 6, c = flat & 63;
        *(float4*)&lds[r][c] = *(const float4*)&W[(size_t)(k0 + r) * 512 + c0 + c];
    }
    __syncthreads();
    int c = t >> 2, kk = (t & 3) * 16;
    #pragma unroll
    for (int half = 0; half < 2; ++half) {
        v8h h8, l8;
        #pragma unroll
        for (int ii = 0; ii < 8; ++ii) {
            float v = lds[kk + half * 8 + ii][c];
            f16 h = (f16)v;
            h8[ii] = h;
            l8[ii] = (f16)(v - (float)h);
        }
        *(v8h*)&Th[(size_t)(c0 + c) * 512 + k0 + kk + half * 8] = h8;
        *(v8h*)&Tl[(size_t)(c0 + c) * 512 + k0 + kk + half * 8] = l8;
    }
}

// LayerNorm all 12288 tokens -> ln16 f16; v tokens also get lo residual
__global__ __launch_bounds__(256) void k_ln16(const float* __restrict__ q,
        const float* __restrict__ kk, const float* __restrict__ v,
        const float* __restrict__ lnw, const float* __restrict__ lnb,
        f16* __restrict__ ln16, f16* __restrict__ lnlo) {
    int t = threadIdx.x, wid = t >> 6, lane = t & 63;
    int token = blockIdx.x * 4 + wid;
    int inp = token >> 12, lt = token & 4095;
    const float* xp = (inp == 0) ? q : ((inp == 1) ? kk : v);
    const float4* xr = (const float4*)(xp + (size_t)lt * 512);
    float4 a = xr[lane], b = xr[lane + 64];
    float s = a.x + a.y + a.z + a.w + b.x + b.y + b.z + b.w;
    float s2 = a.x*a.x + a.y*a.y + a.z*a.z + a.w*a.w
             + b.x*b.x + b.y*b.y + b.z*b.z + b.w*b.w;
    for (int o = 32; o > 0; o >>= 1) { s += __shfl_down(s, o); s2 += __shfl_down(s2, o); }
    float m_ = __shfl(s, 0) * (1.0f / 512.0f);
    float var = __shfl(s2, 0) * (1.0f / 512.0f) - m_ * m_;
    var = fmaxf(var, 0.0f);
    float rs = rsqrtf(var + 1e-5f);
    const float4* w4 = (const float4*)lnw;
    const float4* b4 = (const float4*)lnb;
    float4 wa = w4[lane], wb = w4[lane + 64], ba = b4[lane], bb = b4[lane + 64];
    float ga[4] = { (a.x - m_) * rs * wa.x + ba.x, (a.y - m_) * rs * wa.y + ba.y,
                    (a.z - m_) * rs * wa.z + ba.z, (a.w - m_) * rs * wa.w + ba.w };
    float gb[4] = { (b.x - m_) * rs * wb.x + bb.x, (b.y - m_) * rs * wb.y + bb.y,
                    (b.z - m_) * rs * wb.z + bb.z, (b.w - m_) * rs * wb.w + bb.w };
    f16* orow = ln16 + (size_t)token * 512;
    v4h ha, hb;
    #pragma unroll
    for (int i = 0; i < 4; ++i) { ha[i] = (f16)ga[i]; hb[i] = (f16)gb[i]; }
    *(v4h*)&orow[lane * 4] = ha;
    *(v4h*)&orow[lane * 4 + 256] = hb;
    if (inp == 2) {
        f16* lrow = lnlo + (size_t)lt * 512;
        v4h la, lb;
        #pragma unroll
        for (int i = 0; i < 4; ++i) {
            la[i] = (f16)(ga[i] - (float)ha[i]);
            lb[i] = (f16)(gb[i] - (float)hb[i]);
        }
        *(v4h*)&lrow[lane * 4] = la;
        *(v4h*)&lrow[lane * 4 + 256] = lb;
    }
}

// LN16 @ Win (MFMA). MODE 0: q (fq16 + recip stats). MODE 1: k. MODE 2: v
// (hi only, transposed write; lo residual no longer consumed downstream).
template<int MODE>
__device__ __forceinline__ void proj_body(const f16* __restrict__ A16,
        const f16* __restrict__ Alo,
        const f16* __restrict__ BTh, const f16* __restrict__ BTl,
        f16* __restrict__ fout16, f16* __restrict__ fhT,
        float* __restrict__ oA, float* __restrict__ oB, float* __restrict__ oC,
        float* __restrict__ feat, float* __restrict__ nuacck) {
    int t = threadIdx.x, l = t & 63, w = t >> 6;
    int wr = w >> 1, wc = w & 1;
    int col0 = blockIdx.x * 128 + wc * 64;
    int tok0 = blockIdx.y * 128 + wr * 64;
    int lr = l & 15, kg = (l >> 4) * 8;
    int rg4 = (l >> 4) * 4;
    v4f acc[4][4] = {};
    for (int ks = 0; ks < 512; ks += 32) {
        v8h a[4], b[4];
        #pragma unroll
        for (int i = 0; i < 4; ++i)
            a[i] = *(const v8h*)&A16[(size_t)(tok0 + i * 16 + lr) * 512 + ks + kg];
        #pragma unroll
        for (int j = 0; j < 4; ++j)
            b[j] = *(const v8h*)&BTh[(size_t)(col0 + j * 16 + lr) * 512 + ks + kg];
        if constexpr (MODE == 2) {
            v8h al[4], bl[4];
            #pragma unroll
            for (int i = 0; i < 4; ++i)
                al[i] = *(const v8h*)&Alo[(size_t)(tok0 + i * 16 + lr) * 512 + ks + kg];
            #pragma unroll
            for (int j = 0; j < 4; ++j)
                bl[j] = *(const v8h*)&BTl[(size_t)(col0 + j * 16 + lr) * 512 + ks + kg];
            #pragma unroll
            for (int i = 0; i < 4; ++i)
                #pragma unroll
                for (int j = 0; j < 4; ++j) {
                    acc[i][j] = MFMA(a[i], b[j], acc[i][j]);
                    acc[i][j] = MFMA(a[i], bl[j], acc[i][j]);
                    acc[i][j] = MFMA(al[i], b[j], acc[i][j]);
                }
        } else {
            #pragma unroll
            for (int i = 0; i < 4; ++i)
                #pragma unroll
                for (int j = 0; j < 4; ++j)
                    acc[i][j] = MFMA(a[i], b[j], acc[i][j]);
        }
    }
    int h = col0 >> 6;
    #pragma unroll
    for (int i = 0; i < 4; ++i)
        #pragma unroll
        for (int j = 0; j < 4; ++j)
            #pragma unroll
            for (int r = 0; r < 4; ++r) {
                int token = tok0 + i * 16 + rg4 + r;
                int d = j * 16 + lr;
                int qi = token >> 10, n = token & 1023;
                float val = acc[i][j][r];
                if constexpr (MODE != 2) {
                    fout16[((size_t)((h << 2) + qi) * 1024 + n) * 64 + d] = (f16)val;
                } else {
                    fhT[((size_t)((h << 2) + qi) * 64 + d) * 1024 + n] = (f16)val;
                }
            }
    if constexpr (MODE != 2) {
        #pragma unroll
        for (int i = 0; i < 4; ++i)
            #pragma unroll
            for (int r = 0; r < 4; ++r) {
                float s = 0.f, s2 = 0.f;
                #pragma unroll
                for (int j = 0; j < 4; ++j) { float v = acc[i][j][r]; s += v; s2 += v * v; }
                #pragma unroll
                for (int mk = 1; mk <= 8; mk <<= 1) {
                    s += __shfl_xor(s, mk); s2 += __shfl_xor(s2, mk);
                }
                if (lr == 0) {
                    int token = tok0 + i * 16 + rg4 + r;
                    int qi = token >> 10, n = token & 1023;
                    int row = ((h << 2) + qi) * 1024 + n;
                    float nv = sqrtf(s2);
                    oA[row] = 1.0f / (nv + 1e-6f);
                    oB[row] = 1.0f / fmaxf(nv, 1e-4f);
                    oC[row] = (MODE == 0) ? s * (1.0f / 64.0f) : s;
                }
            }
        float cs[4];
        #pragma unroll
        for (int j = 0; j < 4; ++j) {
            float c = 0.f;
            #pragma unroll
            for (int i = 0; i < 4; ++i)
                #pragma unroll
                for (int r = 0; r < 4; ++r) c += acc[i][j][r];
            c += __shfl_xor(c, 16); c += __shfl_xor(c, 32);
            cs[j] = c;
        }
        if (l < 16) {
            #pragma unroll
            for (int j = 0; j < 4; ++j)
                atomicAdd(&feat[h * 128 + (MODE == 1 ? 64 : 0) + j * 16 + l],
                          cs[j] * (1.0f / 4096.0f));
            if constexpr (MODE == 1) {
                int qi = tok0 >> 10;
                #pragma unroll
                for (int j = 0; j < 4; ++j)
                    atomicAdd(&nuacck[((h << 2) + qi) * 64 + j * 16 + l], cs[j]);
            }
        }
    }
}

__global__ __launch_bounds__(256) void k_proj_all(const f16* __restrict__ ln16,
        const f16* __restrict__ lnlo,
        const f16* __restrict__ BTh, const f16* __restrict__ BTl,
        f16* __restrict__ fq16, f16* __restrict__ fk16,
        f16* __restrict__ fvhT,
        float* __restrict__ rq1, float* __restrict__ rq2, float* __restrict__ muq,
        float* __restrict__ rk1, float* __restrict__ rk2, float* __restrict__ sk,
        float* __restrict__ feat, float* __restrict__ nuacck) {
    int mode = blockIdx.z;
    if (mode == 0)
        proj_body<0>(ln16, nullptr, BTh, BTl, fq16, nullptr,
                     rq1, rq2, muq, feat, nullptr);
    else if (mode == 1)
        proj_body<1>(ln16 + 2097152u, nullptr, BTh, BTl, fk16, nullptr,
                     rk1, rk2, sk, feat, nuacck);
    else
        proj_body<2>(ln16 + 4194304u, lnlo, BTh, BTl, nullptr, fvhT,
                     nullptr, nullptr, nullptr, nullptr, nullptr);
}

// tiny MLP weight predictor, one block per head -> wv[h][3]
__global__ __launch_bounds__(256) void k_mlp(const float* __restrict__ feat,
        const float* __restrict__ W1, const float* __restrict__ b1,
        const float* __restrict__ lw, const float* __restrict__ lb,
        const float* __restrict__ W2, const float* __restrict__ b2,
        const float* __restrict__ W3, const float* __restrict__ b3,
        const float* __restrict__ W4, const float* __restrict__ b4,
        const float* __restrict__ wtemp, float* wv) {
    __shared__ float h1[256], h2[192], h3[64], red[8];
    int t = threadIdx.x;
    int h = blockIdx.x;
    float p = 0.0f;
    for (int i = 0; i < 128; ++i) p += feat[h * 128 + i] * W1[i * 256 + t];
    p += b1[t];
    float s = p, s2 = p * p;
    for (int o = 32; o > 0; o >>= 1) { s += __shfl_down(s, o); s2 += __shfl_down(s2, o); }
    if ((t & 63) == 0) { red[t >> 6] = s; red[4 + (t >> 6)] = s2; }
    __syncthreads();
    float S = red[0] + red[1] + red[2] + red[3];
    float S2 = red[4] + red[5] + red[6] + red[7];
    float mu = S / 256.0f;
    float var = S2 / 256.0f - mu * mu; if (var < 0.0f) var = 0.0f;
    float xh = (p - mu) * rsqrtf(var + 1e-5f) * lw[t] + lb[t];
    h1[t] = fmaxf(xh, 0.0f);
    __syncthreads();
    if (t < 192) {
        float a = 0.0f;
        for (int i = 0; i < 256; ++i) a += h1[i] * W2[i * 192 + t];
        h2[t] = fmaxf(a + b2[t], 0.0f);
    }
    __syncthreads();
    if (t < 64) {
        float a = 0.0f;
        for (int i = 0; i < 192; ++i) a += h2[i] * W3[i * 64 + t];
        h3[t] = fmaxf(a + b3[t], 0.0f);
    }
    __syncthreads();
    if (t == 0) {
        float lg[3];
        for (int j = 0; j < 3; ++j) {
            float a = 0.0f;
            for (int i = 0; i < 64; ++i) a += h3[i] * W4[i * 3 + j];
            lg[j] = a + b4[j];
        }
        float mx = fmaxf(lg[0], fmaxf(lg[1], lg[2]));
        float e0 = expf(lg[0] - mx), e1 = expf(lg[1] - mx), e2 = expf(lg[2] - mx);
        float se = e0 + e1 + e2;
        float pr0 = e0 / se, pr1 = e1 / se, pr2 = e2 / se;
        float wt = wtemp[0]; wt = fminf(fmaxf(wt, 0.01f), 1.0f);
        float q0 = pr0 / wt, q1 = pr1 / wt, q2 = pr2 / wt;
        float m2 = fmaxf(q0, fmaxf(q1, q2));
        float f0 = expf(q0 - m2), f1 = expf(q1 - m2), f2 = expf(q2 - m2);
        float sf = f0 + f1 + f2; f0 /= sf; f1 /= sf; f2 /= sf;
        f0 = fminf(fmaxf(f0, 0.01f), 0.95f);
        f1 = fminf(fmaxf(f1, 0.01f), 0.95f);
        f2 = fminf(fmaxf(f2, 0.01f), 0.95f);
        float sw = f0 + f1 + f2;
        wv[h * 3 + 0] = f0 / sw; wv[h * 3 + 1] = f1 / sw; wv[h * 3 + 2] = f2 / sw;
    }
}

// ---- shared per-pass preamble for passA: grid (16, 2, 32) ----
#define PASS_PREAMBLE_AB                                                       \
    int hq = blockIdx.z;                                                       \
    int half = blockIdx.y;                                                     \
    int m0base = half * 512;                                                   \
    int t = threadIdx.x, l = t & 63, w = t >> 6;                               \
    int lr = l & 15, kg = (l >> 4) * 8, rg4 = (l >> 4) * 4;                    \
    int nb = blockIdx.x * 64 + w * 16;                                         \
    const f16* Q = fq16 + (size_t)hq * 65536;                                  \
    const f16* K = fk16 + (size_t)hq * 65536;                                  \
    v8h aq0 = *(const v8h*)&Q[(size_t)(nb + lr) * 64 + kg];                    \
    v8h aq1 = *(const v8h*)&Q[(size_t)(nb + lr) * 64 + 32 + kg];               \
    const float inv1024 = 1.0f / 1024.0f;                                      \
    float uvp = nuacck[hq * 64 + l] * inv1024;                                 \
    _Pragma("unroll")                                                          \
    for (int o = 32; o > 0; o >>= 1) uvp += __shfl_xor(uvp, o);                \
    float uv = uvp;                                                            \
    float tp = 0.f;                                                            \
    _Pragma("unroll")                                                          \
    for (int e = 0; e < 8; ++e)                                                \
        tp += (float)aq0[e] * nuacck[hq * 64 + kg + e]                         \
            + (float)aq1[e] * nuacck[hq * 64 + 32 + kg + e];                   \
    tp *= inv1024;                                                             \
    tp += __shfl_xor(tp, 16);                                                  \
    tp += __shfl_xor(tp, 32);                                                  \
    float muv[4], tv[4];                                                       \
    _Pragma("unroll")                                                          \
    for (int r = 0; r < 4; ++r) {                                              \
        muv[r] = muq[hq * 1024 + nb + rg4 + r];                                \
        tv[r] = __shfl(tp, rg4 + r);                                           \
    }                                                                          \
    const float Acs = (0.001f / 1024.0f) / 8.0001f;                            \
    float Pr[4], Gr[4];                                                        \
    _Pragma("unroll")                                                          \
    for (int r = 0; r < 4; ++r) {                                              \
        Gr[r] = Acs * muv[r];                                                  \
        Pr[r] = Acs * fmaf(muv[r], uv, -tv[r]);                                \
    }

#define LOAD_KTILE(m0a)                                                        \
    v8h b0[4], b1[4];                                                          \
    _Pragma("unroll")                                                          \
    for (int j = 0; j < 4; ++j) {                                              \
        b0[j] = *(const v8h*)&K[(size_t)((m0a) + j * 16 + lr) * 64 + kg];      \
        b1[j] = *(const v8h*)&K[(size_t)((m0a) + j * 16 + lr) * 64 + 32 + kg]; \
    }

// pass A: cos/cov global+cross sums, per-row cos/cov sums, margin means
__global__ __launch_bounds__(256) void k_passA(const f16* __restrict__ fq16,
        const f16* __restrict__ fk16, const float* __restrict__ rq1,
        const float* __restrict__ rq2, const float* __restrict__ muq,
        const float* __restrict__ rk1, const float* __restrict__ rk2,
        const float* __restrict__ sk, const float* __restrict__ nuacck,
        float* __restrict__ vcrow, float* __restrict__ rowcos,
        float* __restrict__ rowcov, float* __restrict__ pb) {
    __shared__ float rk1s[512], rk2s[512], sks[512];
    PASS_PREAMBLE_AB
    {
        int i2 = t * 2;
        *(float2*)&rk1s[i2] = *(const float2*)&rk1[hq * 1024 + m0base + i2];
        *(float2*)&rk2s[i2] = *(const float2*)&rk2[hq * 1024 + m0base + i2];
        *(float2*)&sks[i2]  = *(const float2*)&sk[hq * 1024 + m0base + i2];
    }
    __syncthreads();
    float rq1v[4], rq2v[4];
    #pragma unroll
    for (int r = 0; r < 4; ++r) {
        rq1v[r] = rq1[hq * 1024 + nb + rg4 + r];
        rq2v[r] = rq2[hq * 1024 + nb + rg4 + r];
    }
    float scos = 0, s2cos = 0, scov = 0, s2cov = 0, sccov = 0;
    float mp[4] = {}, rcs[4] = {}, rcv[4] = {};
    #pragma unroll 2
    for (int m0 = 0; m0 < 512; m0 += 64) {
        LOAD_KTILE(m0base + m0)
        float rk1v[4], rk2v[4], skv[4];
        #pragma unroll
        for (int j = 0; j < 4; ++j) {
            int cg = m0 + j * 16 + lr;
            rk1v[j] = rk1s[cg]; rk2v[j] = rk2s[cg]; skv[j] = sks[cg];
        }
        v4f acc[4] = {};
        #pragma unroll
        for (int j = 0; j < 4; ++j) {
            acc[j] = MFMA(aq0, b0[j], acc[j]);
            acc[j] = MFMA(aq1, b1[j], acc[j]);
        }
        #pragma unroll
        for (int j = 0; j < 4; ++j)
            #pragma unroll
            for (int r = 0; r < 4; ++r) {
                float rv = acc[j][r];
                float cosv = clampf(rv * rq1v[r] * rk1v[j], -0.95f, 0.95f);
                float x2 = rv * rq2v[r] * rk2v[j];
                float marg = fmaxf(0.01f - fmaxf(x2, -0.95f), 0.0f);
                float cov = clampf(fmaf(-Gr[r], skv[j], fmaf(Acs, rv, Pr[r])),
                                   -50.0f, 50.0f);
                scos += cosv; s2cos = fmaf(cosv, cosv, s2cos);
                scov += cov;  s2cov = fmaf(cov, cov, s2cov);
                sccov = fmaf(cosv, cov, sccov);
                mp[r] += marg; rcs[r] += cosv; rcv[r] += cov;
            }
    }
    #pragma unroll
    for (int r = 0; r < 4; ++r) {
        float m_ = mp[r], c_ = rcs[r], v_ = rcv[r];
        #pragma unroll
        for (int mk = 1; mk <= 8; mk <<= 1) {
            m_ += __shfl_xor(m_, mk);
            c_ += __shfl_xor(c_, mk);
            v_ += __shfl_xor(v_, mk);
        }
        if (lr == 0) {
            int row = hq * 1024 + nb + rg4 + r;
            vcrow[half * 32768 + row] = m_ * inv1024;
            rowcos[half * 32768 + row] = c_;
            rowcov[half * 32768 + row] = v_;
        }
    }
    for (int o = 32; o > 0; o >>= 1) {
        scos += __shfl_down(scos, o); s2cos += __shfl_down(s2cos, o);
        scov += __shfl_down(scov, o); s2cov += __shfl_down(s2cov, o);
        sccov += __shfl_down(sccov, o);
    }
    __shared__ float bs[4][5];
    if (l == 0) { bs[w][0] = scos; bs[w][1] = s2cos; bs[w][2] = scov;
                  bs[w][3] = s2cov; bs[w][4] = sccov; }
    __syncthreads();
    if (t == 0) {
        int bid = (hq * 2 + half) * 16 + blockIdx.x;
        #pragma unroll
        for (int s = 0; s < 5; ++s)
            pb[bid * 6 + s] = bs[0][s] + bs[1][s] + bs[2][s] + bs[3][s];
    }
}

// fin1: per-head sums -> hs, global scal[0..2]
__global__ __launch_bounds__(256) void k_fin1(const float* __restrict__ pb,
        const float* __restrict__ vcrow, float* __restrict__ hs,
        float* __restrict__ scal) {
    __shared__ float hsl[40];
    int t = threadIdx.x;
    int hd = t >> 5, idx = t & 31;
    double a0 = 0, a1 = 0, a2 = 0, a3 = 0, a4 = 0;
    for (int i = idx; i < 128; i += 32) {
        const float* p = &pb[(hd * 128 + i) * 6];
        a0 += p[0]; a1 += p[1]; a2 += p[2]; a3 += p[3]; a4 += p[4];
    }
    for (int m = 1; m <= 16; m <<= 1) {
        a0 += __shfl_xor(a0, m); a1 += __shfl_xor(a1, m); a2 += __shfl_xor(a2, m);
        a3 += __shfl_xor(a3, m); a4 += __shfl_xor(a4, m);
    }
    if (idx == 0) {
        hsl[hd * 5 + 0] = (float)a0; hsl[hd * 5 + 1] = (float)a1;
        hsl[hd * 5 + 2] = (float)a2; hsl[hd * 5 + 3] = (float)a3;
        hsl[hd * 5 + 4] = (float)a4;
        hs[hd * 5 + 0] = (float)a0; hs[hd * 5 + 1] = (float)a1;
        hs[hd * 5 + 2] = (float)a2; hs[hd * 5 + 3] = (float)a3;
        hs[hd * 5 + 4] = (float)a4;
    }
    double s4 = 0, s5 = 0;
    for (int i = t; i < 32768; i += 256) {
        double rm = (double)(vcrow[i] + vcrow[32768 + i]);
        s4 += rm; s5 += rm * rm;
    }
    for (int o = 32; o > 0; o >>= 1) { s4 += __shfl_down(s4, o); s5 += __shfl_down(s5, o); }
    __shared__ double red[2][4];
    int wid = t >> 6, lane = t & 63;
    if (lane == 0) { red[0][wid] = s4; red[1][wid] = s5; }
    __syncthreads();
    if (t == 0) {
        double S4 = red[0][0] + red[0][1] + red[0][2] + red[0][3];
        double S5 = red[1][0] + red[1][1] + red[1][2] + red[1][3];
        double S0 = 0, S1 = 0, S2 = 0, S3 = 0;
        for (int h2 = 0; h2 < 8; ++h2) {
            S0 += hsl[h2 * 5 + 0]; S1 += hsl[h2 * 5 + 1];
            S2 += hsl[h2 * 5 + 2]; S3 += hsl[h2 * 5 + 3];
        }
        const double cnt = 33554432.0;
        scal[0] = (float)sqrt(fmax(0.0, (S1 - S0 * S0 / cnt) / (cnt - 1.0)));
        scal[1] = (float)sqrt(fmax(0.0, (S3 - S2 * S2 / cnt) / (cnt - 1.0)));
        double V4 = S4 * 1024.0, V5 = S5 * 1024.0;
        scal[2] = (float)sqrt(fmax(0.0, (V5 - V4 * V4 / cnt) / (cnt - 1.0)));
    }
}

// finrow: per-row addc cross terms -> rp[64][3]
__global__ __launch_bounds__(256) void k_finrow(const float* __restrict__ vcrow,
        const float* __restrict__ rowcos, const float* __restrict__ rowcov,
        const float* __restrict__ wv, const float* __restrict__ scal,
        float* __restrict__ rp) {
    int t = threadIdx.x;
    float s1 = scal[0] + 1e-4f, s2v = scal[1] + 1e-4f, s3 = scal[2] + 1e-4f;
    float p1 = 0, p2 = 0, p3 = 0;
    #pragma unroll
    for (int i = 0; i < 2; ++i) {
        int row = blockIdx.x * 512 + i * 256 + t;
        int h = row >> 12;
        float fc1 = wv[h * 3] / s1;
        float fc2 = wv[h * 3 + 1] * 0.3f / s2v;
        float c3 = wv[h * 3 + 2] * 0.3f / s3;
        float a = (vcrow[row] + vcrow[32768 + row]) * c3;
        float b = fc1 * (rowcos[row] + rowcos[32768 + row])
                + fc2 * (rowcov[row] + rowcov[32768 + row]);
        p1 += a; p2 = fmaf(a, a, p2); p3 = fmaf(a, b, p3);
    }
    for (int o = 32; o > 0; o >>= 1) {
        p1 += __shfl_down(p1, o); p2 += __shfl_down(p2, o); p3 += __shfl_down(p3, o);
    }
    __shared__ float red[3][4];
    int wid = t >> 6, lane = t & 63;
    if (lane == 0) { red[0][wid] = p1; red[1][wid] = p2; red[2][wid] = p3; }
    __syncthreads();
    if (t == 0) {
        rp[blockIdx.x * 3 + 0] = red[0][0] + red[0][1] + red[0][2] + red[0][3];
        rp[blockIdx.x * 3 + 1] = red[1][0] + red[1][1] + red[1][2] + red[1][3];
        rp[blockIdx.x * 3 + 2] = red[2][0] + red[2][1] + red[2][2] + red[2][3];
    }
}

// fin2: ds via decomposition -> temp
__global__ __launch_bounds__(64) void k_fin2(const float* __restrict__ rp,
        const float* __restrict__ hs, const float* __restrict__ wv,
        float* __restrict__ scal) {
    int t = threadIdx.x;
    double p1 = rp[t * 3 + 0], p2 = rp[t * 3 + 1], p3 = rp[t * 3 + 2];
    for (int o = 32; o > 0; o >>= 1) {
        p1 += __shfl_down(p1, o); p2 += __shfl_down(p2, o); p3 += __shfl_down(p3, o);
    }
    if (t == 0) {
        double s1 = (double)scal[0] + 1e-4, s2v = (double)scal[1] + 1e-4;
        double sdd = 1024.0 * p1;
        double sdd2 = 2.0 * p3 + 1024.0 * p2;
        for (int h = 0; h < 8; ++h) {
            double fc1 = (double)wv[h * 3] / s1;
            double fc2 = (double)wv[h * 3 + 1] * 0.3 / s2v;
            sdd += fc1 * hs[h * 5 + 0] + fc2 * hs[h * 5 + 2];
            sdd2 += fc1 * fc1 * hs[h * 5 + 1] + fc2 * fc2 * hs[h * 5 + 3]
                  + 2.0 * fc1 * fc2 * hs[h * 5 + 4];
        }
        const double cnt = 33554432.0;
        double ds = sqrt(fmax(0.0, (sdd2 - sdd * sdd / cnt) / (cnt - 1.0)));
        float temp = (ds < 1e-5) ? 0.01f : ((ds < 1e-3) ? 0.05f : (0.2f + (float)ds * 2.0f));
        temp = fminf(fmaxf(temp, 0.01f), 8.0f);
        scal[3] = temp;
    }
}

// ---- one 64-key tile of the flash pass, parameterized by P buffer.
// V is hi-only now: 2 MFMA per j instead of 4. ----
#define TILE_STEP(PBASE, MK)                                                   \
    {                                                                          \
        int mk = (MK);                                                         \
        v8h b0[4], b1[4];                                                      \
        _Pragma("unroll")                                                      \
        for (int j = 0; j < 4; ++j) {                                          \
            b0[j] = *(const v8h*)&K[(size_t)(mk + j * 16 + lr) * 64 + kg];     \
            b1[j] = *(const v8h*)&K[(size_t)(mk + j * 16 + lr) * 64 + 32 + kg];\
        }                                                                      \
        float rk1v[4], skv[4];                                                 \
        _Pragma("unroll")                                                      \
        for (int j = 0; j < 4; ++j) {                                          \
            int cg = mk + j * 16 + lr;                                         \
            rk1v[j] = rk1s[cg]; skv[j] = sks[cg];                              \
        }                                                                      \
        v4f acc[4] = {};                                                       \
        _Pragma("unroll")                                                      \
        for (int j = 0; j < 4; ++j) {                                          \
            acc[j] = MFMA(aq0, b0[j], acc[j]);                                 \
            acc[j] = MFMA(aq1, b1[j], acc[j]);                                 \
        }                                                                      \
        float dd[4][4];                                                        \
        float tmax[4] = { -1e30f, -1e30f, -1e30f, -1e30f };                    \
        _Pragma("unroll")                                                      \
        for (int j = 0; j < 4; ++j)                                            \
            _Pragma("unroll")                                                  \
            for (int r = 0; r < 4; ++r) {                                      \
                float rv = acc[j][r];                                          \
                float cosv = clampf(rv * rq1v[r] * rk1v[j], -0.95f, 0.95f);    \
                float cov = clampf(fmaf(-Gcr[r], skv[j],                       \
                                        fmaf(Acs, rv, Pcr[r])), -50.0f, 50.0f);\
                float d2 = fmaf(fc2, cov, fmaf(fc1, cosv, addc[r]));           \
                dd[j][r] = d2;                                                 \
                tmax[r] = fmaxf(tmax[r], d2);                                  \
            }                                                                  \
        v4f fv;                                                                \
        _Pragma("unroll")                                                      \
        for (int r = 0; r < 4; ++r) {                                          \
            float tm = tmax[r];                                                \
            tm = fmaxf(tm, __shfl_xor(tm, 1));                                 \
            tm = fmaxf(tm, __shfl_xor(tm, 2));                                 \
            tm = fmaxf(tm, __shfl_xor(tm, 4));                                 \
            tm = fmaxf(tm, __shfl_xor(tm, 8));                                 \
            float mnew = fmaxf(mrun[r], tm);                                   \
            float fr_ = __expf((mrun[r] - mnew) * invt);                       \
            mrun[r] = mnew;                                                    \
            rsacc[r] *= fr_;                                                   \
            fv[r] = fr_;                                                       \
        }                                                                      \
        _Pragma("unroll")                                                      \
        for (int j = 0; j < 4; ++j) accpv[j] *= fv;                            \
        _Pragma("unroll")                                                      \
        for (int j = 0; j < 4; ++j)                                            \
            _Pragma("unroll")                                                  \
            for (int r = 0; r < 4; ++r) {                                      \
                float pe = __expf((dd[j][r] - mrun[r]) * invt);                \
                f16 p16 = (f16)pe;                                             \
                rsacc[r] += (float)p16;                                        \
                (PBASE)[(w * 16 + rg4 + r) * 72 + j * 16 + lr] = p16;          \
            }                                                                  \
        v8h pa0 = *(const v8h*)&(PBASE)[(w * 16 + lr) * 72 + kg];              \
        v8h pa1 = *(const v8h*)&(PBASE)[(w * 16 + lr) * 72 + 32 + kg];         \
        _Pragma("unroll")                                                      \
        for (int j = 0; j < 4; ++j) {                                          \
            size_t vb = ((size_t)hq * 64 + j * 16 + lr) * 1024 + mk;           \
            v8h vh0 = *(const v8h*)&fvhT[vb + kg];                             \
            v8h vh1 = *(const v8h*)&fvhT[vb + 32 + kg];                        \
            accpv[j] = MFMA(pa0, vh0, accpv[j]);                               \
            accpv[j] = MFMA(pa1, vh1, accpv[j]);                               \
        }                                                                      \
    }

// pass C: recompute QK^T -> dots -> ONLINE softmax -> PV (V hi-only) -> av.
// 512 threads = 4 row-groups x 2 K-halves; Pa/Pb ping-pong; combine overlays.
__global__ __launch_bounds__(512) void k_passC(const f16* __restrict__ fq16,
        const f16* __restrict__ fk16, const float* __restrict__ rq1,
        const float* __restrict__ muq, const float* __restrict__ rk1,
        const float* __restrict__ sk, const float* __restrict__ nuacck,
        const float* __restrict__ vcrow, const float* __restrict__ wv,
        const float* __restrict__ scal,
        const f16* __restrict__ fvhT,
        f16* __restrict__ avh, f16* __restrict__ avl) {
    __shared__ __align__(16) char arena[36864];   // Pa(18432) + Pb(18432); combine overlays
    __shared__ float rk1s[1024], sks[1024];
    f16* Pa = (f16*)arena;
    f16* Pb = (f16*)(arena + 18432);
    int hq = blockIdx.y;
    int t = threadIdx.x, l = t & 63, w = t >> 6;
    int rg = w & 3, kh = w >> 2;
    int lr = l & 15, kg = (l >> 4) * 8, rg4 = (l >> 4) * 4;
    int nb = blockIdx.x * 64 + rg * 16;
    int m0base = kh * 512;
    const f16* Q = fq16 + (size_t)hq * 65536;
    const f16* K = fk16 + (size_t)hq * 65536;
    {
        int i2 = t * 2;
        *(float2*)&rk1s[i2] = *(const float2*)&rk1[hq * 1024 + i2];
        *(float2*)&sks[i2]  = *(const float2*)&sk[hq * 1024 + i2];
    }
    __syncthreads();
    v8h aq0 = *(const v8h*)&Q[(size_t)(nb + lr) * 64 + kg];
    v8h aq1 = *(const v8h*)&Q[(size_t)(nb + lr) * 64 + 32 + kg];
    const float inv1024 = 1.0f / 1024.0f;
    float uvp = nuacck[hq * 64 + l] * inv1024;
    #pragma unroll
    for (int o = 32; o > 0; o >>= 1) uvp += __shfl_xor(uvp, o);
    float uv = uvp;
    float tpv = 0.f;
    #pragma unroll
    for (int e = 0; e < 8; ++e)
        tpv += (float)aq0[e] * nuacck[hq * 64 + kg + e]
             + (float)aq1[e] * nuacck[hq * 64 + 32 + kg + e];
    tpv *= inv1024;
    tpv += __shfl_xor(tpv, 16);
    tpv += __shfl_xor(tpv, 32);
    float muv[4], tv[4];
    #pragma unroll
    for (int r = 0; r < 4; ++r) {
        muv[r] = muq[hq * 1024 + nb + rg4 + r];
        tv[r] = __shfl(tpv, rg4 + r);
    }
    const float Acs = (0.001f / 1024.0f) / 8.0001f;
    float Pcr[4], Gcr[4];
    #pragma unroll
    for (int r = 0; r < 4; ++r) {
        Gcr[r] = Acs * muv[r];
        Pcr[r] = Acs * fmaf(muv[r], uv, -tv[r]);
    }
    int h = hq >> 2;
    float s1 = scal[0] + 1e-4f, s2v = scal[1] + 1e-4f, s3 = scal[2] + 1e-4f;
    float fc1 = wv[h * 3] / s1;
    float fc2 = wv[h * 3 + 1] * 0.3f / s2v;
    float c3 = wv[h * 3 + 2] * 0.3f / s3;
    float invt = 1.0f / scal[3];
    float rq1v[4], addc[4];
    #pragma unroll
    for (int r = 0; r < 4; ++r) {
        int row = hq * 1024 + nb + rg4 + r;
        rq1v[r] = rq1[row];
        addc[r] = (vcrow[row] + vcrow[32768 + row]) * c3;
    }
    v4f accpv[4] = {};
    float rsacc[4] = {};
    float mrun[4] = { -1e30f, -1e30f, -1e30f, -1e30f };
    for (int it = 0; it < 4; ++it) {
        TILE_STEP(Pa, m0base + it * 128)
        TILE_STEP(Pb, m0base + it * 128 + 64)
    }
    __syncthreads();   // all Pa/Pb uses complete before combine overlay reuse
    #pragma unroll
    for (int r = 0; r < 4; ++r) {
        float s = rsacc[r];
        s += __shfl_xor(s, 1); s += __shfl_xor(s, 2);
        s += __shfl_xor(s, 4); s += __shfl_xor(s, 8);
        rsacc[r] = s;
    }
    float* cbacc = (float*)arena;            // [4][16][64] = 16384 B
    float* cbrs  = (float*)(arena + 16384);  // [4][4][64]  = 4096 B
    float* cbm   = (float*)(arena + 20480);  // [4][16]     = 256 B
    if (kh == 1) {
        #pragma unroll
        for (int j = 0; j < 4; ++j)
            #pragma unroll
            for (int r = 0; r < 4; ++r)
                cbacc[(rg * 16 + j * 4 + r) * 64 + l] = accpv[j][r];
        #pragma unroll
        for (int r = 0; r < 4; ++r) cbrs[(rg * 4 + r) * 64 + l] = rsacc[r];
        if (lr == 0) {
            #pragma unroll
            for (int r = 0; r < 4; ++r) cbm[rg * 16 + rg4 + r] = mrun[r];
        }
    }
    __syncthreads();
    if (kh == 0) {
        v4f f0v, f1v;
        float rinv[4];
        #pragma unroll
        for (int r = 0; r < 4; ++r) {
            float m1 = cbm[rg * 16 + rg4 + r];
            float mf = fmaxf(mrun[r], m1);
            float f0 = __expf((mrun[r] - mf) * invt);
            float f1 = __expf((m1 - mf) * invt);
            f0v[r] = f0; f1v[r] = f1;
            float rst = rsacc[r] * f0 + cbrs[(rg * 4 + r) * 64 + l] * f1;
            rinv[r] = 1.0f / rst;
        }
        #pragma unroll
        for (int j = 0; j < 4; ++j)
            #pragma unroll
            for (int r = 0; r < 4; ++r) {
                float val = (accpv[j][r] * f0v[r]
                           + cbacc[(rg * 16 + j * 4 + r) * 64 + l] * f1v[r]) * rinv[r];
                size_t idx = ((size_t)(hq * 1024 + nb + rg4 + r)) * 64 + j * 16 + lr;
                f16 hi = (f16)val;
                avh[idx] = hi;
                avl[idx] = (f16)(val - (float)hi);
            }
    }
}

// out = av @ Wout + bout (MFMA, 3-way split)
__global__ __launch_bounds__(256) void k_out_mfma(const f16* __restrict__ avh,
        const f16* __restrict__ avl,
        const f16* __restrict__ WoutTh, const f16* __restrict__ WoutTl,
        const float* __restrict__ bout, float* __restrict__ out) {
    __shared__ float red[2][4][4][4][64];
    int t = threadIdx.x, l = t & 63, w = t >> 6;
    int wc = w & 1, kh = w >> 1;
    int col0 = blockIdx.x * 128 + wc * 64;
    int tok0 = blockIdx.y * 64;
    int qi = tok0 >> 10, nb = tok0 & 1023;
    int lr = l & 15, kg = (l >> 4) * 8;
    v4f acc[4][4] = {};
    for (int ks8 = 0; ks8 < 8; ++ks8) {
        int ks = kh * 256 + ks8 * 32;
        int f = ks + kg;
        int h = f >> 6, d = f & 63;
        size_t hb = (size_t)((h << 2) + qi) * 1024;
        v8h ah[4], al4[4], bh[4], bl4[4];
        #pragma unroll
        for (int i = 0; i < 4; ++i) {
            int n = nb + i * 16 + lr;
            ah[i]  = *(const v8h*)&avh[(hb + n) * 64 + d];
            al4[i] = *(const v8h*)&avl[(hb + n) * 64 + d];
        }
        #pragma unroll
        for (int j = 0; j < 4; ++j) {
            bh[j]  = *(const v8h*)&WoutTh[(size_t)(col0 + j * 16 + lr) * 512 + ks + kg];
            bl4[j] = *(const v8h*)&WoutTl[(size_t)(col0 + j * 16 + lr) * 512 + ks + kg];
        }
        #pragma unroll
        for (int i = 0; i < 4; ++i)
            #pragma unroll
            for (int j = 0; j < 4; ++j) {
                acc[i][j] = MFMA(ah[i], bh[j], acc[i][j]);
                acc[i][j] = MFMA(ah[i], bl4[j], acc[i][j]);
                acc[i][j] = MFMA(al4[i], bh[j], acc[i][j]);
            }
    }
    if (kh == 0) {
        #pragma unroll
        for (int i = 0; i < 4; ++i)
            #pragma unroll
            for (int j = 0; j < 4; ++j)
                #pragma unroll
                for (int r = 0; r < 4; ++r)
                    red[wc][i][j][r][l] = acc[i][j][r];
    }
    __syncthreads();
    if (kh == 1) {
        #pragma unroll
        for (int i = 0; i < 4; ++i)
            #pragma unroll
            for (int j = 0; j < 4; ++j) {
                int col = col0 + j * 16 + lr;
                float bo = bout[col];
                #pragma unroll
                for (int r = 0; r < 4; ++r) {
                    float val = acc[i][j][r] + red[wc][i][j][r][l] + bo;
                    int token = tok0 + i * 16 + (l >> 4) * 4 + r;
                    out[(size_t)token * 512 + col] = val;
                }
            }
    }
}

extern "C" void kernel_launch(void* const* d_in, const int* in_sizes, int n_in,
                              void* d_out, int out_size, void* d_ws, size_t ws_size,
                              hipStream_t stream) {
    const float* q     = (const float*)d_in[0];
    const float* k     = (const float*)d_in[1];
    const float* v     = (const float*)d_in[2];
    const float* ln_w  = (const float*)d_in[3];
    const float* ln_b  = (const float*)d_in[4];
    const float* W_in  = (const float*)d_in[5];
    const float* W_out = (const float*)d_in[6];
    const float* b_out = (const float*)d_in[7];
    const float* wp_W1 = (const float*)d_in[8];
    const float* wp_b1 = (const float*)d_in[9];
    const float* wp_lw = (const float*)d_in[10];
    const float* wp_lb = (const float*)d_in[11];
    const float* wp_W2 = (const float*)d_in[12];
    const float* wp_b2 = (const float*)d_in[13];
    const float* wp_W3 = (const float*)d_in[14];
    const float* wp_b3 = (const float*)d_in[15];
    const float* wp_W4 = (const float*)d_in[16];
    const float* wp_b4 = (const float*)d_in[17];
    const float* wtemp = (const float*)d_in[18];

    float* ws = (float*)d_ws;
    f16* ln16     = (f16*)(ws + OFF_LN16);
    f16* lnlo     = (f16*)(ws + OFF_LNLO);
    f16* fq16     = (f16*)(ws + OFF_FQ16);
    f16* fk16     = (f16*)(ws + OFF_FK16);
    f16* fvhT     = (f16*)(ws + OFF_FVHT);
    f16* WinTh    = (f16*)(ws + OFF_WINTH);
    f16* WinTl    = (f16*)(ws + OFF_WINTL);
    f16* WoutTh   = (f16*)(ws + OFF_WOUTTH);
    f16* WoutTl   = (f16*)(ws + OFF_WOUTTL);
    f16* avh      = (f16*)(ws + OFF_AVH);
    f16* avl      = (f16*)(ws + OFF_AVL);
    float* rq1    = ws + OFF_RQ1;
    float* rq2    = ws + OFF_RQ2;
    float* muq    = ws + OFF_MUQ;
    float* rk1    = ws + OFF_RK1;
    float* rk2    = ws + OFF_RK2;
    float* sk     = ws + OFF_SK;
    float* vcrow  = ws + OFF_VC;
    float* rowcos = ws + OFF_ROWCOS;
    float* rowcov = ws + OFF_ROWCOV;
    float* nuacck = ws + OFF_NUACC;
    float* pb     = ws + OFF_PB;
    float* hs     = ws + OFF_HS;
    float* rp     = ws + OFF_RP;
    float* feat   = ws + OFF_FEAT;
    float* wv     = ws + OFF_WV;
    float* scal   = ws + OFF_SCAL;

    k_zero<<<8, 256, 0, stream>>>(feat, nuacck);
    k_wprep<<<dim3(8, 8, 2), 256, 0, stream>>>(W_in, W_out, WinTh, WinTl, WoutTh, WoutTl);
    k_ln16<<<3072, 256, 0, stream>>>(q, k, v, ln_w, ln_b, ln16, lnlo);
    k_proj_all<<<dim3(4, 32, 3), 256, 0, stream>>>(ln16, lnlo, WinTh, WinTl,
            fq16, fk16, fvhT, rq1, rq2, muq, rk1, rk2, sk, feat, nuacck);
    k_mlp<<<8, 256, 0, stream>>>(feat, wp_W1, wp_b1, wp_lw, wp_lb,
                                 wp_W2, wp_b2, wp_W3, wp_b3, wp_W4, wp_b4,
                                 wtemp, wv);
    k_passA<<<dim3(16, 2, 32), 256, 0, stream>>>(fq16, fk16, rq1, rq2, muq, rk1, rk2,
                                                 sk, nuacck, vcrow, rowcos, rowcov, pb);
    k_fin1<<<1, 256, 0, stream>>>(pb, vcrow, hs, scal);
    k_finrow<<<64, 256, 0, stream>>>(vcrow, rowcos, rowcov, wv, scal, rp);
    k_fin2<<<1, 64, 0, stream>>>(rp, hs, wv, scal);
    k_passC<<<dim3(16, 32), 512, 0, stream>>>(fq16, fk16, rq1, muq, rk1, sk, nuacck,
                                              vcrow, wv, scal, fvhT, avh, avl);
    k_out_mfma<<<dim3(4, 64), 256, 0, stream>>>(avh, avl, WoutTh, WoutTl, b_out,
                                                (float*)d_out);
}

// Round 15
// 262.082 us; speedup vs baseline: 1.1503x; 1.0675x over previous
//
#include <hip/hip_runtime.h>
#include <math.h>

typedef _Float16 f16;
typedef _Float16 v8h __attribute__((ext_vector_type(8)));
typedef _Float16 v4h __attribute__((ext_vector_type(4)));
typedef float    v4f __attribute__((ext_vector_type(4)));

#define MFMA(a, b, c) __builtin_amdgcn_mfma_f32_16x16x32_f16((a), (b), (c), 0, 0, 0)

// ---------------- workspace layout (float offsets) ----------------
#define OFF_LN16    0u
#define OFF_FQ16    4194304u
#define OFF_FK16    5242880u
#define OFF_FVHT    6291456u
#define OFF_WINTH   8388608u
#define OFF_WOUTTH  8650752u
#define OFF_AVH     8912896u
#define OFF_AVL     9961472u
#define OFF_RQ1     11010048u
#define OFF_RQ2     11042816u
#define OFF_MUQ     11075584u
#define OFF_RK1     11108352u
#define OFF_RK2     11141120u
#define OFF_SK      11173888u
#define OFF_VC      11206656u   // 65536 (2 halves)
#define OFF_ROWCOS  11272192u   // 2 halves
#define OFF_ROWCOV  11337728u   // 2 halves
#define OFF_NUACC   11403264u   // 2048
#define OFF_PB      11405312u   // 1024*6
#define OFF_HS      11411456u   // 64
#define OFF_RP      11411520u   // 192
#define OFF_FEAT    11411712u   // 1024
#define OFF_WV      11412736u   // 24
#define OFF_SCAL    11412760u   // 8

__device__ __forceinline__ float clampf(float x, float lo, float hi) {
    return fminf(fmaxf(x, lo), hi);
}

__global__ void k_zero(float* feat, float* nuacck) {
    int i = blockIdx.x * 256 + threadIdx.x;
    if (i < 1024) feat[i] = 0.0f;
    if (i < 2048) nuacck[i] = 0.0f;
}

// transpose of a 512x512 weight to f16: W[k][c] -> WT[c][k] (hi only)
__global__ __launch_bounds__(256) void k_wprep(const float* __restrict__ Win,
        const float* __restrict__ Wout, f16* __restrict__ WinTh,
        f16* __restrict__ WoutTh) {
    __shared__ float lds[64][68];
    const float* W = blockIdx.z ? Wout : Win;
    f16* Th = blockIdx.z ? WoutTh : WinTh;
    int k0 = blockIdx.y * 64, c0 = blockIdx.x * 64;
    int t = threadIdx.x;
    #pragma unroll
    for (int p = 0; p < 4; ++p) {
        int flat = p * 1024 + t * 4;
        int r = flat >> 6, c = flat & 63;
        *(float4*)&lds[r][c] = *(const float4*)&W[(size_t)(k0 + r) * 512 + c0 + c];
    }
    __syncthreads();
    int c = t >> 2, kk = (t & 3) * 16;
    #pragma unroll
    for (int half = 0; half < 2; ++half) {
        v8h h8;
        #pragma unroll
        for (int ii = 0; ii < 8; ++ii)
            h8[ii] = (f16)lds[kk + half * 8 + ii][c];
        *(v8h*)&Th[(size_t)(c0 + c) * 512 + k0 + kk + half * 8] = h8;
    }
}

// LayerNorm all 12288 tokens -> ln16 f16
__global__ __launch_bounds__(256) void k_ln16(const float* __restrict__ q,
        const float* __restrict__ kk, const float* __restrict__ v,
        const float* __restrict__ lnw, const float* __restrict__ lnb,
        f16* __restrict__ ln16) {
    int t = threadIdx.x, wid = t >> 6, lane = t & 63;
    int token = blockIdx.x * 4 + wid;
    int inp = token >> 12, lt = token & 4095;
    const float* xp = (inp == 0) ? q : ((inp == 1) ? kk : v);
    const float4* xr = (const float4*)(xp + (size_t)lt * 512);
    float4 a = xr[lane], b = xr[lane + 64];
    float s = a.x + a.y + a.z + a.w + b.x + b.y + b.z + b.w;
    float s2 = a.x*a.x + a.y*a.y + a.z*a.z + a.w*a.w
             + b.x*b.x + b.y*b.y + b.z*b.z + b.w*b.w;
    for (int o = 32; o > 0; o >>= 1) { s += __shfl_down(s, o); s2 += __shfl_down(s2, o); }
    float m_ = __shfl(s, 0) * (1.0f / 512.0f);
    float var = __shfl(s2, 0) * (1.0f / 512.0f) - m_ * m_;
    var = fmaxf(var, 0.0f);
    float rs = rsqrtf(var + 1e-5f);
    const float4* w4 = (const float4*)lnw;
    const float4* b4 = (const float4*)lnb;
    float4 wa = w4[lane], wb = w4[lane + 64], ba = b4[lane], bb = b4[lane + 64];
    f16* orow = ln16 + (size_t)token * 512;
    v4h ha, hb;
    ha[0] = (f16)((a.x - m_) * rs * wa.x + ba.x);
    ha[1] = (f16)((a.y - m_) * rs * wa.y + ba.y);
    ha[2] = (f16)((a.z - m_) * rs * wa.z + ba.z);
    ha[3] = (f16)((a.w - m_) * rs * wa.w + ba.w);
    hb[0] = (f16)((b.x - m_) * rs * wb.x + bb.x);
    hb[1] = (f16)((b.y - m_) * rs * wb.y + bb.y);
    hb[2] = (f16)((b.z - m_) * rs * wb.z + bb.z);
    hb[3] = (f16)((b.w - m_) * rs * wb.w + bb.w);
    *(v4h*)&orow[lane * 4] = ha;
    *(v4h*)&orow[lane * 4 + 256] = hb;
}

// LN16 @ Win (MFMA), single-precision f16 path for all modes.
// MODE 0: q (fq16 + recip stats). MODE 1: k. MODE 2: v (transposed write).
template<int MODE>
__device__ __forceinline__ void proj_body(const f16* __restrict__ A16,
        const f16* __restrict__ BTh,
        f16* __restrict__ fout16, f16* __restrict__ fhT,
        float* __restrict__ oA, float* __restrict__ oB, float* __restrict__ oC,
        float* __restrict__ feat, float* __restrict__ nuacck) {
    int t = threadIdx.x, l = t & 63, w = t >> 6;
    int wr = w >> 1, wc = w & 1;
    int col0 = blockIdx.x * 128 + wc * 64;
    int tok0 = blockIdx.y * 128 + wr * 64;
    int lr = l & 15, kg = (l >> 4) * 8;
    int rg4 = (l >> 4) * 4;
    v4f acc[4][4] = {};
    for (int ks = 0; ks < 512; ks += 32) {
        v8h a[4], b[4];
        #pragma unroll
        for (int i = 0; i < 4; ++i)
            a[i] = *(const v8h*)&A16[(size_t)(tok0 + i * 16 + lr) * 512 + ks + kg];
        #pragma unroll
        for (int j = 0; j < 4; ++j)
            b[j] = *(const v8h*)&BTh[(size_t)(col0 + j * 16 + lr) * 512 + ks + kg];
        #pragma unroll
        for (int i = 0; i < 4; ++i)
            #pragma unroll
            for (int j = 0; j < 4; ++j)
                acc[i][j] = MFMA(a[i], b[j], acc[i][j]);
    }
    int h = col0 >> 6;
    #pragma unroll
    for (int i = 0; i < 4; ++i)
        #pragma unroll
        for (int j = 0; j < 4; ++j)
            #pragma unroll
            for (int r = 0; r < 4; ++r) {
                int token = tok0 + i * 16 + rg4 + r;
                int d = j * 16 + lr;
                int qi = token >> 10, n = token & 1023;
                float val = acc[i][j][r];
                if constexpr (MODE != 2) {
                    fout16[((size_t)((h << 2) + qi) * 1024 + n) * 64 + d] = (f16)val;
                } else {
                    fhT[((size_t)((h << 2) + qi) * 64 + d) * 1024 + n] = (f16)val;
                }
            }
    if constexpr (MODE != 2) {
        #pragma unroll
        for (int i = 0; i < 4; ++i)
            #pragma unroll
            for (int r = 0; r < 4; ++r) {
                float s = 0.f, s2 = 0.f;
                #pragma unroll
                for (int j = 0; j < 4; ++j) { float v = acc[i][j][r]; s += v; s2 += v * v; }
                #pragma unroll
                for (int mk = 1; mk <= 8; mk <<= 1) {
                    s += __shfl_xor(s, mk); s2 += __shfl_xor(s2, mk);
                }
                if (lr == 0) {
                    int token = tok0 + i * 16 + rg4 + r;
                    int qi = token >> 10, n = token & 1023;
                    int row = ((h << 2) + qi) * 1024 + n;
                    float nv = sqrtf(s2);
                    oA[row] = 1.0f / (nv + 1e-6f);
                    oB[row] = 1.0f / fmaxf(nv, 1e-4f);
                    oC[row] = (MODE == 0) ? s * (1.0f / 64.0f) : s;
                }
            }
        float cs[4];
        #pragma unroll
        for (int j = 0; j < 4; ++j) {
            float c = 0.f;
            #pragma unroll
            for (int i = 0; i < 4; ++i)
                #pragma unroll
                for (int r = 0; r < 4; ++r) c += acc[i][j][r];
            c += __shfl_xor(c, 16); c += __shfl_xor(c, 32);
            cs[j] = c;
        }
        if (l < 16) {
            #pragma unroll
            for (int j = 0; j < 4; ++j)
                atomicAdd(&feat[h * 128 + (MODE == 1 ? 64 : 0) + j * 16 + l],
                          cs[j] * (1.0f / 4096.0f));
            if constexpr (MODE == 1) {
                int qi = tok0 >> 10;
                #pragma unroll
                for (int j = 0; j < 4; ++j)
                    atomicAdd(&nuacck[((h << 2) + qi) * 64 + j * 16 + l], cs[j]);
            }
        }
    }
}

__global__ __launch_bounds__(256) void k_proj_all(const f16* __restrict__ ln16,
        const f16* __restrict__ BTh,
        f16* __restrict__ fq16, f16* __restrict__ fk16,
        f16* __restrict__ fvhT,
        float* __restrict__ rq1, float* __restrict__ rq2, float* __restrict__ muq,
        float* __restrict__ rk1, float* __restrict__ rk2, float* __restrict__ sk,
        float* __restrict__ feat, float* __restrict__ nuacck) {
    int mode = blockIdx.z;
    if (mode == 0)
        proj_body<0>(ln16, BTh, fq16, nullptr, rq1, rq2, muq, feat, nullptr);
    else if (mode == 1)
        proj_body<1>(ln16 + 2097152u, BTh, fk16, nullptr, rk1, rk2, sk, feat, nuacck);
    else
        proj_body<2>(ln16 + 4194304u, BTh, nullptr, fvhT,
                     nullptr, nullptr, nullptr, nullptr, nullptr);
}

// tiny MLP weight predictor, one block per head -> wv[h][3]
__global__ __launch_bounds__(256) void k_mlp(const float* __restrict__ feat,
        const float* __restrict__ W1, const float* __restrict__ b1,
        const float* __restrict__ lw, const float* __restrict__ lb,
        const float* __restrict__ W2, const float* __restrict__ b2,
        const float* __restrict__ W3, const float* __restrict__ b3,
        const float* __restrict__ W4, const float* __restrict__ b4,
        const float* __restrict__ wtemp, float* wv) {
    __shared__ float h1[256], h2[192], h3[64], red[8];
    int t = threadIdx.x;
    int h = blockIdx.x;
    float p = 0.0f;
    for (int i = 0; i < 128; ++i) p += feat[h * 128 + i] * W1[i * 256 + t];
    p += b1[t];
    float s = p, s2 = p * p;
    for (int o = 32; o > 0; o >>= 1) { s += __shfl_down(s, o); s2 += __shfl_down(s2, o); }
    if ((t & 63) == 0) { red[t >> 6] = s; red[4 + (t >> 6)] = s2; }
    __syncthreads();
    float S = red[0] + red[1] + red[2] + red[3];
    float S2 = red[4] + red[5] + red[6] + red[7];
    float mu = S / 256.0f;
    float var = S2 / 256.0f - mu * mu; if (var < 0.0f) var = 0.0f;
    float xh = (p - mu) * rsqrtf(var + 1e-5f) * lw[t] + lb[t];
    h1[t] = fmaxf(xh, 0.0f);
    __syncthreads();
    if (t < 192) {
        float a = 0.0f;
        for (int i = 0; i < 256; ++i) a += h1[i] * W2[i * 192 + t];
        h2[t] = fmaxf(a + b2[t], 0.0f);
    }
    __syncthreads();
    if (t < 64) {
        float a = 0.0f;
        for (int i = 0; i < 192; ++i) a += h2[i] * W3[i * 64 + t];
        h3[t] = fmaxf(a + b3[t], 0.0f);
    }
    __syncthreads();
    if (t == 0) {
        float lg[3];
        for (int j = 0; j < 3; ++j) {
            float a = 0.0f;
            for (int i = 0; i < 64; ++i) a += h3[i] * W4[i * 3 + j];
            lg[j] = a + b4[j];
        }
        float mx = fmaxf(lg[0], fmaxf(lg[1], lg[2]));
        float e0 = expf(lg[0] - mx), e1 = expf(lg[1] - mx), e2 = expf(lg[2] - mx);
        float se = e0 + e1 + e2;
        float pr0 = e0 / se, pr1 = e1 / se, pr2 = e2 / se;
        float wt = wtemp[0]; wt = fminf(fmaxf(wt, 0.01f), 1.0f);
        float q0 = pr0 / wt, q1 = pr1 / wt, q2 = pr2 / wt;
        float m2 = fmaxf(q0, fmaxf(q1, q2));
        float f0 = expf(q0 - m2), f1 = expf(q1 - m2), f2 = expf(q2 - m2);
        float sf = f0 + f1 + f2; f0 /= sf; f1 /= sf; f2 /= sf;
        f0 = fminf(fmaxf(f0, 0.01f), 0.95f);
        f1 = fminf(fmaxf(f1, 0.01f), 0.95f);
        f2 = fminf(fmaxf(f2, 0.01f), 0.95f);
        float sw = f0 + f1 + f2;
        wv[h * 3 + 0] = f0 / sw; wv[h * 3 + 1] = f1 / sw; wv[h * 3 + 2] = f2 / sw;
    }
}

// ---- shared per-pass preamble for passA: grid (16, 2, 32) ----
#define PASS_PREAMBLE_AB                                                       \
    int hq = blockIdx.z;                                                       \
    int half = blockIdx.y;                                                     \
    int m0base = half * 512;                                                   \
    int t = threadIdx.x, l = t & 63, w = t >> 6;                               \
    int lr = l & 15, kg = (l >> 4) * 8, rg4 = (l >> 4) * 4;                    \
    int nb = blockIdx.x * 64 + w * 16;                                         \
    const f16* Q = fq16 + (size_t)hq * 65536;                                  \
    const f16* K = fk16 + (size_t)hq * 65536;                                  \
    v8h aq0 = *(const v8h*)&Q[(size_t)(nb + lr) * 64 + kg];                    \
    v8h aq1 = *(const v8h*)&Q[(size_t)(nb + lr) * 64 + 32 + kg];               \
    const float inv1024 = 1.0f / 1024.0f;                                      \
    float uvp = nuacck[hq * 64 + l] * inv1024;                                 \
    _Pragma("unroll")                                                          \
    for (int o = 32; o > 0; o >>= 1) uvp += __shfl_xor(uvp, o);                \
    float uv = uvp;                                                            \
    float tp = 0.f;                                                            \
    _Pragma("unroll")                                                          \
    for (int e = 0; e < 8; ++e)                                                \
        tp += (float)aq0[e] * nuacck[hq * 64 + kg + e]                         \
            + (float)aq1[e] * nuacck[hq * 64 + 32 + kg + e];                   \
    tp *= inv1024;                                                             \
    tp += __shfl_xor(tp, 16);                                                  \
    tp += __shfl_xor(tp, 32);                                                  \
    float muv[4], tv[4];                                                       \
    _Pragma("unroll")                                                          \
    for (int r = 0; r < 4; ++r) {                                              \
        muv[r] = muq[hq * 1024 + nb + rg4 + r];                                \
        tv[r] = __shfl(tp, rg4 + r);                                           \
    }                                                                          \
    const float Acs = (0.001f / 1024.0f) / 8.0001f;                            \
    float Pr[4], Gr[4];                                                        \
    _Pragma("unroll")                                                          \
    for (int r = 0; r < 4; ++r) {                                              \
        Gr[r] = Acs * muv[r];                                                  \
        Pr[r] = Acs * fmaf(muv[r], uv, -tv[r]);                                \
    }

#define LOAD_KTILE(m0a)                                                        \
    v8h b0[4], b1[4];                                                          \
    _Pragma("unroll")                                                          \
    for (int j = 0; j < 4; ++j) {                                              \
        b0[j] = *(const v8h*)&K[(size_t)((m0a) + j * 16 + lr) * 64 + kg];      \
        b1[j] = *(const v8h*)&K[(size_t)((m0a) + j * 16 + lr) * 64 + 32 + kg]; \
    }

// pass A: cos/cov global+cross sums, per-row cos/cov sums, margin means
__global__ __launch_bounds__(256) void k_passA(const f16* __restrict__ fq16,
        const f16* __restrict__ fk16, const float* __restrict__ rq1,
        const float* __restrict__ rq2, const float* __restrict__ muq,
        const float* __restrict__ rk1, const float* __restrict__ rk2,
        const float* __restrict__ sk, const float* __restrict__ nuacck,
        float* __restrict__ vcrow, float* __restrict__ rowcos,
        float* __restrict__ rowcov, float* __restrict__ pb) {
    __shared__ float rk1s[512], rk2s[512], sks[512];
    PASS_PREAMBLE_AB
    {
        int i2 = t * 2;
        *(float2*)&rk1s[i2] = *(const float2*)&rk1[hq * 1024 + m0base + i2];
        *(float2*)&rk2s[i2] = *(const float2*)&rk2[hq * 1024 + m0base + i2];
        *(float2*)&sks[i2]  = *(const float2*)&sk[hq * 1024 + m0base + i2];
    }
    __syncthreads();
    float rq1v[4], rq2v[4];
    #pragma unroll
    for (int r = 0; r < 4; ++r) {
        rq1v[r] = rq1[hq * 1024 + nb + rg4 + r];
        rq2v[r] = rq2[hq * 1024 + nb + rg4 + r];
    }
    float scos = 0, s2cos = 0, scov = 0, s2cov = 0, sccov = 0;
    float mp[4] = {}, rcs[4] = {}, rcv[4] = {};
    #pragma unroll 2
    for (int m0 = 0; m0 < 512; m0 += 64) {
        LOAD_KTILE(m0base + m0)
        float rk1v[4], rk2v[4], skv[4];
        #pragma unroll
        for (int j = 0; j < 4; ++j) {
            int cg = m0 + j * 16 + lr;
            rk1v[j] = rk1s[cg]; rk2v[j] = rk2s[cg]; skv[j] = sks[cg];
        }
        v4f acc[4] = {};
        #pragma unroll
        for (int j = 0; j < 4; ++j) {
            acc[j] = MFMA(aq0, b0[j], acc[j]);
            acc[j] = MFMA(aq1, b1[j], acc[j]);
        }
        #pragma unroll
        for (int j = 0; j < 4; ++j)
            #pragma unroll
            for (int r = 0; r < 4; ++r) {
                float rv = acc[j][r];
                float cosv = clampf(rv * rq1v[r] * rk1v[j], -0.95f, 0.95f);
                float x2 = rv * rq2v[r] * rk2v[j];
                float marg = fmaxf(0.01f - fmaxf(x2, -0.95f), 0.0f);
                float cov = fmaf(-Gr[r], skv[j], fmaf(Acs, rv, Pr[r]));
                scos += cosv; s2cos = fmaf(cosv, cosv, s2cos);
                scov += cov;  s2cov = fmaf(cov, cov, s2cov);
                sccov = fmaf(cosv, cov, sccov);
                mp[r] += marg; rcs[r] += cosv; rcv[r] += cov;
            }
    }
    #pragma unroll
    for (int r = 0; r < 4; ++r) {
        float m_ = mp[r], c_ = rcs[r], v_ = rcv[r];
        #pragma unroll
        for (int mk = 1; mk <= 8; mk <<= 1) {
            m_ += __shfl_xor(m_, mk);
            c_ += __shfl_xor(c_, mk);
            v_ += __shfl_xor(v_, mk);
        }
        if (lr == 0) {
            int row = hq * 1024 + nb + rg4 + r;
            vcrow[half * 32768 + row] = m_ * inv1024;
            rowcos[half * 32768 + row] = c_;
            rowcov[half * 32768 + row] = v_;
        }
    }
    for (int o = 32; o > 0; o >>= 1) {
        scos += __shfl_down(scos, o); s2cos += __shfl_down(s2cos, o);
        scov += __shfl_down(scov, o); s2cov += __shfl_down(s2cov, o);
        sccov += __shfl_down(sccov, o);
    }
    __shared__ float bs[4][5];
    if (l == 0) { bs[w][0] = scos; bs[w][1] = s2cos; bs[w][2] = scov;
                  bs[w][3] = s2cov; bs[w][4] = sccov; }
    __syncthreads();
    if (t == 0) {
        int bid = (hq * 2 + half) * 16 + blockIdx.x;
        #pragma unroll
        for (int s = 0; s < 5; ++s)
            pb[bid * 6 + s] = bs[0][s] + bs[1][s] + bs[2][s] + bs[3][s];
    }
}

// fin1: per-head sums -> hs, global scal[0..2]
__global__ __launch_bounds__(256) void k_fin1(const float* __restrict__ pb,
        const float* __restrict__ vcrow, float* __restrict__ hs,
        float* __restrict__ scal) {
    __shared__ float hsl[40];
    int t = threadIdx.x;
    int hd = t >> 5, idx = t & 31;
    double a0 = 0, a1 = 0, a2 = 0, a3 = 0, a4 = 0;
    for (int i = idx; i < 128; i += 32) {
        const float* p = &pb[(hd * 128 + i) * 6];
        a0 += p[0]; a1 += p[1]; a2 += p[2]; a3 += p[3]; a4 += p[4];
    }
    for (int m = 1; m <= 16; m <<= 1) {
        a0 += __shfl_xor(a0, m); a1 += __shfl_xor(a1, m); a2 += __shfl_xor(a2, m);
        a3 += __shfl_xor(a3, m); a4 += __shfl_xor(a4, m);
    }
    if (idx == 0) {
        hsl[hd * 5 + 0] = (float)a0; hsl[hd * 5 + 1] = (float)a1;
        hsl[hd * 5 + 2] = (float)a2; hsl[hd * 5 + 3] = (float)a3;
        hsl[hd * 5 + 4] = (float)a4;
        hs[hd * 5 + 0] = (float)a0; hs[hd * 5 + 1] = (float)a1;
        hs[hd * 5 + 2] = (float)a2; hs[hd * 5 + 3] = (float)a3;
        hs[hd * 5 + 4] = (float)a4;
    }
    double s4 = 0, s5 = 0;
    for (int i = t; i < 32768; i += 256) {
        double rm = (double)(vcrow[i] + vcrow[32768 + i]);
        s4 += rm; s5 += rm * rm;
    }
    for (int o = 32; o > 0; o >>= 1) { s4 += __shfl_down(s4, o); s5 += __shfl_down(s5, o); }
    __shared__ double red[2][4];
    int wid = t >> 6, lane = t & 63;
    if (lane == 0) { red[0][wid] = s4; red[1][wid] = s5; }
    __syncthreads();
    if (t == 0) {
        double S4 = red[0][0] + red[0][1] + red[0][2] + red[0][3];
        double S5 = red[1][0] + red[1][1] + red[1][2] + red[1][3];
        double S0 = 0, S1 = 0, S2 = 0, S3 = 0;
        for (int h2 = 0; h2 < 8; ++h2) {
            S0 += hsl[h2 * 5 + 0]; S1 += hsl[h2 * 5 + 1];
            S2 += hsl[h2 * 5 + 2]; S3 += hsl[h2 * 5 + 3];
        }
        const double cnt = 33554432.0;
        scal[0] = (float)sqrt(fmax(0.0, (S1 - S0 * S0 / cnt) / (cnt - 1.0)));
        scal[1] = (float)sqrt(fmax(0.0, (S3 - S2 * S2 / cnt) / (cnt - 1.0)));
        double V4 = S4 * 1024.0, V5 = S5 * 1024.0;
        scal[2] = (float)sqrt(fmax(0.0, (V5 - V4 * V4 / cnt) / (cnt - 1.0)));
    }
}

// finrow: per-row addc cross terms -> rp[64][3]
__global__ __launch_bounds__(256) void k_finrow(const float* __restrict__ vcrow,
        const float* __restrict__ rowcos, const float* __restrict__ rowcov,
        const float* __restrict__ wv, const float* __restrict__ scal,
        float* __restrict__ rp) {
    int t = threadIdx.x;
    float s1 = scal[0] + 1e-4f, s2v = scal[1] + 1e-4f, s3 = scal[2] + 1e-4f;
    float p1 = 0, p2 = 0, p3 = 0;
    #pragma unroll
    for (int i = 0; i < 2; ++i) {
        int row = blockIdx.x * 512 + i * 256 + t;
        int h = row >> 12;
        float fc1 = wv[h * 3] / s1;
        float fc2 = wv[h * 3 + 1] * 0.3f / s2v;
        float c3 = wv[h * 3 + 2] * 0.3f / s3;
        float a = (vcrow[row] + vcrow[32768 + row]) * c3;
        float b = fc1 * (rowcos[row] + rowcos[32768 + row])
                + fc2 * (rowcov[row] + rowcov[32768 + row]);
        p1 += a; p2 = fmaf(a, a, p2); p3 = fmaf(a, b, p3);
    }
    for (int o = 32; o > 0; o >>= 1) {
        p1 += __shfl_down(p1, o); p2 += __shfl_down(p2, o); p3 += __shfl_down(p3, o);
    }
    __shared__ float red[3][4];
    int wid = t >> 6, lane = t & 63;
    if (lane == 0) { red[0][wid] = p1; red[1][wid] = p2; red[2][wid] = p3; }
    __syncthreads();
    if (t == 0) {
        rp[blockIdx.x * 3 + 0] = red[0][0] + red[0][1] + red[0][2] + red[0][3];
        rp[blockIdx.x * 3 + 1] = red[1][0] + red[1][1] + red[1][2] + red[1][3];
        rp[blockIdx.x * 3 + 2] = red[2][0] + red[2][1] + red[2][2] + red[2][3];
    }
}

// fin2: ds via decomposition -> temp
__global__ __launch_bounds__(64) void k_fin2(const float* __restrict__ rp,
        const float* __restrict__ hs, const float* __restrict__ wv,
        float* __restrict__ scal) {
    int t = threadIdx.x;
    double p1 = rp[t * 3 + 0], p2 = rp[t * 3 + 1], p3 = rp[t * 3 + 2];
    for (int o = 32; o > 0; o >>= 1) {
        p1 += __shfl_down(p1, o); p2 += __shfl_down(p2, o); p3 += __shfl_down(p3, o);
    }
    if (t == 0) {
        double s1 = (double)scal[0] + 1e-4, s2v = (double)scal[1] + 1e-4;
        double sdd = 1024.0 * p1;
        double sdd2 = 2.0 * p3 + 1024.0 * p2;
        for (int h = 0; h < 8; ++h) {
            double fc1 = (double)wv[h * 3] / s1;
            double fc2 = (double)wv[h * 3 + 1] * 0.3 / s2v;
            sdd += fc1 * hs[h * 5 + 0] + fc2 * hs[h * 5 + 2];
            sdd2 += fc1 * fc1 * hs[h * 5 + 1] + fc2 * fc2 * hs[h * 5 + 3]
                  + 2.0 * fc1 * fc2 * hs[h * 5 + 4];
        }
        const double cnt = 33554432.0;
        double ds = sqrt(fmax(0.0, (sdd2 - sdd * sdd / cnt) / (cnt - 1.0)));
        float temp = (ds < 1e-5) ? 0.01f : ((ds < 1e-3) ? 0.05f : (0.2f + (float)ds * 2.0f));
        temp = fminf(fmaxf(temp, 0.01f), 8.0f);
        scal[3] = temp;
    }
}

// ---- one 64-key tile of the flash pass, parameterized by P buffer.
// V hi-only: 2 MFMA per j. cov clamp dropped (provably inert). ----
#define TILE_STEP(PBASE, MK)                                                   \
    {                                                                          \
        int mk = (MK);                                                         \
        v8h b0[4], b1[4];                                                      \
        _Pragma("unroll")                                                      \
        for (int j = 0; j < 4; ++j) {                                          \
            b0[j] = *(const v8h*)&K[(size_t)(mk + j * 16 + lr) * 64 + kg];     \
            b1[j] = *(const v8h*)&K[(size_t)(mk + j * 16 + lr) * 64 + 32 + kg];\
        }                                                                      \
        float rk1v[4], skv[4];                                                 \
        _Pragma("unroll")                                                      \
        for (int j = 0; j < 4; ++j) {                                          \
            int cg = mk + j * 16 + lr;                                         \
            rk1v[j] = rk1s[cg]; skv[j] = sks[cg];                              \
        }                                                                      \
        v4f acc[4] = {};                                                       \
        _Pragma("unroll")                                                      \
        for (int j = 0; j < 4; ++j) {                                          \
            acc[j] = MFMA(aq0, b0[j], acc[j]);                                 \
            acc[j] = MFMA(aq1, b1[j], acc[j]);                                 \
        }                                                                      \
        float dd[4][4];                                                        \
        float tmax[4] = { -1e30f, -1e30f, -1e30f, -1e30f };                    \
        _Pragma("unroll")                                                      \
        for (int j = 0; j < 4; ++j)                                            \
            _Pragma("unroll")                                                  \
            for (int r = 0; r < 4; ++r) {                                      \
                float rv = acc[j][r];                                          \
                float cosv = clampf(rv * rq1v[r] * rk1v[j], -0.95f, 0.95f);    \
                float cov = fmaf(-Gcr[r], skv[j], fmaf(Acs, rv, Pcr[r]));      \
                float d2 = fmaf(fc2, cov, fmaf(fc1, cosv, addc[r]));           \
                dd[j][r] = d2;                                                 \
                tmax[r] = fmaxf(tmax[r], d2);                                  \
            }                                                                  \
        v4f fv;                                                                \
        _Pragma("unroll")                                                      \
        for (int r = 0; r < 4; ++r) {                                          \
            float tm = tmax[r];                                                \
            tm = fmaxf(tm, __shfl_xor(tm, 1));                                 \
            tm = fmaxf(tm, __shfl_xor(tm, 2));                                 \
            tm = fmaxf(tm, __shfl_xor(tm, 4));                                 \
            tm = fmaxf(tm, __shfl_xor(tm, 8));                                 \
            float mnew = fmaxf(mrun[r], tm);                                   \
            float fr_ = __expf((mrun[r] - mnew) * invt);                       \
            mrun[r] = mnew;                                                    \
            rsacc[r] *= fr_;                                                   \
            fv[r] = fr_;                                                       \
        }                                                                      \
        _Pragma("unroll")                                                      \
        for (int j = 0; j < 4; ++j) accpv[j] *= fv;                            \
        _Pragma("unroll")                                                      \
        for (int j = 0; j < 4; ++j)                                            \
            _Pragma("unroll")                                                  \
            for (int r = 0; r < 4; ++r) {                                      \
                float pe = __expf((dd[j][r] - mrun[r]) * invt);                \
                f16 p16 = (f16)pe;                                             \
                rsacc[r] += (float)p16;                                        \
                (PBASE)[(w * 16 + rg4 + r) * 72 + j * 16 + lr] = p16;          \
            }                                                                  \
        v8h pa0 = *(const v8h*)&(PBASE)[(w * 16 + lr) * 72 + kg];              \
        v8h pa1 = *(const v8h*)&(PBASE)[(w * 16 + lr) * 72 + 32 + kg];         \
        _Pragma("unroll")                                                      \
        for (int j = 0; j < 4; ++j) {                                          \
            size_t vb = ((size_t)hq * 64 + j * 16 + lr) * 1024 + mk;           \
            v8h vh0 = *(const v8h*)&fvhT[vb + kg];                             \
            v8h vh1 = *(const v8h*)&fvhT[vb + 32 + kg];                        \
            accpv[j] = MFMA(pa0, vh0, accpv[j]);                               \
            accpv[j] = MFMA(pa1, vh1, accpv[j]);                               \
        }                                                                      \
    }

// pass C: recompute QK^T -> dots -> ONLINE softmax -> PV (V hi-only) -> av.
// 512 threads = 4 row-groups x 2 K-halves; Pa/Pb ping-pong; combine overlays.
__global__ __launch_bounds__(512) void k_passC(const f16* __restrict__ fq16,
        const f16* __restrict__ fk16, const float* __restrict__ rq1,
        const float* __restrict__ muq, const float* __restrict__ rk1,
        const float* __restrict__ sk, const float* __restrict__ nuacck,
        const float* __restrict__ vcrow, const float* __restrict__ wv,
        const float* __restrict__ scal,
        const f16* __restrict__ fvhT,
        f16* __restrict__ avh, f16* __restrict__ avl) {
    __shared__ __align__(16) char arena[36864];   // Pa(18432) + Pb(18432); combine overlays
    __shared__ float rk1s[1024], sks[1024];
    f16* Pa = (f16*)arena;
    f16* Pb = (f16*)(arena + 18432);
    int hq = blockIdx.y;
    int t = threadIdx.x, l = t & 63, w = t >> 6;
    int rg = w & 3, kh = w >> 2;
    int lr = l & 15, kg = (l >> 4) * 8, rg4 = (l >> 4) * 4;
    int nb = blockIdx.x * 64 + rg * 16;
    int m0base = kh * 512;
    const f16* Q = fq16 + (size_t)hq * 65536;
    const f16* K = fk16 + (size_t)hq * 65536;
    {
        int i2 = t * 2;
        *(float2*)&rk1s[i2] = *(const float2*)&rk1[hq * 1024 + i2];
        *(float2*)&sks[i2]  = *(const float2*)&sk[hq * 1024 + i2];
    }
    __syncthreads();
    v8h aq0 = *(const v8h*)&Q[(size_t)(nb + lr) * 64 + kg];
    v8h aq1 = *(const v8h*)&Q[(size_t)(nb + lr) * 64 + 32 + kg];
    const float inv1024 = 1.0f / 1024.0f;
    float uvp = nuacck[hq * 64 + l] * inv1024;
    #pragma unroll
    for (int o = 32; o > 0; o >>= 1) uvp += __shfl_xor(uvp, o);
    float uv = uvp;
    float tpv = 0.f;
    #pragma unroll
    for (int e = 0; e < 8; ++e)
        tpv += (float)aq0[e] * nuacck[hq * 64 + kg + e]
             + (float)aq1[e] * nuacck[hq * 64 + 32 + kg + e];
    tpv *= inv1024;
    tpv += __shfl_xor(tpv, 16);
    tpv += __shfl_xor(tpv, 32);
    float muv[4], tv[4];
    #pragma unroll
    for (int r = 0; r < 4; ++r) {
        muv[r] = muq[hq * 1024 + nb + rg4 + r];
        tv[r] = __shfl(tpv, rg4 + r);
    }
    const float Acs = (0.001f / 1024.0f) / 8.0001f;
    float Pcr[4], Gcr[4];
    #pragma unroll
    for (int r = 0; r < 4; ++r) {
        Gcr[r] = Acs * muv[r];
        Pcr[r] = Acs * fmaf(muv[r], uv, -tv[r]);
    }
    int h = hq >> 2;
    float s1 = scal[0] + 1e-4f, s2v = scal[1] + 1e-4f, s3 = scal[2] + 1e-4f;
    float fc1 = wv[h * 3] / s1;
    float fc2 = wv[h * 3 + 1] * 0.3f / s2v;
    float c3 = wv[h * 3 + 2] * 0.3f / s3;
    float invt = 1.0f / scal[3];
    float rq1v[4], addc[4];
    #pragma unroll
    for (int r = 0; r < 4; ++r) {
        int row = hq * 1024 + nb + rg4 + r;
        rq1v[r] = rq1[row];
        addc[r] = (vcrow[row] + vcrow[32768 + row]) * c3;
    }
    v4f accpv[4] = {};
    float rsacc[4] = {};
    float mrun[4] = { -1e30f, -1e30f, -1e30f, -1e30f };
    for (int it = 0; it < 4; ++it) {
        TILE_STEP(Pa, m0base + it * 128)
        TILE_STEP(Pb, m0base + it * 128 + 64)
    }
    __syncthreads();   // all Pa/Pb uses complete before combine overlay reuse
    #pragma unroll
    for (int r = 0; r < 4; ++r) {
        float s = rsacc[r];
        s += __shfl_xor(s, 1); s += __shfl_xor(s, 2);
        s += __shfl_xor(s, 4); s += __shfl_xor(s, 8);
        rsacc[r] = s;
    }
    float* cbacc = (float*)arena;            // [4][16][64] = 16384 B
    float* cbrs  = (float*)(arena + 16384);  // [4][4][64]  = 4096 B
    float* cbm   = (float*)(arena + 20480);  // [4][16]     = 256 B
    if (kh == 1) {
        #pragma unroll
        for (int j = 0; j < 4; ++j)
            #pragma unroll
            for (int r = 0; r < 4; ++r)
                cbacc[(rg * 16 + j * 4 + r) * 64 + l] = accpv[j][r];
        #pragma unroll
        for (int r = 0; r < 4; ++r) cbrs[(rg * 4 + r) * 64 + l] = rsacc[r];
        if (lr == 0) {
            #pragma unroll
            for (int r = 0; r < 4; ++r) cbm[rg * 16 + rg4 + r] = mrun[r];
        }
    }
    __syncthreads();
    if (kh == 0) {
        v4f f0v, f1v;
        float rinv[4];
        #pragma unroll
        for (int r = 0; r < 4; ++r) {
            float m1 = cbm[rg * 16 + rg4 + r];
            float mf = fmaxf(mrun[r], m1);
            float f0 = __expf((mrun[r] - mf) * invt);
            float f1 = __expf((m1 - mf) * invt);
            f0v[r] = f0; f1v[r] = f1;
            float rst = rsacc[r] * f0 + cbrs[(rg * 4 + r) * 64 + l] * f1;
            rinv[r] = 1.0f / rst;
        }
        #pragma unroll
        for (int j = 0; j < 4; ++j)
            #pragma unroll
            for (int r = 0; r < 4; ++r) {
                float val = (accpv[j][r] * f0v[r]
                           + cbacc[(rg * 16 + j * 4 + r) * 64 + l] * f1v[r]) * rinv[r];
                size_t idx = ((size_t)(hq * 1024 + nb + rg4 + r)) * 64 + j * 16 + lr;
                f16 hi = (f16)val;
                avh[idx] = hi;
                avl[idx] = (f16)(val - (float)hi);
            }
    }
}

// out = av @ Wout + bout (MFMA, av hi/lo x Wout hi = 2 MFMAs)
__global__ __launch_bounds__(256) void k_out_mfma(const f16* __restrict__ avh,
        const f16* __restrict__ avl,
        const f16* __restrict__ WoutTh,
        const float* __restrict__ bout, float* __restrict__ out) {
    __shared__ float red[2][4][4][4][64];
    int t = threadIdx.x, l = t & 63, w = t >> 6;
    int wc = w & 1, kh = w >> 1;
    int col0 = blockIdx.x * 128 + wc * 64;
    int tok0 = blockIdx.y * 64;
    int qi = tok0 >> 10, nb = tok0 & 1023;
    int lr = l & 15, kg = (l >> 4) * 8;
    v4f acc[4][4] = {};
    for (int ks8 = 0; ks8 < 8; ++ks8) {
        int ks = kh * 256 + ks8 * 32;
        int f = ks + kg;
        int h = f >> 6, d = f & 63;
        size_t hb = (size_t)((h << 2) + qi) * 1024;
        v8h ah[4], al4[4], bh[4];
        #pragma unroll
        for (int i = 0; i < 4; ++i) {
            int n = nb + i * 16 + lr;
            ah[i]  = *(const v8h*)&avh[(hb + n) * 64 + d];
            al4[i] = *(const v8h*)&avl[(hb + n) * 64 + d];
        }
        #pragma unroll
        for (int j = 0; j < 4; ++j)
            bh[j] = *(const v8h*)&WoutTh[(size_t)(col0 + j * 16 + lr) * 512 + ks + kg];
        #pragma unroll
        for (int i = 0; i < 4; ++i)
            #pragma unroll
            for (int j = 0; j < 4; ++j) {
                acc[i][j] = MFMA(ah[i], bh[j], acc[i][j]);
                acc[i][j] = MFMA(al4[i], bh[j], acc[i][j]);
            }
    }
    if (kh == 0) {
        #pragma unroll
        for (int i = 0; i < 4; ++i)
            #pragma unroll
            for (int j = 0; j < 4; ++j)
                #pragma unroll
                for (int r = 0; r < 4; ++r)
                    red[wc][i][j][r][l] = acc[i][j][r];
    }
    __syncthreads();
    if (kh == 1) {
        #pragma unroll
        for (int i = 0; i < 4; ++i)
            #pragma unroll
            for (int j = 0; j < 4; ++j) {
                int col = col0 + j * 16 + lr;
                float bo = bout[col];
                #pragma unroll
                for (int r = 0; r < 4; ++r) {
                    float val = acc[i][j][r] + red[wc][i][j][r][l] + bo;
                    int token = tok0 + i * 16 + (l >> 4) * 4 + r;
                    out[(size_t)token * 512 + col] = val;
                }
            }
    }
}

extern "C" void kernel_launch(void* const* d_in, const int* in_sizes, int n_in,
                              void* d_out, int out_size, void* d_ws, size_t ws_size,
                              hipStream_t stream) {
    const float* q     = (const float*)d_in[0];
    const float* k     = (const float*)d_in[1];
    const float* v     = (const float*)d_in[2];
    const float* ln_w  = (const float*)d_in[3];
    const float* ln_b  = (const float*)d_in[4];
    const float* W_in  = (const float*)d_in[5];
    const float* W_out = (const float*)d_in[6];
    const float* b_out = (const float*)d_in[7];
    const float* wp_W1 = (const float*)d_in[8];
    const float* wp_b1 = (const float*)d_in[9];
    const float* wp_lw = (const float*)d_in[10];
    const float* wp_lb = (const float*)d_in[11];
    const float* wp_W2 = (const float*)d_in[12];
    const float* wp_b2 = (const float*)d_in[13];
    const float* wp_W3 = (const float*)d_in[14];
    const float* wp_b3 = (const float*)d_in[15];
    const float* wp_W4 = (const float*)d_in[16];
    const float* wp_b4 = (const float*)d_in[17];
    const float* wtemp = (const float*)d_in[18];

    float* ws = (float*)d_ws;
    f16* ln16     = (f16*)(ws + OFF_LN16);
    f16* fq16     = (f16*)(ws + OFF_FQ16);
    f16* fk16     = (f16*)(ws + OFF_FK16);
    f16* fvhT     = (f16*)(ws + OFF_FVHT);
    f16* WinTh    = (f16*)(ws + OFF_WINTH);
    f16* WoutTh   = (f16*)(ws + OFF_WOUTTH);
    f16* avh      = (f16*)(ws + OFF_AVH);
    f16* avl      = (f16*)(ws + OFF_AVL);
    float* rq1    = ws + OFF_RQ1;
    float* rq2    = ws + OFF_RQ2;
    float* muq    = ws + OFF_MUQ;
    float* rk1    = ws + OFF_RK1;
    float* rk2    = ws + OFF_RK2;
    float* sk     = ws + OFF_SK;
    float* vcrow  = ws + OFF_VC;
    float* rowcos = ws + OFF_ROWCOS;
    float* rowcov = ws + OFF_ROWCOV;
    float* nuacck = ws + OFF_NUACC;
    float* pb     = ws + OFF_PB;
    float* hs     = ws + OFF_HS;
    float* rp     = ws + OFF_RP;
    float* feat   = ws + OFF_FEAT;
    float* wv     = ws + OFF_WV;
    float* scal   = ws + OFF_SCAL;

    k_zero<<<8, 256, 0, stream>>>(feat, nuacck);
    k_wprep<<<dim3(8, 8, 2), 256, 0, stream>>>(W_in, W_out, WinTh, WoutTh);
    k_ln16<<<3072, 256, 0, stream>>>(q, k, v, ln_w, ln_b, ln16);
    k_proj_all<<<dim3(4, 32, 3), 256, 0, stream>>>(ln16, WinTh,
            fq16, fk16, fvhT, rq1, rq2, muq, rk1, rk2, sk, feat, nuacck);
    k_mlp<<<8, 256, 0, stream>>>(feat, wp_W1, wp_b1, wp_lw, wp_lb,
                                 wp_W2, wp_b2, wp_W3, wp_b3, wp_W4, wp_b4,
                                 wtemp, wv);
    k_passA<<<dim3(16, 2, 32), 256, 0, stream>>>(fq16, fk16, rq1, rq2, muq, rk1, rk2,
                                                 sk, nuacck, vcrow, rowcos, rowcov, pb);
    k_fin1<<<1, 256, 0, stream>>>(pb, vcrow, hs, scal);
    k_finrow<<<64, 256, 0, stream>>>(vcrow, rowcos, rowcov, wv, scal, rp);
    k_fin2<<<1, 64, 0, stream>>>(rp, hs, wv, scal);
    k_passC<<<dim3(16, 32), 512, 0, stream>>>(fq16, fk16, rq1, muq, rk1, sk, nuacck,
                                              vcrow, wv, scal, fvhT, avh, avl);
    k_out_mfma<<<dim3(4, 64), 256, 0, stream>>>(avh, avl, WoutTh, b_out,
                                                (float*)d_out);
}

// Round 16
// 248.741 us; speedup vs baseline: 1.2120x; 1.0536x over previous
//
#include <hip/hip_runtime.h>
#include <math.h>

typedef _Float16 f16;
typedef _Float16 v8h __attribute__((ext_vector_type(8)));
typedef _Float16 v4h __attribute__((ext_vector_type(4)));
typedef float    v4f __attribute__((ext_vector_type(4)));

#define MFMA(a, b, c) __builtin_amdgcn_mfma_f32_16x16x32_f16((a), (b), (c), 0, 0, 0)

// ---------------- workspace layout (float offsets) ----------------
#define OFF_LN16    0u
#define OFF_FQ16    4194304u
#define OFF_FK16    5242880u
#define OFF_FVHT    6291456u
#define OFF_WINTH   8388608u
#define OFF_WOUTTH  8650752u
#define OFF_AVH     8912896u
#define OFF_AVL     9961472u
#define OFF_RQ1     11010048u
#define OFF_RQ2     11042816u
#define OFF_MUQ     11075584u
#define OFF_RK1     11108352u
#define OFF_RK2     11141120u
#define OFF_SK      11173888u
#define OFF_VC      11206656u   // 65536 (2 halves)
#define OFF_ROWCOS  11272192u   // 2 halves
#define OFF_ROWCOV  11337728u   // 2 halves
#define OFF_NUACC   11403264u   // 2048
#define OFF_PB      11405312u   // 1024*6
#define OFF_HS      11411456u   // 64
#define OFF_RP      11411520u   // 192
#define OFF_FEAT    11411712u   // 1024
#define OFF_WV      11412736u   // 24
#define OFF_SCAL    11412760u   // 8
#define OFF_MAXC    11412768u   // 65536 (2 halves)
#define OFF_MAXV    11478304u   // 65536 (2 halves)

__device__ __forceinline__ float clampf(float x, float lo, float hi) {
    return fminf(fmaxf(x, lo), hi);
}

__global__ void k_zero(float* feat, float* nuacck) {
    int i = blockIdx.x * 256 + threadIdx.x;
    if (i < 1024) feat[i] = 0.0f;
    if (i < 2048) nuacck[i] = 0.0f;
}

// transpose of a 512x512 weight to f16: W[k][c] -> WT[c][k] (hi only)
__global__ __launch_bounds__(256) void k_wprep(const float* __restrict__ Win,
        const float* __restrict__ Wout, f16* __restrict__ WinTh,
        f16* __restrict__ WoutTh) {
    __shared__ float lds[64][68];
    const float* W = blockIdx.z ? Wout : Win;
    f16* Th = blockIdx.z ? WoutTh : WinTh;
    int k0 = blockIdx.y * 64, c0 = blockIdx.x * 64;
    int t = threadIdx.x;
    #pragma unroll
    for (int p = 0; p < 4; ++p) {
        int flat = p * 1024 + t * 4;
        int r = flat >> 6, c = flat & 63;
        *(float4*)&lds[r][c] = *(const float4*)&W[(size_t)(k0 + r) * 512 + c0 + c];
    }
    __syncthreads();
    int c = t >> 2, kk = (t & 3) * 16;
    #pragma unroll
    for (int half = 0; half < 2; ++half) {
        v8h h8;
        #pragma unroll
        for (int ii = 0; ii < 8; ++ii)
            h8[ii] = (f16)lds[kk + half * 8 + ii][c];
        *(v8h*)&Th[(size_t)(c0 + c) * 512 + k0 + kk + half * 8] = h8;
    }
}

// LayerNorm all 12288 tokens -> ln16 f16
__global__ __launch_bounds__(256) void k_ln16(const float* __restrict__ q,
        const float* __restrict__ kk, const float* __restrict__ v,
        const float* __restrict__ lnw, const float* __restrict__ lnb,
        f16* __restrict__ ln16) {
    int t = threadIdx.x, wid = t >> 6, lane = t & 63;
    int token = blockIdx.x * 4 + wid;
    int inp = token >> 12, lt = token & 4095;
    const float* xp = (inp == 0) ? q : ((inp == 1) ? kk : v);
    const float4* xr = (const float4*)(xp + (size_t)lt * 512);
    float4 a = xr[lane], b = xr[lane + 64];
    float s = a.x + a.y + a.z + a.w + b.x + b.y + b.z + b.w;
    float s2 = a.x*a.x + a.y*a.y + a.z*a.z + a.w*a.w
             + b.x*b.x + b.y*b.y + b.z*b.z + b.w*b.w;
    for (int o = 32; o > 0; o >>= 1) { s += __shfl_down(s, o); s2 += __shfl_down(s2, o); }
    float m_ = __shfl(s, 0) * (1.0f / 512.0f);
    float var = __shfl(s2, 0) * (1.0f / 512.0f) - m_ * m_;
    var = fmaxf(var, 0.0f);
    float rs = rsqrtf(var + 1e-5f);
    const float4* w4 = (const float4*)lnw;
    const float4* b4 = (const float4*)lnb;
    float4 wa = w4[lane], wb = w4[lane + 64], ba = b4[lane], bb = b4[lane + 64];
    f16* orow = ln16 + (size_t)token * 512;
    v4h ha, hb;
    ha[0] = (f16)((a.x - m_) * rs * wa.x + ba.x);
    ha[1] = (f16)((a.y - m_) * rs * wa.y + ba.y);
    ha[2] = (f16)((a.z - m_) * rs * wa.z + ba.z);
    ha[3] = (f16)((a.w - m_) * rs * wa.w + ba.w);
    hb[0] = (f16)((b.x - m_) * rs * wb.x + bb.x);
    hb[1] = (f16)((b.y - m_) * rs * wb.y + bb.y);
    hb[2] = (f16)((b.z - m_) * rs * wb.z + bb.z);
    hb[3] = (f16)((b.w - m_) * rs * wb.w + bb.w);
    *(v4h*)&orow[lane * 4] = ha;
    *(v4h*)&orow[lane * 4 + 256] = hb;
}

// LN16 @ Win (MFMA), single-precision f16 path for all modes.
// MODE 0: q (fq16 + recip stats). MODE 1: k. MODE 2: v (transposed write).
template<int MODE>
__device__ __forceinline__ void proj_body(const f16* __restrict__ A16,
        const f16* __restrict__ BTh,
        f16* __restrict__ fout16, f16* __restrict__ fhT,
        float* __restrict__ oA, float* __restrict__ oB, float* __restrict__ oC,
        float* __restrict__ feat, float* __restrict__ nuacck) {
    int t = threadIdx.x, l = t & 63, w = t >> 6;
    int wr = w >> 1, wc = w & 1;
    int col0 = blockIdx.x * 128 + wc * 64;
    int tok0 = blockIdx.y * 128 + wr * 64;
    int lr = l & 15, kg = (l >> 4) * 8;
    int rg4 = (l >> 4) * 4;
    v4f acc[4][4] = {};
    for (int ks = 0; ks < 512; ks += 32) {
        v8h a[4], b[4];
        #pragma unroll
        for (int i = 0; i < 4; ++i)
            a[i] = *(const v8h*)&A16[(size_t)(tok0 + i * 16 + lr) * 512 + ks + kg];
        #pragma unroll
        for (int j = 0; j < 4; ++j)
            b[j] = *(const v8h*)&BTh[(size_t)(col0 + j * 16 + lr) * 512 + ks + kg];
        #pragma unroll
        for (int i = 0; i < 4; ++i)
            #pragma unroll
            for (int j = 0; j < 4; ++j)
                acc[i][j] = MFMA(a[i], b[j], acc[i][j]);
    }
    int h = col0 >> 6;
    #pragma unroll
    for (int i = 0; i < 4; ++i)
        #pragma unroll
        for (int j = 0; j < 4; ++j)
            #pragma unroll
            for (int r = 0; r < 4; ++r) {
                int token = tok0 + i * 16 + rg4 + r;
                int d = j * 16 + lr;
                int qi = token >> 10, n = token & 1023;
                float val = acc[i][j][r];
                if constexpr (MODE != 2) {
                    fout16[((size_t)((h << 2) + qi) * 1024 + n) * 64 + d] = (f16)val;
                } else {
                    fhT[((size_t)((h << 2) + qi) * 64 + d) * 1024 + n] = (f16)val;
                }
            }
    if constexpr (MODE != 2) {
        #pragma unroll
        for (int i = 0; i < 4; ++i)
            #pragma unroll
            for (int r = 0; r < 4; ++r) {
                float s = 0.f, s2 = 0.f;
                #pragma unroll
                for (int j = 0; j < 4; ++j) { float v = acc[i][j][r]; s += v; s2 += v * v; }
                #pragma unroll
                for (int mk = 1; mk <= 8; mk <<= 1) {
                    s += __shfl_xor(s, mk); s2 += __shfl_xor(s2, mk);
                }
                if (lr == 0) {
                    int token = tok0 + i * 16 + rg4 + r;
                    int qi = token >> 10, n = token & 1023;
                    int row = ((h << 2) + qi) * 1024 + n;
                    float nv = sqrtf(s2);
                    oA[row] = 1.0f / (nv + 1e-6f);
                    oB[row] = 1.0f / fmaxf(nv, 1e-4f);
                    oC[row] = (MODE == 0) ? s * (1.0f / 64.0f) : s;
                }
            }
        float cs[4];
        #pragma unroll
        for (int j = 0; j < 4; ++j) {
            float c = 0.f;
            #pragma unroll
            for (int i = 0; i < 4; ++i)
                #pragma unroll
                for (int r = 0; r < 4; ++r) c += acc[i][j][r];
            c += __shfl_xor(c, 16); c += __shfl_xor(c, 32);
            cs[j] = c;
        }
        if (l < 16) {
            #pragma unroll
            for (int j = 0; j < 4; ++j)
                atomicAdd(&feat[h * 128 + (MODE == 1 ? 64 : 0) + j * 16 + l],
                          cs[j] * (1.0f / 4096.0f));
            if constexpr (MODE == 1) {
                int qi = tok0 >> 10;
                #pragma unroll
                for (int j = 0; j < 4; ++j)
                    atomicAdd(&nuacck[((h << 2) + qi) * 64 + j * 16 + l], cs[j]);
            }
        }
    }
}

__global__ __launch_bounds__(256) void k_proj_all(const f16* __restrict__ ln16,
        const f16* __restrict__ BTh,
        f16* __restrict__ fq16, f16* __restrict__ fk16,
        f16* __restrict__ fvhT,
        float* __restrict__ rq1, float* __restrict__ rq2, float* __restrict__ muq,
        float* __restrict__ rk1, float* __restrict__ rk2, float* __restrict__ sk,
        float* __restrict__ feat, float* __restrict__ nuacck) {
    int mode = blockIdx.z;
    if (mode == 0)
        proj_body<0>(ln16, BTh, fq16, nullptr, rq1, rq2, muq, feat, nullptr);
    else if (mode == 1)
        proj_body<1>(ln16 + 2097152u, BTh, fk16, nullptr, rk1, rk2, sk, feat, nuacck);
    else
        proj_body<2>(ln16 + 4194304u, BTh, nullptr, fvhT,
                     nullptr, nullptr, nullptr, nullptr, nullptr);
}

// tiny MLP weight predictor, one block per head -> wv[h][3]
__global__ __launch_bounds__(256) void k_mlp(const float* __restrict__ feat,
        const float* __restrict__ W1, const float* __restrict__ b1,
        const float* __restrict__ lw, const float* __restrict__ lb,
        const float* __restrict__ W2, const float* __restrict__ b2,
        const float* __restrict__ W3, const float* __restrict__ b3,
        const float* __restrict__ W4, const float* __restrict__ b4,
        const float* __restrict__ wtemp, float* wv) {
    __shared__ float h1[256], h2[192], h3[64], red[8];
    int t = threadIdx.x;
    int h = blockIdx.x;
    float p = 0.0f;
    for (int i = 0; i < 128; ++i) p += feat[h * 128 + i] * W1[i * 256 + t];
    p += b1[t];
    float s = p, s2 = p * p;
    for (int o = 32; o > 0; o >>= 1) { s += __shfl_down(s, o); s2 += __shfl_down(s2, o); }
    if ((t & 63) == 0) { red[t >> 6] = s; red[4 + (t >> 6)] = s2; }
    __syncthreads();
    float S = red[0] + red[1] + red[2] + red[3];
    float S2 = red[4] + red[5] + red[6] + red[7];
    float mu = S / 256.0f;
    float var = S2 / 256.0f - mu * mu; if (var < 0.0f) var = 0.0f;
    float xh = (p - mu) * rsqrtf(var + 1e-5f) * lw[t] + lb[t];
    h1[t] = fmaxf(xh, 0.0f);
    __syncthreads();
    if (t < 192) {
        float a = 0.0f;
        for (int i = 0; i < 256; ++i) a += h1[i] * W2[i * 192 + t];
        h2[t] = fmaxf(a + b2[t], 0.0f);
    }
    __syncthreads();
    if (t < 64) {
        float a = 0.0f;
        for (int i = 0; i < 192; ++i) a += h2[i] * W3[i * 64 + t];
        h3[t] = fmaxf(a + b3[t], 0.0f);
    }
    __syncthreads();
    if (t == 0) {
        float lg[3];
        for (int j = 0; j < 3; ++j) {
            float a = 0.0f;
            for (int i = 0; i < 64; ++i) a += h3[i] * W4[i * 3 + j];
            lg[j] = a + b4[j];
        }
        float mx = fmaxf(lg[0], fmaxf(lg[1], lg[2]));
        float e0 = expf(lg[0] - mx), e1 = expf(lg[1] - mx), e2 = expf(lg[2] - mx);
        float se = e0 + e1 + e2;
        float pr0 = e0 / se, pr1 = e1 / se, pr2 = e2 / se;
        float wt = wtemp[0]; wt = fminf(fmaxf(wt, 0.01f), 1.0f);
        float q0 = pr0 / wt, q1 = pr1 / wt, q2 = pr2 / wt;
        float m2 = fmaxf(q0, fmaxf(q1, q2));
        float f0 = expf(q0 - m2), f1 = expf(q1 - m2), f2 = expf(q2 - m2);
        float sf = f0 + f1 + f2; f0 /= sf; f1 /= sf; f2 /= sf;
        f0 = fminf(fmaxf(f0, 0.01f), 0.95f);
        f1 = fminf(fmaxf(f1, 0.01f), 0.95f);
        f2 = fminf(fmaxf(f2, 0.01f), 0.95f);
        float sw = f0 + f1 + f2;
        wv[h * 3 + 0] = f0 / sw; wv[h * 3 + 1] = f1 / sw; wv[h * 3 + 2] = f2 / sw;
    }
}

// ---- shared per-pass preamble for passA: grid (16, 2, 32) ----
#define PASS_PREAMBLE_AB                                                       \
    int hq = blockIdx.z;                                                       \
    int half = blockIdx.y;                                                     \
    int m0base = half * 512;                                                   \
    int t = threadIdx.x, l = t & 63, w = t >> 6;                               \
    int lr = l & 15, kg = (l >> 4) * 8, rg4 = (l >> 4) * 4;                    \
    int nb = blockIdx.x * 64 + w * 16;                                         \
    const f16* Q = fq16 + (size_t)hq * 65536;                                  \
    const f16* K = fk16 + (size_t)hq * 65536;                                  \
    v8h aq0 = *(const v8h*)&Q[(size_t)(nb + lr) * 64 + kg];                    \
    v8h aq1 = *(const v8h*)&Q[(size_t)(nb + lr) * 64 + 32 + kg];               \
    const float inv1024 = 1.0f / 1024.0f;                                      \
    float uvp = nuacck[hq * 64 + l] * inv1024;                                 \
    _Pragma("unroll")                                                          \
    for (int o = 32; o > 0; o >>= 1) uvp += __shfl_xor(uvp, o);                \
    float uv = uvp;                                                            \
    float tp = 0.f;                                                            \
    _Pragma("unroll")                                                          \
    for (int e = 0; e < 8; ++e)                                                \
        tp += (float)aq0[e] * nuacck[hq * 64 + kg + e]                         \
            + (float)aq1[e] * nuacck[hq * 64 + 32 + kg + e];                   \
    tp *= inv1024;                                                             \
    tp += __shfl_xor(tp, 16);                                                  \
    tp += __shfl_xor(tp, 32);                                                  \
    float muv[4], tv[4];                                                       \
    _Pragma("unroll")                                                          \
    for (int r = 0; r < 4; ++r) {                                              \
        muv[r] = muq[hq * 1024 + nb + rg4 + r];                                \
        tv[r] = __shfl(tp, rg4 + r);                                           \
    }                                                                          \
    const float Acs = (0.001f / 1024.0f) / 8.0001f;                            \
    float Pr[4], Gr[4];                                                        \
    _Pragma("unroll")                                                          \
    for (int r = 0; r < 4; ++r) {                                              \
        Gr[r] = Acs * muv[r];                                                  \
        Pr[r] = Acs * fmaf(muv[r], uv, -tv[r]);                                \
    }

#define LOAD_KTILE(m0a)                                                        \
    v8h b0[4], b1[4];                                                          \
    _Pragma("unroll")                                                          \
    for (int j = 0; j < 4; ++j) {                                              \
        b0[j] = *(const v8h*)&K[(size_t)((m0a) + j * 16 + lr) * 64 + kg];      \
        b1[j] = *(const v8h*)&K[(size_t)((m0a) + j * 16 + lr) * 64 + 32 + kg]; \
    }

// pass A: cos/cov global+cross sums, per-row sums AND maxes, margin means
__global__ __launch_bounds__(256) void k_passA(const f16* __restrict__ fq16,
        const f16* __restrict__ fk16, const float* __restrict__ rq1,
        const float* __restrict__ rq2, const float* __restrict__ muq,
        const float* __restrict__ rk1, const float* __restrict__ rk2,
        const float* __restrict__ sk, const float* __restrict__ nuacck,
        float* __restrict__ vcrow, float* __restrict__ rowcos,
        float* __restrict__ rowcov, float* __restrict__ maxc,
        float* __restrict__ maxv, float* __restrict__ pb) {
    __shared__ float rk1s[512], rk2s[512], sks[512];
    PASS_PREAMBLE_AB
    {
        int i2 = t * 2;
        *(float2*)&rk1s[i2] = *(const float2*)&rk1[hq * 1024 + m0base + i2];
        *(float2*)&rk2s[i2] = *(const float2*)&rk2[hq * 1024 + m0base + i2];
        *(float2*)&sks[i2]  = *(const float2*)&sk[hq * 1024 + m0base + i2];
    }
    __syncthreads();
    float rq1v[4], rq2v[4];
    #pragma unroll
    for (int r = 0; r < 4; ++r) {
        rq1v[r] = rq1[hq * 1024 + nb + rg4 + r];
        rq2v[r] = rq2[hq * 1024 + nb + rg4 + r];
    }
    float scos = 0, s2cos = 0, scov = 0, s2cov = 0, sccov = 0;
    float mp[4] = {}, rcs[4] = {}, rcv[4] = {};
    float mcs[4] = { -1e30f, -1e30f, -1e30f, -1e30f };
    float mcv[4] = { -1e30f, -1e30f, -1e30f, -1e30f };
    #pragma unroll 2
    for (int m0 = 0; m0 < 512; m0 += 64) {
        LOAD_KTILE(m0base + m0)
        float rk1v[4], rk2v[4], skv[4];
        #pragma unroll
        for (int j = 0; j < 4; ++j) {
            int cg = m0 + j * 16 + lr;
            rk1v[j] = rk1s[cg]; rk2v[j] = rk2s[cg]; skv[j] = sks[cg];
        }
        v4f acc[4] = {};
        #pragma unroll
        for (int j = 0; j < 4; ++j) {
            acc[j] = MFMA(aq0, b0[j], acc[j]);
            acc[j] = MFMA(aq1, b1[j], acc[j]);
        }
        #pragma unroll
        for (int j = 0; j < 4; ++j)
            #pragma unroll
            for (int r = 0; r < 4; ++r) {
                float rv = acc[j][r];
                float cosv = clampf(rv * rq1v[r] * rk1v[j], -0.95f, 0.95f);
                float x2 = rv * rq2v[r] * rk2v[j];
                float marg = fmaxf(0.01f - fmaxf(x2, -0.95f), 0.0f);
                float cov = fmaf(-Gr[r], skv[j], fmaf(Acs, rv, Pr[r]));
                scos += cosv; s2cos = fmaf(cosv, cosv, s2cos);
                scov += cov;  s2cov = fmaf(cov, cov, s2cov);
                sccov = fmaf(cosv, cov, sccov);
                mp[r] += marg; rcs[r] += cosv; rcv[r] += cov;
                mcs[r] = fmaxf(mcs[r], cosv);
                mcv[r] = fmaxf(mcv[r], cov);
            }
    }
    #pragma unroll
    for (int r = 0; r < 4; ++r) {
        float m_ = mp[r], c_ = rcs[r], v_ = rcv[r];
        float xc = mcs[r], xv = mcv[r];
        #pragma unroll
        for (int mk = 1; mk <= 8; mk <<= 1) {
            m_ += __shfl_xor(m_, mk);
            c_ += __shfl_xor(c_, mk);
            v_ += __shfl_xor(v_, mk);
            xc = fmaxf(xc, __shfl_xor(xc, mk));
            xv = fmaxf(xv, __shfl_xor(xv, mk));
        }
        if (lr == 0) {
            int row = hq * 1024 + nb + rg4 + r;
            vcrow[half * 32768 + row] = m_ * inv1024;
            rowcos[half * 32768 + row] = c_;
            rowcov[half * 32768 + row] = v_;
            maxc[half * 32768 + row] = xc;
            maxv[half * 32768 + row] = xv;
        }
    }
    for (int o = 32; o > 0; o >>= 1) {
        scos += __shfl_down(scos, o); s2cos += __shfl_down(s2cos, o);
        scov += __shfl_down(scov, o); s2cov += __shfl_down(s2cov, o);
        sccov += __shfl_down(sccov, o);
    }
    __shared__ float bs[4][5];
    if (l == 0) { bs[w][0] = scos; bs[w][1] = s2cos; bs[w][2] = scov;
                  bs[w][3] = s2cov; bs[w][4] = sccov; }
    __syncthreads();
    if (t == 0) {
        int bid = (hq * 2 + half) * 16 + blockIdx.x;
        #pragma unroll
        for (int s = 0; s < 5; ++s)
            pb[bid * 6 + s] = bs[0][s] + bs[1][s] + bs[2][s] + bs[3][s];
    }
}

// fin1: per-head sums -> hs, global scal[0..2]
__global__ __launch_bounds__(256) void k_fin1(const float* __restrict__ pb,
        const float* __restrict__ vcrow, float* __restrict__ hs,
        float* __restrict__ scal) {
    __shared__ float hsl[40];
    int t = threadIdx.x;
    int hd = t >> 5, idx = t & 31;
    double a0 = 0, a1 = 0, a2 = 0, a3 = 0, a4 = 0;
    for (int i = idx; i < 128; i += 32) {
        const float* p = &pb[(hd * 128 + i) * 6];
        a0 += p[0]; a1 += p[1]; a2 += p[2]; a3 += p[3]; a4 += p[4];
    }
    for (int m = 1; m <= 16; m <<= 1) {
        a0 += __shfl_xor(a0, m); a1 += __shfl_xor(a1, m); a2 += __shfl_xor(a2, m);
        a3 += __shfl_xor(a3, m); a4 += __shfl_xor(a4, m);
    }
    if (idx == 0) {
        hsl[hd * 5 + 0] = (float)a0; hsl[hd * 5 + 1] = (float)a1;
        hsl[hd * 5 + 2] = (float)a2; hsl[hd * 5 + 3] = (float)a3;
        hsl[hd * 5 + 4] = (float)a4;
        hs[hd * 5 + 0] = (float)a0; hs[hd * 5 + 1] = (float)a1;
        hs[hd * 5 + 2] = (float)a2; hs[hd * 5 + 3] = (float)a3;
        hs[hd * 5 + 4] = (float)a4;
    }
    double s4 = 0, s5 = 0;
    for (int i = t; i < 32768; i += 256) {
        double rm = (double)(vcrow[i] + vcrow[32768 + i]);
        s4 += rm; s5 += rm * rm;
    }
    for (int o = 32; o > 0; o >>= 1) { s4 += __shfl_down(s4, o); s5 += __shfl_down(s5, o); }
    __shared__ double red[2][4];
    int wid = t >> 6, lane = t & 63;
    if (lane == 0) { red[0][wid] = s4; red[1][wid] = s5; }
    __syncthreads();
    if (t == 0) {
        double S4 = red[0][0] + red[0][1] + red[0][2] + red[0][3];
        double S5 = red[1][0] + red[1][1] + red[1][2] + red[1][3];
        double S0 = 0, S1 = 0, S2 = 0, S3 = 0;
        for (int h2 = 0; h2 < 8; ++h2) {
            S0 += hsl[h2 * 5 + 0]; S1 += hsl[h2 * 5 + 1];
            S2 += hsl[h2 * 5 + 2]; S3 += hsl[h2 * 5 + 3];
        }
        const double cnt = 33554432.0;
        scal[0] = (float)sqrt(fmax(0.0, (S1 - S0 * S0 / cnt) / (cnt - 1.0)));
        scal[1] = (float)sqrt(fmax(0.0, (S3 - S2 * S2 / cnt) / (cnt - 1.0)));
        double V4 = S4 * 1024.0, V5 = S5 * 1024.0;
        scal[2] = (float)sqrt(fmax(0.0, (V5 - V4 * V4 / cnt) / (cnt - 1.0)));
    }
}

// finrow: per-row addc cross terms -> rp[64][3]
__global__ __launch_bounds__(256) void k_finrow(const float* __restrict__ vcrow,
        const float* __restrict__ rowcos, const float* __restrict__ rowcov,
        const float* __restrict__ wv, const float* __restrict__ scal,
        float* __restrict__ rp) {
    int t = threadIdx.x;
    float s1 = scal[0] + 1e-4f, s2v = scal[1] + 1e-4f, s3 = scal[2] + 1e-4f;
    float p1 = 0, p2 = 0, p3 = 0;
    #pragma unroll
    for (int i = 0; i < 2; ++i) {
        int row = blockIdx.x * 512 + i * 256 + t;
        int h = row >> 12;
        float fc1 = wv[h * 3] / s1;
        float fc2 = wv[h * 3 + 1] * 0.3f / s2v;
        float c3 = wv[h * 3 + 2] * 0.3f / s3;
        float a = (vcrow[row] + vcrow[32768 + row]) * c3;
        float b = fc1 * (rowcos[row] + rowcos[32768 + row])
                + fc2 * (rowcov[row] + rowcov[32768 + row]);
        p1 += a; p2 = fmaf(a, a, p2); p3 = fmaf(a, b, p3);
    }
    for (int o = 32; o > 0; o >>= 1) {
        p1 += __shfl_down(p1, o); p2 += __shfl_down(p2, o); p3 += __shfl_down(p3, o);
    }
    __shared__ float red[3][4];
    int wid = t >> 6, lane = t & 63;
    if (lane == 0) { red[0][wid] = p1; red[1][wid] = p2; red[2][wid] = p3; }
    __syncthreads();
    if (t == 0) {
        rp[blockIdx.x * 3 + 0] = red[0][0] + red[0][1] + red[0][2] + red[0][3];
        rp[blockIdx.x * 3 + 1] = red[1][0] + red[1][1] + red[1][2] + red[1][3];
        rp[blockIdx.x * 3 + 2] = red[2][0] + red[2][1] + red[2][2] + red[2][3];
    }
}

// fin2: ds via decomposition -> temp
__global__ __launch_bounds__(64) void k_fin2(const float* __restrict__ rp,
        const float* __restrict__ hs, const float* __restrict__ wv,
        float* __restrict__ scal) {
    int t = threadIdx.x;
    double p1 = rp[t * 3 + 0], p2 = rp[t * 3 + 1], p3 = rp[t * 3 + 2];
    for (int o = 32; o > 0; o >>= 1) {
        p1 += __shfl_down(p1, o); p2 += __shfl_down(p2, o); p3 += __shfl_down(p3, o);
    }
    if (t == 0) {
        double s1 = (double)scal[0] + 1e-4, s2v = (double)scal[1] + 1e-4;
        double sdd = 1024.0 * p1;
        double sdd2 = 2.0 * p3 + 1024.0 * p2;
        for (int h = 0; h < 8; ++h) {
            double fc1 = (double)wv[h * 3] / s1;
            double fc2 = (double)wv[h * 3 + 1] * 0.3 / s2v;
            sdd += fc1 * hs[h * 5 + 0] + fc2 * hs[h * 5 + 2];
            sdd2 += fc1 * fc1 * hs[h * 5 + 1] + fc2 * fc2 * hs[h * 5 + 3]
                  + 2.0 * fc1 * fc2 * hs[h * 5 + 4];
        }
        const double cnt = 33554432.0;
        double ds = sqrt(fmax(0.0, (sdd2 - sdd * sdd / cnt) / (cnt - 1.0)));
        float temp = (ds < 1e-5) ? 0.01f : ((ds < 1e-3) ? 0.05f : (0.2f + (float)ds * 2.0f));
        temp = fminf(fmaxf(temp, 0.01f), 8.0f);
        scal[3] = temp;
    }
}

// ---- one 64-key tile of the pass-C loop with STATIC row bound mxr:
// no online max, no rescale; P = exp(dd*invt - mxr). ----
#define TILE_STEP(PBASE, MK)                                                   \
    {                                                                          \
        int mk = (MK);                                                         \
        v8h b0[4], b1[4];                                                      \
        _Pragma("unroll")                                                      \
        for (int j = 0; j < 4; ++j) {                                          \
            b0[j] = *(const v8h*)&K[(size_t)(mk + j * 16 + lr) * 64 + kg];     \
            b1[j] = *(const v8h*)&K[(size_t)(mk + j * 16 + lr) * 64 + 32 + kg];\
        }                                                                      \
        float rk1v[4], skv[4];                                                 \
        _Pragma("unroll")                                                      \
        for (int j = 0; j < 4; ++j) {                                          \
            int cg = mk + j * 16 + lr;                                         \
            rk1v[j] = rk1s[cg]; skv[j] = sks[cg];                              \
        }                                                                      \
        v4f acc[4] = {};                                                       \
        _Pragma("unroll")                                                      \
        for (int j = 0; j < 4; ++j) {                                          \
            acc[j] = MFMA(aq0, b0[j], acc[j]);                                 \
            acc[j] = MFMA(aq1, b1[j], acc[j]);                                 \
        }                                                                      \
        _Pragma("unroll")                                                      \
        for (int j = 0; j < 4; ++j)                                            \
            _Pragma("unroll")                                                  \
            for (int r = 0; r < 4; ++r) {                                      \
                float rv = acc[j][r];                                          \
                float cosv = clampf(rv * rq1v[r] * rk1v[j], -0.95f, 0.95f);    \
                float cov = fmaf(-Gcr[r], skv[j], fmaf(Acs, rv, Pcr[r]));      \
                float d2 = fmaf(fc2, cov, fmaf(fc1, cosv, addc[r]));           \
                float pe = __expf(fmaf(d2, invt, -mxr[r]));                    \
                f16 p16 = (f16)pe;                                             \
                rsacc[r] += (float)p16;                                        \
                (PBASE)[(w * 16 + rg4 + r) * 72 + j * 16 + lr] = p16;          \
            }                                                                  \
        v8h pa0 = *(const v8h*)&(PBASE)[(w * 16 + lr) * 72 + kg];              \
        v8h pa1 = *(const v8h*)&(PBASE)[(w * 16 + lr) * 72 + 32 + kg];         \
        _Pragma("unroll")                                                      \
        for (int j = 0; j < 4; ++j) {                                          \
            size_t vb = ((size_t)hq * 64 + j * 16 + lr) * 1024 + mk;           \
            v8h vh0 = *(const v8h*)&fvhT[vb + kg];                             \
            v8h vh1 = *(const v8h*)&fvhT[vb + 32 + kg];                        \
            accpv[j] = MFMA(pa0, vh0, accpv[j]);                               \
            accpv[j] = MFMA(pa1, vh1, accpv[j]);                               \
        }                                                                      \
    }

// pass C: QK^T -> dots -> exp with STATIC row bound -> PV (V hi-only) -> av.
// 512 threads = 4 row-groups x 2 K-halves; Pa/Pb ping-pong; plain-add combine.
__global__ __launch_bounds__(512) void k_passC(const f16* __restrict__ fq16,
        const f16* __restrict__ fk16, const float* __restrict__ rq1,
        const float* __restrict__ muq, const float* __restrict__ rk1,
        const float* __restrict__ sk, const float* __restrict__ nuacck,
        const float* __restrict__ vcrow, const float* __restrict__ maxca,
        const float* __restrict__ maxva, const float* __restrict__ wv,
        const float* __restrict__ scal,
        const f16* __restrict__ fvhT,
        f16* __restrict__ avh, f16* __restrict__ avl) {
    __shared__ __align__(16) char arena[36864];   // Pa(18432) + Pb(18432); combine overlays
    __shared__ float rk1s[1024], sks[1024];
    f16* Pa = (f16*)arena;
    f16* Pb = (f16*)(arena + 18432);
    int hq = blockIdx.y;
    int t = threadIdx.x, l = t & 63, w = t >> 6;
    int rg = w & 3, kh = w >> 2;
    int lr = l & 15, kg = (l >> 4) * 8, rg4 = (l >> 4) * 4;
    int nb = blockIdx.x * 64 + rg * 16;
    int m0base = kh * 512;
    const f16* Q = fq16 + (size_t)hq * 65536;
    const f16* K = fk16 + (size_t)hq * 65536;
    {
        int i2 = t * 2;
        *(float2*)&rk1s[i2] = *(const float2*)&rk1[hq * 1024 + i2];
        *(float2*)&sks[i2]  = *(const float2*)&sk[hq * 1024 + i2];
    }
    __syncthreads();
    v8h aq0 = *(const v8h*)&Q[(size_t)(nb + lr) * 64 + kg];
    v8h aq1 = *(const v8h*)&Q[(size_t)(nb + lr) * 64 + 32 + kg];
    const float inv1024 = 1.0f / 1024.0f;
    float uvp = nuacck[hq * 64 + l] * inv1024;
    #pragma unroll
    for (int o = 32; o > 0; o >>= 1) uvp += __shfl_xor(uvp, o);
    float uv = uvp;
    float tpv = 0.f;
    #pragma unroll
    for (int e = 0; e < 8; ++e)
        tpv += (float)aq0[e] * nuacck[hq * 64 + kg + e]
             + (float)aq1[e] * nuacck[hq * 64 + 32 + kg + e];
    tpv *= inv1024;
    tpv += __shfl_xor(tpv, 16);
    tpv += __shfl_xor(tpv, 32);
    float muv[4], tv[4];
    #pragma unroll
    for (int r = 0; r < 4; ++r) {
        muv[r] = muq[hq * 1024 + nb + rg4 + r];
        tv[r] = __shfl(tpv, rg4 + r);
    }
    const float Acs = (0.001f / 1024.0f) / 8.0001f;
    float Pcr[4], Gcr[4];
    #pragma unroll
    for (int r = 0; r < 4; ++r) {
        Gcr[r] = Acs * muv[r];
        Pcr[r] = Acs * fmaf(muv[r], uv, -tv[r]);
    }
    int h = hq >> 2;
    float s1 = scal[0] + 1e-4f, s2v = scal[1] + 1e-4f, s3 = scal[2] + 1e-4f;
    float fc1 = wv[h * 3] / s1;
    float fc2 = wv[h * 3 + 1] * 0.3f / s2v;
    float c3 = wv[h * 3 + 2] * 0.3f / s3;
    float invt = 1.0f / scal[3];
    float rq1v[4], addc[4], mxr[4];
    #pragma unroll
    for (int r = 0; r < 4; ++r) {
        int row = hq * 1024 + nb + rg4 + r;
        rq1v[r] = rq1[row];
        addc[r] = (vcrow[row] + vcrow[32768 + row]) * c3;
        float mc = fmaxf(maxca[row], maxca[32768 + row]);
        float mv = fmaxf(maxva[row], maxva[32768 + row]);
        mxr[r] = fmaf(fc1, mc, fmaf(fc2, mv, addc[r])) * invt;
    }
    v4f accpv[4] = {};
    float rsacc[4] = {};
    for (int it = 0; it < 4; ++it) {
        TILE_STEP(Pa, m0base + it * 128)
        TILE_STEP(Pb, m0base + it * 128 + 64)
    }
    __syncthreads();   // all Pa/Pb uses complete before combine overlay reuse
    #pragma unroll
    for (int r = 0; r < 4; ++r) {
        float s = rsacc[r];
        s += __shfl_xor(s, 1); s += __shfl_xor(s, 2);
        s += __shfl_xor(s, 4); s += __shfl_xor(s, 8);
        rsacc[r] = s;
    }
    float* cbacc = (float*)arena;            // [4][16][64] = 16384 B
    float* cbrs  = (float*)(arena + 16384);  // [4][4][64]  = 4096 B
    if (kh == 1) {
        #pragma unroll
        for (int j = 0; j < 4; ++j)
            #pragma unroll
            for (int r = 0; r < 4; ++r)
                cbacc[(rg * 16 + j * 4 + r) * 64 + l] = accpv[j][r];
        #pragma unroll
        for (int r = 0; r < 4; ++r) cbrs[(rg * 4 + r) * 64 + l] = rsacc[r];
    }
    __syncthreads();
    if (kh == 0) {
        float rinv[4];
        #pragma unroll
        for (int r = 0; r < 4; ++r)
            rinv[r] = 1.0f / (rsacc[r] + cbrs[(rg * 4 + r) * 64 + l]);
        #pragma unroll
        for (int j = 0; j < 4; ++j)
            #pragma unroll
            for (int r = 0; r < 4; ++r) {
                float val = (accpv[j][r] + cbacc[(rg * 16 + j * 4 + r) * 64 + l])
                            * rinv[r];
                size_t idx = ((size_t)(hq * 1024 + nb + rg4 + r)) * 64 + j * 16 + lr;
                f16 hi = (f16)val;
                avh[idx] = hi;
                avl[idx] = (f16)(val - (float)hi);
            }
    }
}

// out = av @ Wout + bout (MFMA, av hi/lo x Wout hi = 2 MFMAs)
__global__ __launch_bounds__(256) void k_out_mfma(const f16* __restrict__ avh,
        const f16* __restrict__ avl,
        const f16* __restrict__ WoutTh,
        const float* __restrict__ bout, float* __restrict__ out) {
    __shared__ float red[2][4][4][4][64];
    int t = threadIdx.x, l = t & 63, w = t >> 6;
    int wc = w & 1, kh = w >> 1;
    int col0 = blockIdx.x * 128 + wc * 64;
    int tok0 = blockIdx.y * 64;
    int qi = tok0 >> 10, nb = tok0 & 1023;
    int lr = l & 15, kg = (l >> 4) * 8;
    v4f acc[4][4] = {};
    for (int ks8 = 0; ks8 < 8; ++ks8) {
        int ks = kh * 256 + ks8 * 32;
        int f = ks + kg;
        int h = f >> 6, d = f & 63;
        size_t hb = (size_t)((h << 2) + qi) * 1024;
        v8h ah[4], al4[4], bh[4];
        #pragma unroll
        for (int i = 0; i < 4; ++i) {
            int n = nb + i * 16 + lr;
            ah[i]  = *(const v8h*)&avh[(hb + n) * 64 + d];
            al4[i] = *(const v8h*)&avl[(hb + n) * 64 + d];
        }
        #pragma unroll
        for (int j = 0; j < 4; ++j)
            bh[j] = *(const v8h*)&WoutTh[(size_t)(col0 + j * 16 + lr) * 512 + ks + kg];
        #pragma unroll
        for (int i = 0; i < 4; ++i)
            #pragma unroll
            for (int j = 0; j < 4; ++j) {
                acc[i][j] = MFMA(ah[i], bh[j], acc[i][j]);
                acc[i][j] = MFMA(al4[i], bh[j], acc[i][j]);
            }
    }
    if (kh == 0) {
        #pragma unroll
        for (int i = 0; i < 4; ++i)
            #pragma unroll
            for (int j = 0; j < 4; ++j)
                #pragma unroll
                for (int r = 0; r < 4; ++r)
                    red[wc][i][j][r][l] = acc[i][j][r];
    }
    __syncthreads();
    if (kh == 1) {
        #pragma unroll
        for (int i = 0; i < 4; ++i)
            #pragma unroll
            for (int j = 0; j < 4; ++j) {
                int col = col0 + j * 16 + lr;
                float bo = bout[col];
                #pragma unroll
                for (int r = 0; r < 4; ++r) {
                    float val = acc[i][j][r] + red[wc][i][j][r][l] + bo;
                    int token = tok0 + i * 16 + (l >> 4) * 4 + r;
                    out[(size_t)token * 512 + col] = val;
                }
            }
    }
}

extern "C" void kernel_launch(void* const* d_in, const int* in_sizes, int n_in,
                              void* d_out, int out_size, void* d_ws, size_t ws_size,
                              hipStream_t stream) {
    const float* q     = (const float*)d_in[0];
    const float* k     = (const float*)d_in[1];
    const float* v     = (const float*)d_in[2];
    const float* ln_w  = (const float*)d_in[3];
    const float* ln_b  = (const float*)d_in[4];
    const float* W_in  = (const float*)d_in[5];
    const float* W_out = (const float*)d_in[6];
    const float* b_out = (const float*)d_in[7];
    const float* wp_W1 = (const float*)d_in[8];
    const float* wp_b1 = (const float*)d_in[9];
    const float* wp_lw = (const float*)d_in[10];
    const float* wp_lb = (const float*)d_in[11];
    const float* wp_W2 = (const float*)d_in[12];
    const float* wp_b2 = (const float*)d_in[13];
    const float* wp_W3 = (const float*)d_in[14];
    const float* wp_b3 = (const float*)d_in[15];
    const float* wp_W4 = (const float*)d_in[16];
    const float* wp_b4 = (const float*)d_in[17];
    const float* wtemp = (const float*)d_in[18];

    float* ws = (float*)d_ws;
    f16* ln16     = (f16*)(ws + OFF_LN16);
    f16* fq16     = (f16*)(ws + OFF_FQ16);
    f16* fk16     = (f16*)(ws + OFF_FK16);
    f16* fvhT     = (f16*)(ws + OFF_FVHT);
    f16* WinTh    = (f16*)(ws + OFF_WINTH);
    f16* WoutTh   = (f16*)(ws + OFF_WOUTTH);
    f16* avh      = (f16*)(ws + OFF_AVH);
    f16* avl      = (f16*)(ws + OFF_AVL);
    float* rq1    = ws + OFF_RQ1;
    float* rq2    = ws + OFF_RQ2;
    float* muq    = ws + OFF_MUQ;
    float* rk1    = ws + OFF_RK1;
    float* rk2    = ws + OFF_RK2;
    float* sk     = ws + OFF_SK;
    float* vcrow  = ws + OFF_VC;
    float* rowcos = ws + OFF_ROWCOS;
    float* rowcov = ws + OFF_ROWCOV;
    float* maxc   = ws + OFF_MAXC;
    float* maxv   = ws + OFF_MAXV;
    float* nuacck = ws + OFF_NUACC;
    float* pb     = ws + OFF_PB;
    float* hs     = ws + OFF_HS;
    float* rp     = ws + OFF_RP;
    float* feat   = ws + OFF_FEAT;
    float* wv     = ws + OFF_WV;
    float* scal   = ws + OFF_SCAL;

    k_zero<<<8, 256, 0, stream>>>(feat, nuacck);
    k_wprep<<<dim3(8, 8, 2), 256, 0, stream>>>(W_in, W_out, WinTh, WoutTh);
    k_ln16<<<3072, 256, 0, stream>>>(q, k, v, ln_w, ln_b, ln16);
    k_proj_all<<<dim3(4, 32, 3), 256, 0, stream>>>(ln16, WinTh,
            fq16, fk16, fvhT, rq1, rq2, muq, rk1, rk2, sk, feat, nuacck);
    k_mlp<<<8, 256, 0, stream>>>(feat, wp_W1, wp_b1, wp_lw, wp_lb,
                                 wp_W2, wp_b2, wp_W3, wp_b3, wp_W4, wp_b4,
                                 wtemp, wv);
    k_passA<<<dim3(16, 2, 32), 256, 0, stream>>>(fq16, fk16, rq1, rq2, muq, rk1, rk2,
                                                 sk, nuacck, vcrow, rowcos, rowcov,
                                                 maxc, maxv, pb);
    k_fin1<<<1, 256, 0, stream>>>(pb, vcrow, hs, scal);
    k_finrow<<<64, 256, 0, stream>>>(vcrow, rowcos, rowcov, wv, scal, rp);
    k_fin2<<<1, 64, 0, stream>>>(rp, hs, wv, scal);
    k_passC<<<dim3(16, 32), 512, 0, stream>>>(fq16, fk16, rq1, muq, rk1, sk, nuacck,
                                              vcrow, maxc, maxv, wv, scal,
                                              fvhT, avh, avl);
    k_out_mfma<<<dim3(4, 64), 256, 0, stream>>>(avh, avl, WoutTh, b_out,
                                                (float*)d_out);
}

// Round 17
// 241.429 us; speedup vs baseline: 1.2487x; 1.0303x over previous
//
#include <hip/hip_runtime.h>
#include <math.h>

typedef _Float16 f16;
typedef _Float16 v8h __attribute__((ext_vector_type(8)));
typedef _Float16 v4h __attribute__((ext_vector_type(4)));
typedef float    v4f __attribute__((ext_vector_type(4)));

#define MFMA(a, b, c) __builtin_amdgcn_mfma_f32_16x16x32_f16((a), (b), (c), 0, 0, 0)

// ---------------- workspace layout (float offsets) ----------------
#define OFF_LN16    0u
#define OFF_FQ16    4194304u
#define OFF_FK16    5242880u
#define OFF_FVHT    6291456u
#define OFF_WINTH   8388608u
#define OFF_WOUTTH  8650752u
#define OFF_AVH     8912896u
#define OFF_RQ1     11010048u
#define OFF_RQ2     11042816u
#define OFF_MUQ     11075584u
#define OFF_RK1     11108352u
#define OFF_RK2     11141120u
#define OFF_SK      11173888u
#define OFF_VC      11206656u   // 65536 (2 halves)
#define OFF_ROWCOS  11272192u   // 2 halves
#define OFF_ROWCOV  11337728u   // 2 halves
#define OFF_NUACC   11403264u   // 2048
#define OFF_PB      11405312u   // 1024*6
#define OFF_HS      11411456u   // 64
#define OFF_RP      11411520u   // 192
#define OFF_FEAT    11411712u   // 1024
#define OFF_WV      11412736u   // 24
#define OFF_SCAL    11412760u   // 8
#define OFF_MAXC    11412768u   // 65536 (2 halves)
#define OFF_MAXV    11478304u   // 65536 (2 halves)

__device__ __forceinline__ float clampf(float x, float lo, float hi) {
    return fminf(fmaxf(x, lo), hi);
}

__global__ void k_zero(float* feat, float* nuacck) {
    int i = blockIdx.x * 256 + threadIdx.x;
    if (i < 1024) feat[i] = 0.0f;
    if (i < 2048) nuacck[i] = 0.0f;
}

// transpose of a 512x512 weight to f16: W[k][c] -> WT[c][k] (hi only)
__global__ __launch_bounds__(256) void k_wprep(const float* __restrict__ Win,
        const float* __restrict__ Wout, f16* __restrict__ WinTh,
        f16* __restrict__ WoutTh) {
    __shared__ float lds[64][68];
    const float* W = blockIdx.z ? Wout : Win;
    f16* Th = blockIdx.z ? WoutTh : WinTh;
    int k0 = blockIdx.y * 64, c0 = blockIdx.x * 64;
    int t = threadIdx.x;
    #pragma unroll
    for (int p = 0; p < 4; ++p) {
        int flat = p * 1024 + t * 4;
        int r = flat >> 6, c = flat & 63;
        *(float4*)&lds[r][c] = *(const float4*)&W[(size_t)(k0 + r) * 512 + c0 + c];
    }
    __syncthreads();
    int c = t >> 2, kk = (t & 3) * 16;
    #pragma unroll
    for (int half = 0; half < 2; ++half) {
        v8h h8;
        #pragma unroll
        for (int ii = 0; ii < 8; ++ii)
            h8[ii] = (f16)lds[kk + half * 8 + ii][c];
        *(v8h*)&Th[(size_t)(c0 + c) * 512 + k0 + kk + half * 8] = h8;
    }
}

// LayerNorm all 12288 tokens -> ln16 f16
__global__ __launch_bounds__(256) void k_ln16(const float* __restrict__ q,
        const float* __restrict__ kk, const float* __restrict__ v,
        const float* __restrict__ lnw, const float* __restrict__ lnb,
        f16* __restrict__ ln16) {
    int t = threadIdx.x, wid = t >> 6, lane = t & 63;
    int token = blockIdx.x * 4 + wid;
    int inp = token >> 12, lt = token & 4095;
    const float* xp = (inp == 0) ? q : ((inp == 1) ? kk : v);
    const float4* xr = (const float4*)(xp + (size_t)lt * 512);
    float4 a = xr[lane], b = xr[lane + 64];
    float s = a.x + a.y + a.z + a.w + b.x + b.y + b.z + b.w;
    float s2 = a.x*a.x + a.y*a.y + a.z*a.z + a.w*a.w
             + b.x*b.x + b.y*b.y + b.z*b.z + b.w*b.w;
    for (int o = 32; o > 0; o >>= 1) { s += __shfl_down(s, o); s2 += __shfl_down(s2, o); }
    float m_ = __shfl(s, 0) * (1.0f / 512.0f);
    float var = __shfl(s2, 0) * (1.0f / 512.0f) - m_ * m_;
    var = fmaxf(var, 0.0f);
    float rs = rsqrtf(var + 1e-5f);
    const float4* w4 = (const float4*)lnw;
    const float4* b4 = (const float4*)lnb;
    float4 wa = w4[lane], wb = w4[lane + 64], ba = b4[lane], bb = b4[lane + 64];
    f16* orow = ln16 + (size_t)token * 512;
    v4h ha, hb;
    ha[0] = (f16)((a.x - m_) * rs * wa.x + ba.x);
    ha[1] = (f16)((a.y - m_) * rs * wa.y + ba.y);
    ha[2] = (f16)((a.z - m_) * rs * wa.z + ba.z);
    ha[3] = (f16)((a.w - m_) * rs * wa.w + ba.w);
    hb[0] = (f16)((b.x - m_) * rs * wb.x + bb.x);
    hb[1] = (f16)((b.y - m_) * rs * wb.y + bb.y);
    hb[2] = (f16)((b.z - m_) * rs * wb.z + bb.z);
    hb[3] = (f16)((b.w - m_) * rs * wb.w + bb.w);
    *(v4h*)&orow[lane * 4] = ha;
    *(v4h*)&orow[lane * 4 + 256] = hb;
}

// LN16 @ Win (MFMA), single-precision f16 path for all modes.
// MODE 0: q (fq16 + recip stats). MODE 1: k. MODE 2: v (transposed write).
template<int MODE>
__device__ __forceinline__ void proj_body(const f16* __restrict__ A16,
        const f16* __restrict__ BTh,
        f16* __restrict__ fout16, f16* __restrict__ fhT,
        float* __restrict__ oA, float* __restrict__ oB, float* __restrict__ oC,
        float* __restrict__ feat, float* __restrict__ nuacck) {
    int t = threadIdx.x, l = t & 63, w = t >> 6;
    int wr = w >> 1, wc = w & 1;
    int col0 = blockIdx.x * 128 + wc * 64;
    int tok0 = blockIdx.y * 128 + wr * 64;
    int lr = l & 15, kg = (l >> 4) * 8;
    int rg4 = (l >> 4) * 4;
    v4f acc[4][4] = {};
    for (int ks = 0; ks < 512; ks += 32) {
        v8h a[4], b[4];
        #pragma unroll
        for (int i = 0; i < 4; ++i)
            a[i] = *(const v8h*)&A16[(size_t)(tok0 + i * 16 + lr) * 512 + ks + kg];
        #pragma unroll
        for (int j = 0; j < 4; ++j)
            b[j] = *(const v8h*)&BTh[(size_t)(col0 + j * 16 + lr) * 512 + ks + kg];
        #pragma unroll
        for (int i = 0; i < 4; ++i)
            #pragma unroll
            for (int j = 0; j < 4; ++j)
                acc[i][j] = MFMA(a[i], b[j], acc[i][j]);
    }
    int h = col0 >> 6;
    #pragma unroll
    for (int i = 0; i < 4; ++i)
        #pragma unroll
        for (int j = 0; j < 4; ++j)
            #pragma unroll
            for (int r = 0; r < 4; ++r) {
                int token = tok0 + i * 16 + rg4 + r;
                int d = j * 16 + lr;
                int qi = token >> 10, n = token & 1023;
                float val = acc[i][j][r];
                if constexpr (MODE != 2) {
                    fout16[((size_t)((h << 2) + qi) * 1024 + n) * 64 + d] = (f16)val;
                } else {
                    fhT[((size_t)((h << 2) + qi) * 64 + d) * 1024 + n] = (f16)val;
                }
            }
    if constexpr (MODE != 2) {
        #pragma unroll
        for (int i = 0; i < 4; ++i)
            #pragma unroll
            for (int r = 0; r < 4; ++r) {
                float s = 0.f, s2 = 0.f;
                #pragma unroll
                for (int j = 0; j < 4; ++j) { float v = acc[i][j][r]; s += v; s2 += v * v; }
                #pragma unroll
                for (int mk = 1; mk <= 8; mk <<= 1) {
                    s += __shfl_xor(s, mk); s2 += __shfl_xor(s2, mk);
                }
                if (lr == 0) {
                    int token = tok0 + i * 16 + rg4 + r;
                    int qi = token >> 10, n = token & 1023;
                    int row = ((h << 2) + qi) * 1024 + n;
                    float nv = sqrtf(s2);
                    oA[row] = 1.0f / (nv + 1e-6f);
                    oB[row] = 1.0f / fmaxf(nv, 1e-4f);
                    oC[row] = (MODE == 0) ? s * (1.0f / 64.0f) : s;
                }
            }
        float cs[4];
        #pragma unroll
        for (int j = 0; j < 4; ++j) {
            float c = 0.f;
            #pragma unroll
            for (int i = 0; i < 4; ++i)
                #pragma unroll
                for (int r = 0; r < 4; ++r) c += acc[i][j][r];
            c += __shfl_xor(c, 16); c += __shfl_xor(c, 32);
            cs[j] = c;
        }
        if (l < 16) {
            #pragma unroll
            for (int j = 0; j < 4; ++j)
                atomicAdd(&feat[h * 128 + (MODE == 1 ? 64 : 0) + j * 16 + l],
                          cs[j] * (1.0f / 4096.0f));
            if constexpr (MODE == 1) {
                int qi = tok0 >> 10;
                #pragma unroll
                for (int j = 0; j < 4; ++j)
                    atomicAdd(&nuacck[((h << 2) + qi) * 64 + j * 16 + l], cs[j]);
            }
        }
    }
}

__global__ __launch_bounds__(256) void k_proj_all(const f16* __restrict__ ln16,
        const f16* __restrict__ BTh,
        f16* __restrict__ fq16, f16* __restrict__ fk16,
        f16* __restrict__ fvhT,
        float* __restrict__ rq1, float* __restrict__ rq2, float* __restrict__ muq,
        float* __restrict__ rk1, float* __restrict__ rk2, float* __restrict__ sk,
        float* __restrict__ feat, float* __restrict__ nuacck) {
    int mode = blockIdx.z;
    if (mode == 0)
        proj_body<0>(ln16, BTh, fq16, nullptr, rq1, rq2, muq, feat, nullptr);
    else if (mode == 1)
        proj_body<1>(ln16 + 2097152u, BTh, fk16, nullptr, rk1, rk2, sk, feat, nuacck);
    else
        proj_body<2>(ln16 + 4194304u, BTh, nullptr, fvhT,
                     nullptr, nullptr, nullptr, nullptr, nullptr);
}

// tiny MLP weight predictor, one block per head -> wv[h][3]
__global__ __launch_bounds__(256) void k_mlp(const float* __restrict__ feat,
        const float* __restrict__ W1, const float* __restrict__ b1,
        const float* __restrict__ lw, const float* __restrict__ lb,
        const float* __restrict__ W2, const float* __restrict__ b2,
        const float* __restrict__ W3, const float* __restrict__ b3,
        const float* __restrict__ W4, const float* __restrict__ b4,
        const float* __restrict__ wtemp, float* wv) {
    __shared__ float h1[256], h2[192], h3[64], red[8];
    int t = threadIdx.x;
    int h = blockIdx.x;
    float p = 0.0f;
    for (int i = 0; i < 128; ++i) p += feat[h * 128 + i] * W1[i * 256 + t];
    p += b1[t];
    float s = p, s2 = p * p;
    for (int o = 32; o > 0; o >>= 1) { s += __shfl_down(s, o); s2 += __shfl_down(s2, o); }
    if ((t & 63) == 0) { red[t >> 6] = s; red[4 + (t >> 6)] = s2; }
    __syncthreads();
    float S = red[0] + red[1] + red[2] + red[3];
    float S2 = red[4] + red[5] + red[6] + red[7];
    float mu = S / 256.0f;
    float var = S2 / 256.0f - mu * mu; if (var < 0.0f) var = 0.0f;
    float xh = (p - mu) * rsqrtf(var + 1e-5f) * lw[t] + lb[t];
    h1[t] = fmaxf(xh, 0.0f);
    __syncthreads();
    if (t < 192) {
        float a = 0.0f;
        for (int i = 0; i < 256; ++i) a += h1[i] * W2[i * 192 + t];
        h2[t] = fmaxf(a + b2[t], 0.0f);
    }
    __syncthreads();
    if (t < 64) {
        float a = 0.0f;
        for (int i = 0; i < 192; ++i) a += h2[i] * W3[i * 64 + t];
        h3[t] = fmaxf(a + b3[t], 0.0f);
    }
    __syncthreads();
    if (t == 0) {
        float lg[3];
        for (int j = 0; j < 3; ++j) {
            float a = 0.0f;
            for (int i = 0; i < 64; ++i) a += h3[i] * W4[i * 3 + j];
            lg[j] = a + b4[j];
        }
        float mx = fmaxf(lg[0], fmaxf(lg[1], lg[2]));
        float e0 = expf(lg[0] - mx), e1 = expf(lg[1] - mx), e2 = expf(lg[2] - mx);
        float se = e0 + e1 + e2;
        float pr0 = e0 / se, pr1 = e1 / se, pr2 = e2 / se;
        float wt = wtemp[0]; wt = fminf(fmaxf(wt, 0.01f), 1.0f);
        float q0 = pr0 / wt, q1 = pr1 / wt, q2 = pr2 / wt;
        float m2 = fmaxf(q0, fmaxf(q1, q2));
        float f0 = expf(q0 - m2), f1 = expf(q1 - m2), f2 = expf(q2 - m2);
        float sf = f0 + f1 + f2; f0 /= sf; f1 /= sf; f2 /= sf;
        f0 = fminf(fmaxf(f0, 0.01f), 0.95f);
        f1 = fminf(fmaxf(f1, 0.01f), 0.95f);
        f2 = fminf(fmaxf(f2, 0.01f), 0.95f);
        float sw = f0 + f1 + f2;
        wv[h * 3 + 0] = f0 / sw; wv[h * 3 + 1] = f1 / sw; wv[h * 3 + 2] = f2 / sw;
    }
}

// ---- shared per-pass preamble for passA: grid (16, 2, 32) ----
#define PASS_PREAMBLE_AB                                                       \
    int hq = blockIdx.z;                                                       \
    int half = blockIdx.y;                                                     \
    int m0base = half * 512;                                                   \
    int t = threadIdx.x, l = t & 63, w = t >> 6;                               \
    int lr = l & 15, kg = (l >> 4) * 8, rg4 = (l >> 4) * 4;                    \
    int nb = blockIdx.x * 64 + w * 16;                                         \
    const f16* Q = fq16 + (size_t)hq * 65536;                                  \
    const f16* K = fk16 + (size_t)hq * 65536;                                  \
    v8h aq0 = *(const v8h*)&Q[(size_t)(nb + lr) * 64 + kg];                    \
    v8h aq1 = *(const v8h*)&Q[(size_t)(nb + lr) * 64 + 32 + kg];               \
    const float inv1024 = 1.0f / 1024.0f;                                      \
    float uvp = nuacck[hq * 64 + l] * inv1024;                                 \
    _Pragma("unroll")                                                          \
    for (int o = 32; o > 0; o >>= 1) uvp += __shfl_xor(uvp, o);                \
    float uv = uvp;                                                            \
    float tp = 0.f;                                                            \
    _Pragma("unroll")                                                          \
    for (int e = 0; e < 8; ++e)                                                \
        tp += (float)aq0[e] * nuacck[hq * 64 + kg + e]                         \
            + (float)aq1[e] * nuacck[hq * 64 + 32 + kg + e];                   \
    tp *= inv1024;                                                             \
    tp += __shfl_xor(tp, 16);                                                  \
    tp += __shfl_xor(tp, 32);                                                  \
    float muv[4], tv[4];                                                       \
    _Pragma("unroll")                                                          \
    for (int r = 0; r < 4; ++r) {                                              \
        muv[r] = muq[hq * 1024 + nb + rg4 + r];                                \
        tv[r] = __shfl(tp, rg4 + r);                                           \
    }                                                                          \
    const float Acs = (0.001f / 1024.0f) / 8.0001f;                            \
    float Pr[4], Gr[4];                                                        \
    _Pragma("unroll")                                                          \
    for (int r = 0; r < 4; ++r) {                                              \
        Gr[r] = Acs * muv[r];                                                  \
        Pr[r] = Acs * fmaf(muv[r], uv, -tv[r]);                                \
    }

#define LOAD_KTILE(m0a)                                                        \
    v8h b0[4], b1[4];                                                          \
    _Pragma("unroll")                                                          \
    for (int j = 0; j < 4; ++j) {                                              \
        b0[j] = *(const v8h*)&K[(size_t)((m0a) + j * 16 + lr) * 64 + kg];      \
        b1[j] = *(const v8h*)&K[(size_t)((m0a) + j * 16 + lr) * 64 + 32 + kg]; \
    }

// pass A: cos/cov global+cross sums, per-row sums AND maxes, margin means.
// scos/scov derived from row sums post-loop (exact totals, fewer inner ops).
__global__ __launch_bounds__(256) void k_passA(const f16* __restrict__ fq16,
        const f16* __restrict__ fk16, const float* __restrict__ rq1,
        const float* __restrict__ rq2, const float* __restrict__ muq,
        const float* __restrict__ rk1, const float* __restrict__ rk2,
        const float* __restrict__ sk, const float* __restrict__ nuacck,
        float* __restrict__ vcrow, float* __restrict__ rowcos,
        float* __restrict__ rowcov, float* __restrict__ maxc,
        float* __restrict__ maxv, float* __restrict__ pb) {
    __shared__ float rk1s[512], rk2s[512], sks[512];
    PASS_PREAMBLE_AB
    {
        int i2 = t * 2;
        *(float2*)&rk1s[i2] = *(const float2*)&rk1[hq * 1024 + m0base + i2];
        *(float2*)&rk2s[i2] = *(const float2*)&rk2[hq * 1024 + m0base + i2];
        *(float2*)&sks[i2]  = *(const float2*)&sk[hq * 1024 + m0base + i2];
    }
    __syncthreads();
    float rq1v[4], rq2v[4];
    #pragma unroll
    for (int r = 0; r < 4; ++r) {
        rq1v[r] = rq1[hq * 1024 + nb + rg4 + r];
        rq2v[r] = rq2[hq * 1024 + nb + rg4 + r];
    }
    float s2cos = 0, s2cov = 0, sccov = 0;
    float mp[4] = {}, rcs[4] = {}, rcv[4] = {};
    float mcs[4] = { -1e30f, -1e30f, -1e30f, -1e30f };
    float mcv[4] = { -1e30f, -1e30f, -1e30f, -1e30f };
    #pragma unroll 2
    for (int m0 = 0; m0 < 512; m0 += 64) {
        LOAD_KTILE(m0base + m0)
        float rk1v[4], rk2v[4], skv[4];
        #pragma unroll
        for (int j = 0; j < 4; ++j) {
            int cg = m0 + j * 16 + lr;
            rk1v[j] = rk1s[cg]; rk2v[j] = rk2s[cg]; skv[j] = sks[cg];
        }
        v4f acc[4] = {};
        #pragma unroll
        for (int j = 0; j < 4; ++j) {
            acc[j] = MFMA(aq0, b0[j], acc[j]);
            acc[j] = MFMA(aq1, b1[j], acc[j]);
        }
        #pragma unroll
        for (int j = 0; j < 4; ++j)
            #pragma unroll
            for (int r = 0; r < 4; ++r) {
                float rv = acc[j][r];
                float cosv = clampf(rv * rq1v[r] * rk1v[j], -0.95f, 0.95f);
                float x2 = rv * rq2v[r] * rk2v[j];
                float marg = fmaxf(0.01f - fmaxf(x2, -0.95f), 0.0f);
                float cov = fmaf(-Gr[r], skv[j], fmaf(Acs, rv, Pr[r]));
                s2cos = fmaf(cosv, cosv, s2cos);
                s2cov = fmaf(cov, cov, s2cov);
                sccov = fmaf(cosv, cov, sccov);
                mp[r] += marg; rcs[r] += cosv; rcv[r] += cov;
                mcs[r] = fmaxf(mcs[r], cosv);
                mcv[r] = fmaxf(mcv[r], cov);
            }
    }
    float scos = rcs[0] + rcs[1] + rcs[2] + rcs[3];
    float scov = rcv[0] + rcv[1] + rcv[2] + rcv[3];
    #pragma unroll
    for (int r = 0; r < 4; ++r) {
        float m_ = mp[r], c_ = rcs[r], v_ = rcv[r];
        float xc = mcs[r], xv = mcv[r];
        #pragma unroll
        for (int mk = 1; mk <= 8; mk <<= 1) {
            m_ += __shfl_xor(m_, mk);
            c_ += __shfl_xor(c_, mk);
            v_ += __shfl_xor(v_, mk);
            xc = fmaxf(xc, __shfl_xor(xc, mk));
            xv = fmaxf(xv, __shfl_xor(xv, mk));
        }
        if (lr == 0) {
            int row = hq * 1024 + nb + rg4 + r;
            vcrow[half * 32768 + row] = m_ * inv1024;
            rowcos[half * 32768 + row] = c_;
            rowcov[half * 32768 + row] = v_;
            maxc[half * 32768 + row] = xc;
            maxv[half * 32768 + row] = xv;
        }
    }
    for (int o = 32; o > 0; o >>= 1) {
        scos += __shfl_down(scos, o); s2cos += __shfl_down(s2cos, o);
        scov += __shfl_down(scov, o); s2cov += __shfl_down(s2cov, o);
        sccov += __shfl_down(sccov, o);
    }
    __shared__ float bs[4][5];
    if (l == 0) { bs[w][0] = scos; bs[w][1] = s2cos; bs[w][2] = scov;
                  bs[w][3] = s2cov; bs[w][4] = sccov; }
    __syncthreads();
    if (t == 0) {
        int bid = (hq * 2 + half) * 16 + blockIdx.x;
        #pragma unroll
        for (int s = 0; s < 5; ++s)
            pb[bid * 6 + s] = bs[0][s] + bs[1][s] + bs[2][s] + bs[3][s];
    }
}

// fin1: per-head sums -> hs, global scal[0..2]
__global__ __launch_bounds__(256) void k_fin1(const float* __restrict__ pb,
        const float* __restrict__ vcrow, float* __restrict__ hs,
        float* __restrict__ scal) {
    __shared__ float hsl[40];
    int t = threadIdx.x;
    int hd = t >> 5, idx = t & 31;
    double a0 = 0, a1 = 0, a2 = 0, a3 = 0, a4 = 0;
    for (int i = idx; i < 128; i += 32) {
        const float* p = &pb[(hd * 128 + i) * 6];
        a0 += p[0]; a1 += p[1]; a2 += p[2]; a3 += p[3]; a4 += p[4];
    }
    for (int m = 1; m <= 16; m <<= 1) {
        a0 += __shfl_xor(a0, m); a1 += __shfl_xor(a1, m); a2 += __shfl_xor(a2, m);
        a3 += __shfl_xor(a3, m); a4 += __shfl_xor(a4, m);
    }
    if (idx == 0) {
        hsl[hd * 5 + 0] = (float)a0; hsl[hd * 5 + 1] = (float)a1;
        hsl[hd * 5 + 2] = (float)a2; hsl[hd * 5 + 3] = (float)a3;
        hsl[hd * 5 + 4] = (float)a4;
        hs[hd * 5 + 0] = (float)a0; hs[hd * 5 + 1] = (float)a1;
        hs[hd * 5 + 2] = (float)a2; hs[hd * 5 + 3] = (float)a3;
        hs[hd * 5 + 4] = (float)a4;
    }
    double s4 = 0, s5 = 0;
    for (int i = t; i < 32768; i += 256) {
        double rm = (double)(vcrow[i] + vcrow[32768 + i]);
        s4 += rm; s5 += rm * rm;
    }
    for (int o = 32; o > 0; o >>= 1) { s4 += __shfl_down(s4, o); s5 += __shfl_down(s5, o); }
    __shared__ double red[2][4];
    int wid = t >> 6, lane = t & 63;
    if (lane == 0) { red[0][wid] = s4; red[1][wid] = s5; }
    __syncthreads();
    if (t == 0) {
        double S4 = red[0][0] + red[0][1] + red[0][2] + red[0][3];
        double S5 = red[1][0] + red[1][1] + red[1][2] + red[1][3];
        double S0 = 0, S1 = 0, S2 = 0, S3 = 0;
        for (int h2 = 0; h2 < 8; ++h2) {
            S0 += hsl[h2 * 5 + 0]; S1 += hsl[h2 * 5 + 1];
            S2 += hsl[h2 * 5 + 2]; S3 += hsl[h2 * 5 + 3];
        }
        const double cnt = 33554432.0;
        scal[0] = (float)sqrt(fmax(0.0, (S1 - S0 * S0 / cnt) / (cnt - 1.0)));
        scal[1] = (float)sqrt(fmax(0.0, (S3 - S2 * S2 / cnt) / (cnt - 1.0)));
        double V4 = S4 * 1024.0, V5 = S5 * 1024.0;
        scal[2] = (float)sqrt(fmax(0.0, (V5 - V4 * V4 / cnt) / (cnt - 1.0)));
    }
}

// finrow: per-row addc cross terms -> rp[64][3]
__global__ __launch_bounds__(256) void k_finrow(const float* __restrict__ vcrow,
        const float* __restrict__ rowcos, const float* __restrict__ rowcov,
        const float* __restrict__ wv, const float* __restrict__ scal,
        float* __restrict__ rp) {
    int t = threadIdx.x;
    float s1 = scal[0] + 1e-4f, s2v = scal[1] + 1e-4f, s3 = scal[2] + 1e-4f;
    float p1 = 0, p2 = 0, p3 = 0;
    #pragma unroll
    for (int i = 0; i < 2; ++i) {
        int row = blockIdx.x * 512 + i * 256 + t;
        int h = row >> 12;
        float fc1 = wv[h * 3] / s1;
        float fc2 = wv[h * 3 + 1] * 0.3f / s2v;
        float c3 = wv[h * 3 + 2] * 0.3f / s3;
        float a = (vcrow[row] + vcrow[32768 + row]) * c3;
        float b = fc1 * (rowcos[row] + rowcos[32768 + row])
                + fc2 * (rowcov[row] + rowcov[32768 + row]);
        p1 += a; p2 = fmaf(a, a, p2); p3 = fmaf(a, b, p3);
    }
    for (int o = 32; o > 0; o >>= 1) {
        p1 += __shfl_down(p1, o); p2 += __shfl_down(p2, o); p3 += __shfl_down(p3, o);
    }
    __shared__ float red[3][4];
    int wid = t >> 6, lane = t & 63;
    if (lane == 0) { red[0][wid] = p1; red[1][wid] = p2; red[2][wid] = p3; }
    __syncthreads();
    if (t == 0) {
        rp[blockIdx.x * 3 + 0] = red[0][0] + red[0][1] + red[0][2] + red[0][3];
        rp[blockIdx.x * 3 + 1] = red[1][0] + red[1][1] + red[1][2] + red[1][3];
        rp[blockIdx.x * 3 + 2] = red[2][0] + red[2][1] + red[2][2] + red[2][3];
    }
}

// fin2: ds via decomposition -> temp
__global__ __launch_bounds__(64) void k_fin2(const float* __restrict__ rp,
        const float* __restrict__ hs, const float* __restrict__ wv,
        float* __restrict__ scal) {
    int t = threadIdx.x;
    double p1 = rp[t * 3 + 0], p2 = rp[t * 3 + 1], p3 = rp[t * 3 + 2];
    for (int o = 32; o > 0; o >>= 1) {
        p1 += __shfl_down(p1, o); p2 += __shfl_down(p2, o); p3 += __shfl_down(p3, o);
    }
    if (t == 0) {
        double s1 = (double)scal[0] + 1e-4, s2v = (double)scal[1] + 1e-4;
        double sdd = 1024.0 * p1;
        double sdd2 = 2.0 * p3 + 1024.0 * p2;
        for (int h = 0; h < 8; ++h) {
            double fc1 = (double)wv[h * 3] / s1;
            double fc2 = (double)wv[h * 3 + 1] * 0.3 / s2v;
            sdd += fc1 * hs[h * 5 + 0] + fc2 * hs[h * 5 + 2];
            sdd2 += fc1 * fc1 * hs[h * 5 + 1] + fc2 * fc2 * hs[h * 5 + 3]
                  + 2.0 * fc1 * fc2 * hs[h * 5 + 4];
        }
        const double cnt = 33554432.0;
        double ds = sqrt(fmax(0.0, (sdd2 - sdd * sdd / cnt) / (cnt - 1.0)));
        float temp = (ds < 1e-5) ? 0.01f : ((ds < 1e-3) ? 0.05f : (0.2f + (float)ds * 2.0f));
        temp = fminf(fmaxf(temp, 0.01f), 8.0f);
        scal[3] = temp;
    }
}

// ---- one 64-key tile of the pass-C loop with fully folded constants:
// arg = fc1s*cosv + A2*rv - G2_r*sk + C_r (already includes -M_r and log2e);
// P = exp2(arg). ----
#define TILE_STEP(PBASE, MK)                                                   \
    {                                                                          \
        int mk = (MK);                                                         \
        v8h b0[4], b1[4];                                                      \
        _Pragma("unroll")                                                      \
        for (int j = 0; j < 4; ++j) {                                          \
            b0[j] = *(const v8h*)&K[(size_t)(mk + j * 16 + lr) * 64 + kg];     \
            b1[j] = *(const v8h*)&K[(size_t)(mk + j * 16 + lr) * 64 + 32 + kg];\
        }                                                                      \
        float rk1v[4], skv[4];                                                 \
        _Pragma("unroll")                                                      \
        for (int j = 0; j < 4; ++j) {                                          \
            int cg = mk + j * 16 + lr;                                         \
            rk1v[j] = rk1s[cg]; skv[j] = sks[cg];                              \
        }                                                                      \
        v4f acc[4] = {};                                                       \
        _Pragma("unroll")                                                      \
        for (int j = 0; j < 4; ++j) {                                          \
            acc[j] = MFMA(aq0, b0[j], acc[j]);                                 \
            acc[j] = MFMA(aq1, b1[j], acc[j]);                                 \
        }                                                                      \
        _Pragma("unroll")                                                      \
        for (int j = 0; j < 4; ++j)                                            \
            _Pragma("unroll")                                                  \
            for (int r = 0; r < 4; ++r) {                                      \
                float rv = acc[j][r];                                          \
                float cosv = clampf(rv * rq1v[r] * rk1v[j], -0.95f, 0.95f);    \
                float arg = fmaf(fc1s, cosv,                                   \
                              fmaf(-G2[r], skv[j], fmaf(A2, rv, Cr[r])));      \
                float pe = exp2f(arg);                                         \
                f16 p16 = (f16)pe;                                             \
                rsacc[r] += (float)p16;                                        \
                (PBASE)[(w * 16 + rg4 + r) * 72 + j * 16 + lr] = p16;          \
            }                                                                  \
        v8h pa0 = *(const v8h*)&(PBASE)[(w * 16 + lr) * 72 + kg];              \
        v8h pa1 = *(const v8h*)&(PBASE)[(w * 16 + lr) * 72 + 32 + kg];         \
        _Pragma("unroll")                                                      \
        for (int j = 0; j < 4; ++j) {                                          \
            size_t vb = ((size_t)hq * 64 + j * 16 + lr) * 1024 + mk;           \
            v8h vh0 = *(const v8h*)&fvhT[vb + kg];                             \
            v8h vh1 = *(const v8h*)&fvhT[vb + 32 + kg];                        \
            accpv[j] = MFMA(pa0, vh0, accpv[j]);                               \
            accpv[j] = MFMA(pa1, vh1, accpv[j]);                               \
        }                                                                      \
    }

// pass C: QK^T -> exp2 with folded static bound -> PV (V hi-only) -> av (f16).
// 512 threads = 4 row-groups x 2 K-halves; Pa/Pb ping-pong; plain-add combine.
__global__ __launch_bounds__(512) void k_passC(const f16* __restrict__ fq16,
        const f16* __restrict__ fk16, const float* __restrict__ rq1,
        const float* __restrict__ muq, const float* __restrict__ rk1,
        const float* __restrict__ sk, const float* __restrict__ nuacck,
        const float* __restrict__ vcrow, const float* __restrict__ maxca,
        const float* __restrict__ maxva, const float* __restrict__ wv,
        const float* __restrict__ scal,
        const f16* __restrict__ fvhT,
        f16* __restrict__ avh) {
    __shared__ __align__(16) char arena[36864];   // Pa(18432) + Pb(18432); combine overlays
    __shared__ float rk1s[1024], sks[1024];
    f16* Pa = (f16*)arena;
    f16* Pb = (f16*)(arena + 18432);
    int hq = blockIdx.y;
    int t = threadIdx.x, l = t & 63, w = t >> 6;
    int rg = w & 3, kh = w >> 2;
    int lr = l & 15, kg = (l >> 4) * 8, rg4 = (l >> 4) * 4;
    int nb = blockIdx.x * 64 + rg * 16;
    int m0base = kh * 512;
    const f16* Q = fq16 + (size_t)hq * 65536;
    const f16* K = fk16 + (size_t)hq * 65536;
    {
        int i2 = t * 2;
        *(float2*)&rk1s[i2] = *(const float2*)&rk1[hq * 1024 + i2];
        *(float2*)&sks[i2]  = *(const float2*)&sk[hq * 1024 + i2];
    }
    __syncthreads();
    v8h aq0 = *(const v8h*)&Q[(size_t)(nb + lr) * 64 + kg];
    v8h aq1 = *(const v8h*)&Q[(size_t)(nb + lr) * 64 + 32 + kg];
    const float inv1024 = 1.0f / 1024.0f;
    float uvp = nuacck[hq * 64 + l] * inv1024;
    #pragma unroll
    for (int o = 32; o > 0; o >>= 1) uvp += __shfl_xor(uvp, o);
    float uv = uvp;
    float tpv = 0.f;
    #pragma unroll
    for (int e = 0; e < 8; ++e)
        tpv += (float)aq0[e] * nuacck[hq * 64 + kg + e]
             + (float)aq1[e] * nuacck[hq * 64 + 32 + kg + e];
    tpv *= inv1024;
    tpv += __shfl_xor(tpv, 16);
    tpv += __shfl_xor(tpv, 32);
    float muv[4], tv[4];
    #pragma unroll
    for (int r = 0; r < 4; ++r) {
        muv[r] = muq[hq * 1024 + nb + rg4 + r];
        tv[r] = __shfl(tpv, rg4 + r);
    }
    const float Acs = (0.001f / 1024.0f) / 8.0001f;
    int h = hq >> 2;
    float s1 = scal[0] + 1e-4f, s2v = scal[1] + 1e-4f, s3 = scal[2] + 1e-4f;
    float fc1 = wv[h * 3] / s1;
    float fc2 = wv[h * 3 + 1] * 0.3f / s2v;
    float c3 = wv[h * 3 + 2] * 0.3f / s3;
    const float LOG2E = 1.44269504088896f;
    float sfold = (1.0f / scal[3]) * LOG2E;
    float fc1s = fc1 * sfold;
    float A2 = fc2 * Acs * sfold;
    float rq1v[4], G2[4], Cr[4];
    #pragma unroll
    for (int r = 0; r < 4; ++r) {
        int row = hq * 1024 + nb + rg4 + r;
        rq1v[r] = rq1[row];
        float addc = (vcrow[row] + vcrow[32768 + row]) * c3;
        float mc = fmaxf(maxca[row], maxca[32768 + row]);
        float mv = fmaxf(maxva[row], maxva[32768 + row]);
        // dd = fc1*cos + fc2*(Acs*rv - Gcr*sk + Pcr) + addc;  M = fc1*mc+fc2*mv+addc
        // arg = (dd - M)*invt*LOG2E = fc1s*cos + A2*rv - G2*sk + Cr
        float Pcr = Acs * fmaf(muv[r], uv, -tv[r]);
        G2[r] = fc2 * Acs * muv[r] * sfold;
        Cr[r] = (fc2 * Pcr - fc1 * mc - fc2 * mv) * sfold;
    }
    v4f accpv[4] = {};
    float rsacc[4] = {};
    for (int it = 0; it < 4; ++it) {
        TILE_STEP(Pa, m0base + it * 128)
        TILE_STEP(Pb, m0base + it * 128 + 64)
    }
    __syncthreads();   // all Pa/Pb uses complete before combine overlay reuse
    #pragma unroll
    for (int r = 0; r < 4; ++r) {
        float s = rsacc[r];
        s += __shfl_xor(s, 1); s += __shfl_xor(s, 2);
        s += __shfl_xor(s, 4); s += __shfl_xor(s, 8);
        rsacc[r] = s;
    }
    float* cbacc = (float*)arena;            // [4][16][64] = 16384 B
    float* cbrs  = (float*)(arena + 16384);  // [4][4][64]  = 4096 B
    if (kh == 1) {
        #pragma unroll
        for (int j = 0; j < 4; ++j)
            #pragma unroll
            for (int r = 0; r < 4; ++r)
                cbacc[(rg * 16 + j * 4 + r) * 64 + l] = accpv[j][r];
        #pragma unroll
        for (int r = 0; r < 4; ++r) cbrs[(rg * 4 + r) * 64 + l] = rsacc[r];
    }
    __syncthreads();
    if (kh == 0) {
        float rinv[4];
        #pragma unroll
        for (int r = 0; r < 4; ++r)
            rinv[r] = 1.0f / (rsacc[r] + cbrs[(rg * 4 + r) * 64 + l]);
        #pragma unroll
        for (int j = 0; j < 4; ++j)
            #pragma unroll
            for (int r = 0; r < 4; ++r) {
                float val = (accpv[j][r] + cbacc[(rg * 16 + j * 4 + r) * 64 + l])
                            * rinv[r];
                size_t idx = ((size_t)(hq * 1024 + nb + rg4 + r)) * 64 + j * 16 + lr;
                avh[idx] = (f16)val;
            }
    }
}

// out = av @ Wout + bout (single MFMA per fragment)
__global__ __launch_bounds__(256) void k_out_mfma(const f16* __restrict__ avh,
        const f16* __restrict__ WoutTh,
        const float* __restrict__ bout, float* __restrict__ out) {
    __shared__ float red[2][4][4][4][64];
    int t = threadIdx.x, l = t & 63, w = t >> 6;
    int wc = w & 1, kh = w >> 1;
    int col0 = blockIdx.x * 128 + wc * 64;
    int tok0 = blockIdx.y * 64;
    int qi = tok0 >> 10, nb = tok0 & 1023;
    int lr = l & 15, kg = (l >> 4) * 8;
    v4f acc[4][4] = {};
    for (int ks8 = 0; ks8 < 8; ++ks8) {
        int ks = kh * 256 + ks8 * 32;
        int f = ks + kg;
        int h = f >> 6, d = f & 63;
        size_t hb = (size_t)((h << 2) + qi) * 1024;
        v8h ah[4], bh[4];
        #pragma unroll
        for (int i = 0; i < 4; ++i) {
            int n = nb + i * 16 + lr;
            ah[i] = *(const v8h*)&avh[(hb + n) * 64 + d];
        }
        #pragma unroll
        for (int j = 0; j < 4; ++j)
            bh[j] = *(const v8h*)&WoutTh[(size_t)(col0 + j * 16 + lr) * 512 + ks + kg];
        #pragma unroll
        for (int i = 0; i < 4; ++i)
            #pragma unroll
            for (int j = 0; j < 4; ++j)
                acc[i][j] = MFMA(ah[i], bh[j], acc[i][j]);
    }
    if (kh == 0) {
        #pragma unroll
        for (int i = 0; i < 4; ++i)
            #pragma unroll
            for (int j = 0; j < 4; ++j)
                #pragma unroll
                for (int r = 0; r < 4; ++r)
                    red[wc][i][j][r][l] = acc[i][j][r];
    }
    __syncthreads();
    if (kh == 1) {
        #pragma unroll
        for (int i = 0; i < 4; ++i)
            #pragma unroll
            for (int j = 0; j < 4; ++j) {
                int col = col0 + j * 16 + lr;
                float bo = bout[col];
                #pragma unroll
                for (int r = 0; r < 4; ++r) {
                    float val = acc[i][j][r] + red[wc][i][j][r][l] + bo;
                    int token = tok0 + i * 16 + (l >> 4) * 4 + r;
                    out[(size_t)token * 512 + col] = val;
                }
            }
    }
}

extern "C" void kernel_launch(void* const* d_in, const int* in_sizes, int n_in,
                              void* d_out, int out_size, void* d_ws, size_t ws_size,
                              hipStream_t stream) {
    const float* q     = (const float*)d_in[0];
    const float* k     = (const float*)d_in[1];
    const float* v     = (const float*)d_in[2];
    const float* ln_w  = (const float*)d_in[3];
    const float* ln_b  = (const float*)d_in[4];
    const float* W_in  = (const float*)d_in[5];
    const float* W_out = (const float*)d_in[6];
    const float* b_out = (const float*)d_in[7];
    const float* wp_W1 = (const float*)d_in[8];
    const float* wp_b1 = (const float*)d_in[9];
    const float* wp_lw = (const float*)d_in[10];
    const float* wp_lb = (const float*)d_in[11];
    const float* wp_W2 = (const float*)d_in[12];
    const float* wp_b2 = (const float*)d_in[13];
    const float* wp_W3 = (const float*)d_in[14];
    const float* wp_b3 = (const float*)d_in[15];
    const float* wp_W4 = (const float*)d_in[16];
    const float* wp_b4 = (const float*)d_in[17];
    const float* wtemp = (const float*)d_in[18];

    float* ws = (float*)d_ws;
    f16* ln16     = (f16*)(ws + OFF_LN16);
    f16* fq16     = (f16*)(ws + OFF_FQ16);
    f16* fk16     = (f16*)(ws + OFF_FK16);
    f16* fvhT     = (f16*)(ws + OFF_FVHT);
    f16* WinTh    = (f16*)(ws + OFF_WINTH);
    f16* WoutTh   = (f16*)(ws + OFF_WOUTTH);
    f16* avh      = (f16*)(ws + OFF_AVH);
    float* rq1    = ws + OFF_RQ1;
    float* rq2    = ws + OFF_RQ2;
    float* muq    = ws + OFF_MUQ;
    float* rk1    = ws + OFF_RK1;
    float* rk2    = ws + OFF_RK2;
    float* sk     = ws + OFF_SK;
    float* vcrow  = ws + OFF_VC;
    float* rowcos = ws + OFF_ROWCOS;
    float* rowcov = ws + OFF_ROWCOV;
    float* maxc   = ws + OFF_MAXC;
    float* maxv   = ws + OFF_MAXV;
    float* nuacck = ws + OFF_NUACC;
    float* pb     = ws + OFF_PB;
    float* hs     = ws + OFF_HS;
    float* rp     = ws + OFF_RP;
    float* feat   = ws + OFF_FEAT;
    float* wv     = ws + OFF_WV;
    float* scal   = ws + OFF_SCAL;

    k_zero<<<8, 256, 0, stream>>>(feat, nuacck);
    k_wprep<<<dim3(8, 8, 2), 256, 0, stream>>>(W_in, W_out, WinTh, WoutTh);
    k_ln16<<<3072, 256, 0, stream>>>(q, k, v, ln_w, ln_b, ln16);
    k_proj_all<<<dim3(4, 32, 3), 256, 0, stream>>>(ln16, WinTh,
            fq16, fk16, fvhT, rq1, rq2, muq, rk1, rk2, sk, feat, nuacck);
    k_mlp<<<8, 256, 0, stream>>>(feat, wp_W1, wp_b1, wp_lw, wp_lb,
                                 wp_W2, wp_b2, wp_W3, wp_b3, wp_W4, wp_b4,
                                 wtemp, wv);
    k_passA<<<dim3(16, 2, 32), 256, 0, stream>>>(fq16, fk16, rq1, rq2, muq, rk1, rk2,
                                                 sk, nuacck, vcrow, rowcos, rowcov,
                                                 maxc, maxv, pb);
    k_fin1<<<1, 256, 0, stream>>>(pb, vcrow, hs, scal);
    k_finrow<<<64, 256, 0, stream>>>(vcrow, rowcos, rowcov, wv, scal, rp);
    k_fin2<<<1, 64, 0, stream>>>(rp, hs, wv, scal);
    k_passC<<<dim3(16, 32), 512, 0, stream>>>(fq16, fk16, rq1, muq, rk1, sk, nuacck,
                                              vcrow, maxc, maxv, wv, scal,
                                              fvhT, avh);
    k_out_mfma<<<dim3(4, 64), 256, 0, stream>>>(avh, WoutTh, b_out,
                                                (float*)d_out);
}

// Round 18
// 233.186 us; speedup vs baseline: 1.2928x; 1.0353x over previous
//
#include <hip/hip_runtime.h>
#include <math.h>

typedef _Float16 f16;
typedef _Float16 v8h __attribute__((ext_vector_type(8)));
typedef _Float16 v4h __attribute__((ext_vector_type(4)));
typedef float    v4f __attribute__((ext_vector_type(4)));

#define MFMA(a, b, c) __builtin_amdgcn_mfma_f32_16x16x32_f16((a), (b), (c), 0, 0, 0)

// ---------------- workspace layout (float offsets) ----------------
#define OFF_LN16    0u
#define OFF_FQ16    4194304u
#define OFF_FK16    5242880u
#define OFF_FVHT    6291456u
#define OFF_WINTH   8388608u
#define OFF_WOUTTH  8650752u
#define OFF_AVH     8912896u
#define OFF_RQ1     11010048u
#define OFF_MUQ     11075584u
#define OFF_RK1     11108352u
#define OFF_SK      11173888u
#define OFF_VC      11206656u   // 65536 (2 halves)
#define OFF_ROWCOS  11272192u   // 2 halves
#define OFF_ROWCOV  11337728u   // 2 halves
#define OFF_NUACC   11403264u   // 2048
#define OFF_PB      11405312u   // 1024*6
#define OFF_HS      11411456u   // 64
#define OFF_RP      11411520u   // 192
#define OFF_FEAT    11411712u   // 1024
#define OFF_WV      11412736u   // 24
#define OFF_SCAL    11412760u   // 8
#define OFF_MAXC    11412768u   // 65536 (2 halves)
#define OFF_MAXV    11478304u   // 65536 (2 halves)

__device__ __forceinline__ float clampf(float x, float lo, float hi) {
    return fminf(fmaxf(x, lo), hi);
}

__global__ void k_zero(float* feat, float* nuacck) {
    int i = blockIdx.x * 256 + threadIdx.x;
    if (i < 1024) feat[i] = 0.0f;
    if (i < 2048) nuacck[i] = 0.0f;
}

// transpose of a 512x512 weight to f16: W[k][c] -> WT[c][k] (hi only)
__global__ __launch_bounds__(256) void k_wprep(const float* __restrict__ Win,
        const float* __restrict__ Wout, f16* __restrict__ WinTh,
        f16* __restrict__ WoutTh) {
    __shared__ float lds[64][68];
    const float* W = blockIdx.z ? Wout : Win;
    f16* Th = blockIdx.z ? WoutTh : WinTh;
    int k0 = blockIdx.y * 64, c0 = blockIdx.x * 64;
    int t = threadIdx.x;
    #pragma unroll
    for (int p = 0; p < 4; ++p) {
        int flat = p * 1024 + t * 4;
        int r = flat >> 6, c = flat & 63;
        *(float4*)&lds[r][c] = *(const float4*)&W[(size_t)(k0 + r) * 512 + c0 + c];
    }
    __syncthreads();
    int c = t >> 2, kk = (t & 3) * 16;
    #pragma unroll
    for (int half = 0; half < 2; ++half) {
        v8h h8;
        #pragma unroll
        for (int ii = 0; ii < 8; ++ii)
            h8[ii] = (f16)lds[kk + half * 8 + ii][c];
        *(v8h*)&Th[(size_t)(c0 + c) * 512 + k0 + kk + half * 8] = h8;
    }
}

// LayerNorm all 12288 tokens -> ln16 f16
__global__ __launch_bounds__(256) void k_ln16(const float* __restrict__ q,
        const float* __restrict__ kk, const float* __restrict__ v,
        const float* __restrict__ lnw, const float* __restrict__ lnb,
        f16* __restrict__ ln16) {
    int t = threadIdx.x, wid = t >> 6, lane = t & 63;
    int token = blockIdx.x * 4 + wid;
    int inp = token >> 12, lt = token & 4095;
    const float* xp = (inp == 0) ? q : ((inp == 1) ? kk : v);
    const float4* xr = (const float4*)(xp + (size_t)lt * 512);
    float4 a = xr[lane], b = xr[lane + 64];
    float s = a.x + a.y + a.z + a.w + b.x + b.y + b.z + b.w;
    float s2 = a.x*a.x + a.y*a.y + a.z*a.z + a.w*a.w
             + b.x*b.x + b.y*b.y + b.z*b.z + b.w*b.w;
    for (int o = 32; o > 0; o >>= 1) { s += __shfl_down(s, o); s2 += __shfl_down(s2, o); }
    float m_ = __shfl(s, 0) * (1.0f / 512.0f);
    float var = __shfl(s2, 0) * (1.0f / 512.0f) - m_ * m_;
    var = fmaxf(var, 0.0f);
    float rs = rsqrtf(var + 1e-5f);
    const float4* w4 = (const float4*)lnw;
    const float4* b4 = (const float4*)lnb;
    float4 wa = w4[lane], wb = w4[lane + 64], ba = b4[lane], bb = b4[lane + 64];
    f16* orow = ln16 + (size_t)token * 512;
    v4h ha, hb;
    ha[0] = (f16)((a.x - m_) * rs * wa.x + ba.x);
    ha[1] = (f16)((a.y - m_) * rs * wa.y + ba.y);
    ha[2] = (f16)((a.z - m_) * rs * wa.z + ba.z);
    ha[3] = (f16)((a.w - m_) * rs * wa.w + ba.w);
    hb[0] = (f16)((b.x - m_) * rs * wb.x + bb.x);
    hb[1] = (f16)((b.y - m_) * rs * wb.y + bb.y);
    hb[2] = (f16)((b.z - m_) * rs * wb.z + bb.z);
    hb[3] = (f16)((b.w - m_) * rs * wb.w + bb.w);
    *(v4h*)&orow[lane * 4] = ha;
    *(v4h*)&orow[lane * 4 + 256] = hb;
}

// LN16 @ Win (MFMA), single-precision f16 path for all modes.
// MODE 0: q (fq16 + recip norm + mean). MODE 1: k. MODE 2: v (transposed).
template<int MODE>
__device__ __forceinline__ void proj_body(const f16* __restrict__ A16,
        const f16* __restrict__ BTh,
        f16* __restrict__ fout16, f16* __restrict__ fhT,
        float* __restrict__ oA, float* __restrict__ oC,
        float* __restrict__ feat, float* __restrict__ nuacck) {
    int t = threadIdx.x, l = t & 63, w = t >> 6;
    int wr = w >> 1, wc = w & 1;
    int col0 = blockIdx.x * 128 + wc * 64;
    int tok0 = blockIdx.y * 128 + wr * 64;
    int lr = l & 15, kg = (l >> 4) * 8;
    int rg4 = (l >> 4) * 4;
    v4f acc[4][4] = {};
    for (int ks = 0; ks < 512; ks += 32) {
        v8h a[4], b[4];
        #pragma unroll
        for (int i = 0; i < 4; ++i)
            a[i] = *(const v8h*)&A16[(size_t)(tok0 + i * 16 + lr) * 512 + ks + kg];
        #pragma unroll
        for (int j = 0; j < 4; ++j)
            b[j] = *(const v8h*)&BTh[(size_t)(col0 + j * 16 + lr) * 512 + ks + kg];
        #pragma unroll
        for (int i = 0; i < 4; ++i)
            #pragma unroll
            for (int j = 0; j < 4; ++j)
                acc[i][j] = MFMA(a[i], b[j], acc[i][j]);
    }
    int h = col0 >> 6;
    #pragma unroll
    for (int i = 0; i < 4; ++i)
        #pragma unroll
        for (int j = 0; j < 4; ++j)
            #pragma unroll
            for (int r = 0; r < 4; ++r) {
                int token = tok0 + i * 16 + rg4 + r;
                int d = j * 16 + lr;
                int qi = token >> 10, n = token & 1023;
                float val = acc[i][j][r];
                if constexpr (MODE != 2) {
                    fout16[((size_t)((h << 2) + qi) * 1024 + n) * 64 + d] = (f16)val;
                } else {
                    fhT[((size_t)((h << 2) + qi) * 64 + d) * 1024 + n] = (f16)val;
                }
            }
    if constexpr (MODE != 2) {
        #pragma unroll
        for (int i = 0; i < 4; ++i)
            #pragma unroll
            for (int r = 0; r < 4; ++r) {
                float s = 0.f, s2 = 0.f;
                #pragma unroll
                for (int j = 0; j < 4; ++j) { float v = acc[i][j][r]; s += v; s2 += v * v; }
                #pragma unroll
                for (int mk = 1; mk <= 8; mk <<= 1) {
                    s += __shfl_xor(s, mk); s2 += __shfl_xor(s2, mk);
                }
                if (lr == 0) {
                    int token = tok0 + i * 16 + rg4 + r;
                    int qi = token >> 10, n = token & 1023;
                    int row = ((h << 2) + qi) * 1024 + n;
                    float nv = sqrtf(s2);
                    oA[row] = 1.0f / (nv + 1e-6f);
                    oC[row] = (MODE == 0) ? s * (1.0f / 64.0f) : s;
                }
            }
        float cs[4];
        #pragma unroll
        for (int j = 0; j < 4; ++j) {
            float c = 0.f;
            #pragma unroll
            for (int i = 0; i < 4; ++i)
                #pragma unroll
                for (int r = 0; r < 4; ++r) c += acc[i][j][r];
            c += __shfl_xor(c, 16); c += __shfl_xor(c, 32);
            cs[j] = c;
        }
        if (l < 16) {
            #pragma unroll
            for (int j = 0; j < 4; ++j)
                atomicAdd(&feat[h * 128 + (MODE == 1 ? 64 : 0) + j * 16 + l],
                          cs[j] * (1.0f / 4096.0f));
            if constexpr (MODE == 1) {
                int qi = tok0 >> 10;
                #pragma unroll
                for (int j = 0; j < 4; ++j)
                    atomicAdd(&nuacck[((h << 2) + qi) * 64 + j * 16 + l], cs[j]);
            }
        }
    }
}

__global__ __launch_bounds__(256) void k_proj_all(const f16* __restrict__ ln16,
        const f16* __restrict__ BTh,
        f16* __restrict__ fq16, f16* __restrict__ fk16,
        f16* __restrict__ fvhT,
        float* __restrict__ rq1, float* __restrict__ muq,
        float* __restrict__ rk1, float* __restrict__ sk,
        float* __restrict__ feat, float* __restrict__ nuacck) {
    int mode = blockIdx.z;
    if (mode == 0)
        proj_body<0>(ln16, BTh, fq16, nullptr, rq1, muq, feat, nullptr);
    else if (mode == 1)
        proj_body<1>(ln16 + 2097152u, BTh, fk16, nullptr, rk1, sk, feat, nuacck);
    else
        proj_body<2>(ln16 + 4194304u, BTh, nullptr, fvhT,
                     nullptr, nullptr, nullptr, nullptr);
}

// tiny MLP weight predictor, one block per head -> wv[h][3]
__global__ __launch_bounds__(256) void k_mlp(const float* __restrict__ feat,
        const float* __restrict__ W1, const float* __restrict__ b1,
        const float* __restrict__ lw, const float* __restrict__ lb,
        const float* __restrict__ W2, const float* __restrict__ b2,
        const float* __restrict__ W3, const float* __restrict__ b3,
        const float* __restrict__ W4, const float* __restrict__ b4,
        const float* __restrict__ wtemp, float* wv) {
    __shared__ float h1[256], h2[192], h3[64], red[8];
    int t = threadIdx.x;
    int h = blockIdx.x;
    float p = 0.0f;
    for (int i = 0; i < 128; ++i) p += feat[h * 128 + i] * W1[i * 256 + t];
    p += b1[t];
    float s = p, s2 = p * p;
    for (int o = 32; o > 0; o >>= 1) { s += __shfl_down(s, o); s2 += __shfl_down(s2, o); }
    if ((t & 63) == 0) { red[t >> 6] = s; red[4 + (t >> 6)] = s2; }
    __syncthreads();
    float S = red[0] + red[1] + red[2] + red[3];
    float S2 = red[4] + red[5] + red[6] + red[7];
    float mu = S / 256.0f;
    float var = S2 / 256.0f - mu * mu; if (var < 0.0f) var = 0.0f;
    float xh = (p - mu) * rsqrtf(var + 1e-5f) * lw[t] + lb[t];
    h1[t] = fmaxf(xh, 0.0f);
    __syncthreads();
    if (t < 192) {
        float a = 0.0f;
        for (int i = 0; i < 256; ++i) a += h1[i] * W2[i * 192 + t];
        h2[t] = fmaxf(a + b2[t], 0.0f);
    }
    __syncthreads();
    if (t < 64) {
        float a = 0.0f;
        for (int i = 0; i < 192; ++i) a += h2[i] * W3[i * 64 + t];
        h3[t] = fmaxf(a + b3[t], 0.0f);
    }
    __syncthreads();
    if (t == 0) {
        float lg[3];
        for (int j = 0; j < 3; ++j) {
            float a = 0.0f;
            for (int i = 0; i < 64; ++i) a += h3[i] * W4[i * 3 + j];
            lg[j] = a + b4[j];
        }
        float mx = fmaxf(lg[0], fmaxf(lg[1], lg[2]));
        float e0 = expf(lg[0] - mx), e1 = expf(lg[1] - mx), e2 = expf(lg[2] - mx);
        float se = e0 + e1 + e2;
        float pr0 = e0 / se, pr1 = e1 / se, pr2 = e2 / se;
        float wt = wtemp[0]; wt = fminf(fmaxf(wt, 0.01f), 1.0f);
        float q0 = pr0 / wt, q1 = pr1 / wt, q2 = pr2 / wt;
        float m2 = fmaxf(q0, fmaxf(q1, q2));
        float f0 = expf(q0 - m2), f1 = expf(q1 - m2), f2 = expf(q2 - m2);
        float sf = f0 + f1 + f2; f0 /= sf; f1 /= sf; f2 /= sf;
        f0 = fminf(fmaxf(f0, 0.01f), 0.95f);
        f1 = fminf(fmaxf(f1, 0.01f), 0.95f);
        f2 = fminf(fmaxf(f2, 0.01f), 0.95f);
        float sw = f0 + f1 + f2;
        wv[h * 3 + 0] = f0 / sw; wv[h * 3 + 1] = f1 / sw; wv[h * 3 + 2] = f2 / sw;
    }
}

// ---- shared per-pass preamble for passA: grid (16, 2, 32) ----
#define PASS_PREAMBLE_AB                                                       \
    int hq = blockIdx.z;                                                       \
    int half = blockIdx.y;                                                     \
    int m0base = half * 512;                                                   \
    int t = threadIdx.x, l = t & 63, w = t >> 6;                               \
    int lr = l & 15, kg = (l >> 4) * 8, rg4 = (l >> 4) * 4;                    \
    int nb = blockIdx.x * 64 + w * 16;                                         \
    const f16* Q = fq16 + (size_t)hq * 65536;                                  \
    const f16* K = fk16 + (size_t)hq * 65536;                                  \
    v8h aq0 = *(const v8h*)&Q[(size_t)(nb + lr) * 64 + kg];                    \
    v8h aq1 = *(const v8h*)&Q[(size_t)(nb + lr) * 64 + 32 + kg];               \
    const float inv1024 = 1.0f / 1024.0f;                                      \
    float uvp = nuacck[hq * 64 + l] * inv1024;                                 \
    _Pragma("unroll")                                                          \
    for (int o = 32; o > 0; o >>= 1) uvp += __shfl_xor(uvp, o);                \
    float uv = uvp;                                                            \
    float tp = 0.f;                                                            \
    _Pragma("unroll")                                                          \
    for (int e = 0; e < 8; ++e)                                                \
        tp += (float)aq0[e] * nuacck[hq * 64 + kg + e]                         \
            + (float)aq1[e] * nuacck[hq * 64 + 32 + kg + e];                   \
    tp *= inv1024;                                                             \
    tp += __shfl_xor(tp, 16);                                                  \
    tp += __shfl_xor(tp, 32);                                                  \
    float muv[4], tv[4];                                                       \
    _Pragma("unroll")                                                          \
    for (int r = 0; r < 4; ++r) {                                              \
        muv[r] = muq[hq * 1024 + nb + rg4 + r];                                \
        tv[r] = __shfl(tp, rg4 + r);                                           \
    }                                                                          \
    const float Acs = (0.001f / 1024.0f) / 8.0001f;                            \
    float Pr[4], Gr[4];                                                        \
    _Pragma("unroll")                                                          \
    for (int r = 0; r < 4; ++r) {                                              \
        Gr[r] = Acs * muv[r];                                                  \
        Pr[r] = Acs * fmaf(muv[r], uv, -tv[r]);                                \
    }

#define LOAD_KTILE(m0a)                                                        \
    v8h b0[4], b1[4];                                                          \
    _Pragma("unroll")                                                          \
    for (int j = 0; j < 4; ++j) {                                              \
        b0[j] = *(const v8h*)&K[(size_t)((m0a) + j * 16 + lr) * 64 + kg];      \
        b1[j] = *(const v8h*)&K[(size_t)((m0a) + j * 16 + lr) * 64 + 32 + kg]; \
    }

// pass A: cos/cov global+cross sums, per-row sums AND maxes, margin means.
// margin derived from cosv (rq2/rk2 path removed: denominators differ <3e-6).
__global__ __launch_bounds__(256) void k_passA(const f16* __restrict__ fq16,
        const f16* __restrict__ fk16, const float* __restrict__ rq1,
        const float* __restrict__ muq,
        const float* __restrict__ rk1,
        const float* __restrict__ sk, const float* __restrict__ nuacck,
        float* __restrict__ vcrow, float* __restrict__ rowcos,
        float* __restrict__ rowcov, float* __restrict__ maxc,
        float* __restrict__ maxv, float* __restrict__ pb) {
    __shared__ float rk1s[512], sks[512];
    PASS_PREAMBLE_AB
    {
        int i2 = t * 2;
        *(float2*)&rk1s[i2] = *(const float2*)&rk1[hq * 1024 + m0base + i2];
        *(float2*)&sks[i2]  = *(const float2*)&sk[hq * 1024 + m0base + i2];
    }
    __syncthreads();
    float rq1v[4];
    #pragma unroll
    for (int r = 0; r < 4; ++r)
        rq1v[r] = rq1[hq * 1024 + nb + rg4 + r];
    float s2cos = 0, s2cov = 0, sccov = 0;
    float mp[4] = {}, rcs[4] = {}, rcv[4] = {};
    float mcs[4] = { -1e30f, -1e30f, -1e30f, -1e30f };
    float mcv[4] = { -1e30f, -1e30f, -1e30f, -1e30f };
    #pragma unroll 2
    for (int m0 = 0; m0 < 512; m0 += 64) {
        LOAD_KTILE(m0base + m0)
        float rk1v[4], skv[4];
        #pragma unroll
        for (int j = 0; j < 4; ++j) {
            int cg = m0 + j * 16 + lr;
            rk1v[j] = rk1s[cg]; skv[j] = sks[cg];
        }
        v4f acc[4] = {};
        #pragma unroll
        for (int j = 0; j < 4; ++j) {
            acc[j] = MFMA(aq0, b0[j], acc[j]);
            acc[j] = MFMA(aq1, b1[j], acc[j]);
        }
        #pragma unroll
        for (int j = 0; j < 4; ++j)
            #pragma unroll
            for (int r = 0; r < 4; ++r) {
                float rv = acc[j][r];
                float cosv = clampf(rv * rq1v[r] * rk1v[j], -0.95f, 0.95f);
                float marg = fmaxf(0.01f - cosv, 0.0f);
                float cov = fmaf(-Gr[r], skv[j], fmaf(Acs, rv, Pr[r]));
                s2cos = fmaf(cosv, cosv, s2cos);
                s2cov = fmaf(cov, cov, s2cov);
                sccov = fmaf(cosv, cov, sccov);
                mp[r] += marg; rcs[r] += cosv; rcv[r] += cov;
                mcs[r] = fmaxf(mcs[r], cosv);
                mcv[r] = fmaxf(mcv[r], cov);
            }
    }
    float scos = rcs[0] + rcs[1] + rcs[2] + rcs[3];
    float scov = rcv[0] + rcv[1] + rcv[2] + rcv[3];
    #pragma unroll
    for (int r = 0; r < 4; ++r) {
        float m_ = mp[r], c_ = rcs[r], v_ = rcv[r];
        float xc = mcs[r], xv = mcv[r];
        #pragma unroll
        for (int mk = 1; mk <= 8; mk <<= 1) {
            m_ += __shfl_xor(m_, mk);
            c_ += __shfl_xor(c_, mk);
            v_ += __shfl_xor(v_, mk);
            xc = fmaxf(xc, __shfl_xor(xc, mk));
            xv = fmaxf(xv, __shfl_xor(xv, mk));
        }
        if (lr == 0) {
            int row = hq * 1024 + nb + rg4 + r;
            vcrow[half * 32768 + row] = m_ * inv1024;
            rowcos[half * 32768 + row] = c_;
            rowcov[half * 32768 + row] = v_;
            maxc[half * 32768 + row] = xc;
            maxv[half * 32768 + row] = xv;
        }
    }
    for (int o = 32; o > 0; o >>= 1) {
        scos += __shfl_down(scos, o); s2cos += __shfl_down(s2cos, o);
        scov += __shfl_down(scov, o); s2cov += __shfl_down(s2cov, o);
        sccov += __shfl_down(sccov, o);
    }
    __shared__ float bs[4][5];
    if (l == 0) { bs[w][0] = scos; bs[w][1] = s2cos; bs[w][2] = scov;
                  bs[w][3] = s2cov; bs[w][4] = sccov; }
    __syncthreads();
    if (t == 0) {
        int bid = (hq * 2 + half) * 16 + blockIdx.x;
        #pragma unroll
        for (int s = 0; s < 5; ++s)
            pb[bid * 6 + s] = bs[0][s] + bs[1][s] + bs[2][s] + bs[3][s];
    }
}

// fin1: per-head sums -> hs, global scal[0..2]
__global__ __launch_bounds__(256) void k_fin1(const float* __restrict__ pb,
        const float* __restrict__ vcrow, float* __restrict__ hs,
        float* __restrict__ scal) {
    __shared__ float hsl[40];
    int t = threadIdx.x;
    int hd = t >> 5, idx = t & 31;
    double a0 = 0, a1 = 0, a2 = 0, a3 = 0, a4 = 0;
    for (int i = idx; i < 128; i += 32) {
        const float* p = &pb[(hd * 128 + i) * 6];
        a0 += p[0]; a1 += p[1]; a2 += p[2]; a3 += p[3]; a4 += p[4];
    }
    for (int m = 1; m <= 16; m <<= 1) {
        a0 += __shfl_xor(a0, m); a1 += __shfl_xor(a1, m); a2 += __shfl_xor(a2, m);
        a3 += __shfl_xor(a3, m); a4 += __shfl_xor(a4, m);
    }
    if (idx == 0) {
        hsl[hd * 5 + 0] = (float)a0; hsl[hd * 5 + 1] = (float)a1;
        hsl[hd * 5 + 2] = (float)a2; hsl[hd * 5 + 3] = (float)a3;
        hsl[hd * 5 + 4] = (float)a4;
        hs[hd * 5 + 0] = (float)a0; hs[hd * 5 + 1] = (float)a1;
        hs[hd * 5 + 2] = (float)a2; hs[hd * 5 + 3] = (float)a3;
        hs[hd * 5 + 4] = (float)a4;
    }
    double s4 = 0, s5 = 0;
    for (int i = t; i < 32768; i += 256) {
        double rm = (double)(vcrow[i] + vcrow[32768 + i]);
        s4 += rm; s5 += rm * rm;
    }
    for (int o = 32; o > 0; o >>= 1) { s4 += __shfl_down(s4, o); s5 += __shfl_down(s5, o); }
    __shared__ double red[2][4];
    int wid = t >> 6, lane = t & 63;
    if (lane == 0) { red[0][wid] = s4; red[1][wid] = s5; }
    __syncthreads();
    if (t == 0) {
        double S4 = red[0][0] + red[0][1] + red[0][2] + red[0][3];
        double S5 = red[1][0] + red[1][1] + red[1][2] + red[1][3];
        double S0 = 0, S1 = 0, S2 = 0, S3 = 0;
        for (int h2 = 0; h2 < 8; ++h2) {
            S0 += hsl[h2 * 5 + 0]; S1 += hsl[h2 * 5 + 1];
            S2 += hsl[h2 * 5 + 2]; S3 += hsl[h2 * 5 + 3];
        }
        const double cnt = 33554432.0;
        scal[0] = (float)sqrt(fmax(0.0, (S1 - S0 * S0 / cnt) / (cnt - 1.0)));
        scal[1] = (float)sqrt(fmax(0.0, (S3 - S2 * S2 / cnt) / (cnt - 1.0)));
        double V4 = S4 * 1024.0, V5 = S5 * 1024.0;
        scal[2] = (float)sqrt(fmax(0.0, (V5 - V4 * V4 / cnt) / (cnt - 1.0)));
    }
}

// finrow: per-row addc cross terms -> rp[64][3]
__global__ __launch_bounds__(256) void k_finrow(const float* __restrict__ vcrow,
        const float* __restrict__ rowcos, const float* __restrict__ rowcov,
        const float* __restrict__ wv, const float* __restrict__ scal,
        float* __restrict__ rp) {
    int t = threadIdx.x;
    float s1 = scal[0] + 1e-4f, s2v = scal[1] + 1e-4f, s3 = scal[2] + 1e-4f;
    float p1 = 0, p2 = 0, p3 = 0;
    #pragma unroll
    for (int i = 0; i < 2; ++i) {
        int row = blockIdx.x * 512 + i * 256 + t;
        int h = row >> 12;
        float fc1 = wv[h * 3] / s1;
        float fc2 = wv[h * 3 + 1] * 0.3f / s2v;
        float c3 = wv[h * 3 + 2] * 0.3f / s3;
        float a = (vcrow[row] + vcrow[32768 + row]) * c3;
        float b = fc1 * (rowcos[row] + rowcos[32768 + row])
                + fc2 * (rowcov[row] + rowcov[32768 + row]);
        p1 += a; p2 = fmaf(a, a, p2); p3 = fmaf(a, b, p3);
    }
    for (int o = 32; o > 0; o >>= 1) {
        p1 += __shfl_down(p1, o); p2 += __shfl_down(p2, o); p3 += __shfl_down(p3, o);
    }
    __shared__ float red[3][4];
    int wid = t >> 6, lane = t & 63;
    if (lane == 0) { red[0][wid] = p1; red[1][wid] = p2; red[2][wid] = p3; }
    __syncthreads();
    if (t == 0) {
        rp[blockIdx.x * 3 + 0] = red[0][0] + red[0][1] + red[0][2] + red[0][3];
        rp[blockIdx.x * 3 + 1] = red[1][0] + red[1][1] + red[1][2] + red[1][3];
        rp[blockIdx.x * 3 + 2] = red[2][0] + red[2][1] + red[2][2] + red[2][3];
    }
}

// fin2: ds via decomposition -> temp
__global__ __launch_bounds__(64) void k_fin2(const float* __restrict__ rp,
        const float* __restrict__ hs, const float* __restrict__ wv,
        float* __restrict__ scal) {
    int t = threadIdx.x;
    double p1 = rp[t * 3 + 0], p2 = rp[t * 3 + 1], p3 = rp[t * 3 + 2];
    for (int o = 32; o > 0; o >>= 1) {
        p1 += __shfl_down(p1, o); p2 += __shfl_down(p2, o); p3 += __shfl_down(p3, o);
    }
    if (t == 0) {
        double s1 = (double)scal[0] + 1e-4, s2v = (double)scal[1] + 1e-4;
        double sdd = 1024.0 * p1;
        double sdd2 = 2.0 * p3 + 1024.0 * p2;
        for (int h = 0; h < 8; ++h) {
            double fc1 = (double)wv[h * 3] / s1;
            double fc2 = (double)wv[h * 3 + 1] * 0.3 / s2v;
            sdd += fc1 * hs[h * 5 + 0] + fc2 * hs[h * 5 + 2];
            sdd2 += fc1 * fc1 * hs[h * 5 + 1] + fc2 * fc2 * hs[h * 5 + 3]
                  + 2.0 * fc1 * fc2 * hs[h * 5 + 4];
        }
        const double cnt = 33554432.0;
        double ds = sqrt(fmax(0.0, (sdd2 - sdd * sdd / cnt) / (cnt - 1.0)));
        float temp = (ds < 1e-5) ? 0.01f : ((ds < 1e-3) ? 0.05f : (0.2f + (float)ds * 2.0f));
        temp = fminf(fmaxf(temp, 0.01f), 8.0f);
        scal[3] = temp;
    }
}

// ---- one 64-key tile of the pass-C loop with fully folded constants:
// arg = fc1s*cosv + A2*rv - G2_r*sk + C_r (already includes -M_r and log2e);
// P = exp2(arg). ----
#define TILE_STEP(PBASE, MK)                                                   \
    {                                                                          \
        int mk = (MK);                                                         \
        v8h b0[4], b1[4];                                                      \
        _Pragma("unroll")                                                      \
        for (int j = 0; j < 4; ++j) {                                          \
            b0[j] = *(const v8h*)&K[(size_t)(mk + j * 16 + lr) * 64 + kg];     \
            b1[j] = *(const v8h*)&K[(size_t)(mk + j * 16 + lr) * 64 + 32 + kg];\
        }                                                                      \
        float rk1v[4], skv[4];                                                 \
        _Pragma("unroll")                                                      \
        for (int j = 0; j < 4; ++j) {                                          \
            int cg = mk + j * 16 + lr;                                         \
            rk1v[j] = rk1s[cg]; skv[j] = sks[cg];                              \
        }                                                                      \
        v4f acc[4] = {};                                                       \
        _Pragma("unroll")                                                      \
        for (int j = 0; j < 4; ++j) {                                          \
            acc[j] = MFMA(aq0, b0[j], acc[j]);                                 \
            acc[j] = MFMA(aq1, b1[j], acc[j]);                                 \
        }                                                                      \
        _Pragma("unroll")                                                      \
        for (int j = 0; j < 4; ++j)                                            \
            _Pragma("unroll")                                                  \
            for (int r = 0; r < 4; ++r) {                                      \
                float rv = acc[j][r];                                          \
                float cosv = clampf(rv * rq1v[r] * rk1v[j], -0.95f, 0.95f);    \
                float arg = fmaf(fc1s, cosv,                                   \
                              fmaf(-G2[r], skv[j], fmaf(A2, rv, Cr[r])));      \
                float pe = exp2f(arg);                                         \
                f16 p16 = (f16)pe;                                             \
                rsacc[r] += (float)p16;                                        \
                (PBASE)[(w * 16 + rg4 + r) * 72 + j * 16 + lr] = p16;          \
            }                                                                  \
        v8h pa0 = *(const v8h*)&(PBASE)[(w * 16 + lr) * 72 + kg];              \
        v8h pa1 = *(const v8h*)&(PBASE)[(w * 16 + lr) * 72 + 32 + kg];         \
        _Pragma("unroll")                                                      \
        for (int j = 0; j < 4; ++j) {                                          \
            size_t vb = ((size_t)hq * 64 + j * 16 + lr) * 1024 + mk;           \
            v8h vh0 = *(const v8h*)&fvhT[vb + kg];                             \
            v8h vh1 = *(const v8h*)&fvhT[vb + 32 + kg];                        \
            accpv[j] = MFMA(pa0, vh0, accpv[j]);                               \
            accpv[j] = MFMA(pa1, vh1, accpv[j]);                               \
        }                                                                      \
    }

// pass C: QK^T -> exp2 with folded static bound -> PV (V hi-only) -> av (f16).
// 512 threads = 4 row-groups x 2 K-halves; Pa/Pb ping-pong; plain-add combine.
__global__ __launch_bounds__(512) void k_passC(const f16* __restrict__ fq16,
        const f16* __restrict__ fk16, const float* __restrict__ rq1,
        const float* __restrict__ muq, const float* __restrict__ rk1,
        const float* __restrict__ sk, const float* __restrict__ nuacck,
        const float* __restrict__ vcrow, const float* __restrict__ maxca,
        const float* __restrict__ maxva, const float* __restrict__ wv,
        const float* __restrict__ scal,
        const f16* __restrict__ fvhT,
        f16* __restrict__ avh) {
    __shared__ __align__(16) char arena[36864];   // Pa(18432) + Pb(18432); combine overlays
    __shared__ float rk1s[1024], sks[1024];
    f16* Pa = (f16*)arena;
    f16* Pb = (f16*)(arena + 18432);
    int hq = blockIdx.y;
    int t = threadIdx.x, l = t & 63, w = t >> 6;
    int rg = w & 3, kh = w >> 2;
    int lr = l & 15, kg = (l >> 4) * 8, rg4 = (l >> 4) * 4;
    int nb = blockIdx.x * 64 + rg * 16;
    int m0base = kh * 512;
    const f16* Q = fq16 + (size_t)hq * 65536;
    const f16* K = fk16 + (size_t)hq * 65536;
    {
        int i2 = t * 2;
        *(float2*)&rk1s[i2] = *(const float2*)&rk1[hq * 1024 + i2];
        *(float2*)&sks[i2]  = *(const float2*)&sk[hq * 1024 + i2];
    }
    __syncthreads();
    v8h aq0 = *(const v8h*)&Q[(size_t)(nb + lr) * 64 + kg];
    v8h aq1 = *(const v8h*)&Q[(size_t)(nb + lr) * 64 + 32 + kg];
    const float inv1024 = 1.0f / 1024.0f;
    float uvp = nuacck[hq * 64 + l] * inv1024;
    #pragma unroll
    for (int o = 32; o > 0; o >>= 1) uvp += __shfl_xor(uvp, o);
    float uv = uvp;
    float tpv = 0.f;
    #pragma unroll
    for (int e = 0; e < 8; ++e)
        tpv += (float)aq0[e] * nuacck[hq * 64 + kg + e]
             + (float)aq1[e] * nuacck[hq * 64 + 32 + kg + e];
    tpv *= inv1024;
    tpv += __shfl_xor(tpv, 16);
    tpv += __shfl_xor(tpv, 32);
    float muv[4], tv[4];
    #pragma unroll
    for (int r = 0; r < 4; ++r) {
        muv[r] = muq[hq * 1024 + nb + rg4 + r];
        tv[r] = __shfl(tpv, rg4 + r);
    }
    const float Acs = (0.001f / 1024.0f) / 8.0001f;
    int h = hq >> 2;
    float s1 = scal[0] + 1e-4f, s2v = scal[1] + 1e-4f, s3 = scal[2] + 1e-4f;
    float fc1 = wv[h * 3] / s1;
    float fc2 = wv[h * 3 + 1] * 0.3f / s2v;
    float c3 = wv[h * 3 + 2] * 0.3f / s3;
    const float LOG2E = 1.44269504088896f;
    float sfold = (1.0f / scal[3]) * LOG2E;
    float fc1s = fc1 * sfold;
    float A2 = fc2 * Acs * sfold;
    float rq1v[4], G2[4], Cr[4];
    #pragma unroll
    for (int r = 0; r < 4; ++r) {
        int row = hq * 1024 + nb + rg4 + r;
        rq1v[r] = rq1[row];
        float addc = (vcrow[row] + vcrow[32768 + row]) * c3;
        float mc = fmaxf(maxca[row], maxca[32768 + row]);
        float mv = fmaxf(maxva[row], maxva[32768 + row]);
        float Pcr = Acs * fmaf(muv[r], uv, -tv[r]);
        G2[r] = fc2 * Acs * muv[r] * sfold;
        Cr[r] = (fc2 * Pcr - fc1 * mc - fc2 * mv) * sfold;
    }
    v4f accpv[4] = {};
    float rsacc[4] = {};
    for (int it = 0; it < 4; ++it) {
        TILE_STEP(Pa, m0base + it * 128)
        TILE_STEP(Pb, m0base + it * 128 + 64)
    }
    __syncthreads();   // all Pa/Pb uses complete before combine overlay reuse
    #pragma unroll
    for (int r = 0; r < 4; ++r) {
        float s = rsacc[r];
        s += __shfl_xor(s, 1); s += __shfl_xor(s, 2);
        s += __shfl_xor(s, 4); s += __shfl_xor(s, 8);
        rsacc[r] = s;
    }
    float* cbacc = (float*)arena;            // [4][16][64] = 16384 B
    float* cbrs  = (float*)(arena + 16384);  // [4][4][64]  = 4096 B
    if (kh == 1) {
        #pragma unroll
        for (int j = 0; j < 4; ++j)
            #pragma unroll
            for (int r = 0; r < 4; ++r)
                cbacc[(rg * 16 + j * 4 + r) * 64 + l] = accpv[j][r];
        #pragma unroll
        for (int r = 0; r < 4; ++r) cbrs[(rg * 4 + r) * 64 + l] = rsacc[r];
    }
    __syncthreads();
    if (kh == 0) {
        float rinv[4];
        #pragma unroll
        for (int r = 0; r < 4; ++r)
            rinv[r] = 1.0f / (rsacc[r] + cbrs[(rg * 4 + r) * 64 + l]);
        #pragma unroll
        for (int j = 0; j < 4; ++j)
            #pragma unroll
            for (int r = 0; r < 4; ++r) {
                float val = (accpv[j][r] + cbacc[(rg * 16 + j * 4 + r) * 64 + l])
                            * rinv[r];
                size_t idx = ((size_t)(hq * 1024 + nb + rg4 + r)) * 64 + j * 16 + lr;
                avh[idx] = (f16)val;
            }
    }
}

// out = av @ Wout + bout (single MFMA per fragment)
__global__ __launch_bounds__(256) void k_out_mfma(const f16* __restrict__ avh,
        const f16* __restrict__ WoutTh,
        const float* __restrict__ bout, float* __restrict__ out) {
    __shared__ float red[2][4][4][4][64];
    int t = threadIdx.x, l = t & 63, w = t >> 6;
    int wc = w & 1, kh = w >> 1;
    int col0 = blockIdx.x * 128 + wc * 64;
    int tok0 = blockIdx.y * 64;
    int qi = tok0 >> 10, nb = tok0 & 1023;
    int lr = l & 15, kg = (l >> 4) * 8;
    v4f acc[4][4] = {};
    for (int ks8 = 0; ks8 < 8; ++ks8) {
        int ks = kh * 256 + ks8 * 32;
        int f = ks + kg;
        int h = f >> 6, d = f & 63;
        size_t hb = (size_t)((h << 2) + qi) * 1024;
        v8h ah[4], bh[4];
        #pragma unroll
        for (int i = 0; i < 4; ++i) {
            int n = nb + i * 16 + lr;
            ah[i] = *(const v8h*)&avh[(hb + n) * 64 + d];
        }
        #pragma unroll
        for (int j = 0; j < 4; ++j)
            bh[j] = *(const v8h*)&WoutTh[(size_t)(col0 + j * 16 + lr) * 512 + ks + kg];
        #pragma unroll
        for (int i = 0; i < 4; ++i)
            #pragma unroll
            for (int j = 0; j < 4; ++j)
                acc[i][j] = MFMA(ah[i], bh[j], acc[i][j]);
    }
    if (kh == 0) {
        #pragma unroll
        for (int i = 0; i < 4; ++i)
            #pragma unroll
            for (int j = 0; j < 4; ++j)
                #pragma unroll
                for (int r = 0; r < 4; ++r)
                    red[wc][i][j][r][l] = acc[i][j][r];
    }
    __syncthreads();
    if (kh == 1) {
        #pragma unroll
        for (int i = 0; i < 4; ++i)
            #pragma unroll
            for (int j = 0; j < 4; ++j) {
                int col = col0 + j * 16 + lr;
                float bo = bout[col];
                #pragma unroll
                for (int r = 0; r < 4; ++r) {
                    float val = acc[i][j][r] + red[wc][i][j][r][l] + bo;
                    int token = tok0 + i * 16 + (l >> 4) * 4 + r;
                    out[(size_t)token * 512 + col] = val;
                }
            }
    }
}

extern "C" void kernel_launch(void* const* d_in, const int* in_sizes, int n_in,
                              void* d_out, int out_size, void* d_ws, size_t ws_size,
                              hipStream_t stream) {
    const float* q     = (const float*)d_in[0];
    const float* k     = (const float*)d_in[1];
    const float* v     = (const float*)d_in[2];
    const float* ln_w  = (const float*)d_in[3];
    const float* ln_b  = (const float*)d_in[4];
    const float* W_in  = (const float*)d_in[5];
    const float* W_out = (const float*)d_in[6];
    const float* b_out = (const float*)d_in[7];
    const float* wp_W1 = (const float*)d_in[8];
    const float* wp_b1 = (const float*)d_in[9];
    const float* wp_lw = (const float*)d_in[10];
    const float* wp_lb = (const float*)d_in[11];
    const float* wp_W2 = (const float*)d_in[12];
    const float* wp_b2 = (const float*)d_in[13];
    const float* wp_W3 = (const float*)d_in[14];
    const float* wp_b3 = (const float*)d_in[15];
    const float* wp_W4 = (const float*)d_in[16];
    const float* wp_b4 = (const float*)d_in[17];
    const float* wtemp = (const float*)d_in[18];

    float* ws = (float*)d_ws;
    f16* ln16     = (f16*)(ws + OFF_LN16);
    f16* fq16     = (f16*)(ws + OFF_FQ16);
    f16* fk16     = (f16*)(ws + OFF_FK16);
    f16* fvhT     = (f16*)(ws + OFF_FVHT);
    f16* WinTh    = (f16*)(ws + OFF_WINTH);
    f16* WoutTh   = (f16*)(ws + OFF_WOUTTH);
    f16* avh      = (f16*)(ws + OFF_AVH);
    float* rq1    = ws + OFF_RQ1;
    float* muq    = ws + OFF_MUQ;
    float* rk1    = ws + OFF_RK1;
    float* sk     = ws + OFF_SK;
    float* vcrow  = ws + OFF_VC;
    float* rowcos = ws + OFF_ROWCOS;
    float* rowcov = ws + OFF_ROWCOV;
    float* maxc   = ws + OFF_MAXC;
    float* maxv   = ws + OFF_MAXV;
    float* nuacck = ws + OFF_NUACC;
    float* pb     = ws + OFF_PB;
    float* hs     = ws + OFF_HS;
    float* rp     = ws + OFF_RP;
    float* feat   = ws + OFF_FEAT;
    float* wv     = ws + OFF_WV;
    float* scal   = ws + OFF_SCAL;

    k_zero<<<8, 256, 0, stream>>>(feat, nuacck);
    k_wprep<<<dim3(8, 8, 2), 256, 0, stream>>>(W_in, W_out, WinTh, WoutTh);
    k_ln16<<<3072, 256, 0, stream>>>(q, k, v, ln_w, ln_b, ln16);
    k_proj_all<<<dim3(4, 32, 3), 256, 0, stream>>>(ln16, WinTh,
            fq16, fk16, fvhT, rq1, muq, rk1, sk, feat, nuacck);
    k_mlp<<<8, 256, 0, stream>>>(feat, wp_W1, wp_b1, wp_lw, wp_lb,
                                 wp_W2, wp_b2, wp_W3, wp_b3, wp_W4, wp_b4,
                                 wtemp, wv);
    k_passA<<<dim3(16, 2, 32), 256, 0, stream>>>(fq16, fk16, rq1, muq, rk1,
                                                 sk, nuacck, vcrow, rowcos, rowcov,
                                                 maxc, maxv, pb);
    k_fin1<<<1, 256, 0, stream>>>(pb, vcrow, hs, scal);
    k_finrow<<<64, 256, 0, stream>>>(vcrow, rowcos, rowcov, wv, scal, rp);
    k_fin2<<<1, 64, 0, stream>>>(rp, hs, wv, scal);
    k_passC<<<dim3(16, 32), 512, 0, stream>>>(fq16, fk16, rq1, muq, rk1, sk, nuacck,
                                              vcrow, maxc, maxv, wv, scal,
                                              fvhT, avh);
    k_out_mfma<<<dim3(4, 64), 256, 0, stream>>>(avh, WoutTh, b_out,
                                                (float*)d_out);
}